// Round 1
// baseline (13196.664 us; speedup 1.0000x reference)
//
#include <hip/hip_runtime.h>
#include <hip/hip_bf16.h>
#include <math.h>

#define B_ 4
#define T_ 1024
#define O_ 128
#define D_ 512
#define H_ 8
#define L_ 6
#define TK_ 2176
#define MM_ 100000
#define EH_ 4
#define EHD_ 128
#define HD_ 64

// PRIMES computed per reference: base=131, x=base+h*1009; row[i]=x; x=x*31+1 (uint32 wrap)
__device__ __constant__ unsigned int PRIMES_[4][4] = {
  {131u,  4062u,  125923u, 3903614u},
  {1140u, 35341u, 1095572u, 33962733u},
  {2149u, 66620u, 2065221u, 64021852u},
  {3158u, 97899u, 3034870u, 94080971u},
};

__device__ __forceinline__ float wave_max_f(float v) {
  #pragma unroll
  for (int off = 32; off; off >>= 1) v = fmaxf(v, __shfl_xor(v, off));
  return v;
}
__device__ __forceinline__ float wave_sum_f(float v) {
  #pragma unroll
  for (int off = 32; off; off >>= 1) v += __shfl_xor(v, off);
  return v;
}

// ---------------- rope tables: cos/sin [TK][32] ----------------
__global__ void rope_table_k(float* __restrict__ rc, float* __restrict__ rs) {
  int t = blockIdx.x;
  int j = threadIdx.x; // 0..31
  float freq = __powf(10000.0f, -(float)j / 32.0f);
  float ang = (float)t * freq;
  rc[t * 32 + j] = cosf(ang);
  rs[t * 32 + j] = sinf(ang);
}

// ---------------- ssum @ ssum_W -> ssp[B][D] ----------------
__global__ __launch_bounds__(256) void ssum_proj_k(const float* __restrict__ ssum,
                                                   const float* __restrict__ sW,
                                                   float* __restrict__ ssp) {
  int col = blockIdx.x * 256 + threadIdx.x;
  int b = blockIdx.y;
  float acc = 0.f;
  for (int d = 0; d < D_; ++d) acc += ssum[b * D_ + d] * sW[(size_t)d * D_ + col];
  ssp[b * D_ + col] = acc;
}

// ---------------- generic tiled f32 GEMM: C = [C +] A@W + bias, optional fused RoPE ----------------
// A: M x K (row-major), W: K x N, C: M x N. grid = (N/64, M/64), block 256.
__global__ __launch_bounds__(256) void sgemm_k(const float* __restrict__ A,
                                               const float* __restrict__ W,
                                               const float* __restrict__ bias,
                                               float* __restrict__ C,
                                               int M, int N, int K,
                                               int addC, int posmod,
                                               const float* __restrict__ rc,
                                               const float* __restrict__ rs) {
  __shared__ float As[16][68];
  __shared__ float Bs[16][68];
  int tid = threadIdx.x;
  int row0 = blockIdx.y * 64;
  int col0 = blockIdx.x * 64;
  int tx = tid & 15, ty = tid >> 4;
  int am = tid >> 2, ak = (tid & 3) * 4;
  int bk = tid >> 4, bc = (tid & 15) * 4;
  float acc[4][4] = {};
  for (int k0 = 0; k0 < K; k0 += 16) {
    float4 av = *reinterpret_cast<const float4*>(&A[(size_t)(row0 + am) * K + k0 + ak]);
    As[ak + 0][am] = av.x; As[ak + 1][am] = av.y; As[ak + 2][am] = av.z; As[ak + 3][am] = av.w;
    float4 bv = *reinterpret_cast<const float4*>(&W[(size_t)(k0 + bk) * N + col0 + bc]);
    *reinterpret_cast<float4*>(&Bs[bk][bc]) = bv;
    __syncthreads();
    #pragma unroll
    for (int kk = 0; kk < 16; ++kk) {
      float4 a4 = *reinterpret_cast<const float4*>(&As[kk][ty * 4]);
      float4 b4 = *reinterpret_cast<const float4*>(&Bs[kk][tx * 4]);
      float a[4] = {a4.x, a4.y, a4.z, a4.w};
      float b[4] = {b4.x, b4.y, b4.z, b4.w};
      #pragma unroll
      for (int i = 0; i < 4; ++i)
        #pragma unroll
        for (int j = 0; j < 4; ++j) acc[i][j] += a[i] * b[j];
    }
    __syncthreads();
  }
  int cbase = col0 + tx * 4;
  float bb[4] = {0.f, 0.f, 0.f, 0.f};
  if (bias) {
    float4 b4 = *reinterpret_cast<const float4*>(&bias[cbase]);
    bb[0] = b4.x; bb[1] = b4.y; bb[2] = b4.z; bb[3] = b4.w;
  }
  #pragma unroll
  for (int i = 0; i < 4; ++i) {
    int row = row0 + ty * 4 + i;
    float v[4];
    #pragma unroll
    for (int j = 0; j < 4; ++j) v[j] = acc[i][j] + bb[j];
    if (posmod) {
      int pos = row % posmod;
      #pragma unroll
      for (int pp = 0; pp < 2; ++pp) {
        int d = (cbase + pp * 2) & 63;
        int j = d >> 1;
        float c = rc[(size_t)pos * 32 + j], s = rs[(size_t)pos * 32 + j];
        float x0 = v[2 * pp], x1 = v[2 * pp + 1];
        v[2 * pp] = x0 * c - x1 * s;
        v[2 * pp + 1] = x0 * s + x1 * c;
      }
    }
    float4* outp = reinterpret_cast<float4*>(&C[(size_t)row * N + cbase]);
    float4 res = make_float4(v[0], v[1], v[2], v[3]);
    if (addC) {
      float4 old = *outp;
      res.x += old.x; res.y += old.y; res.z += old.z; res.w += old.w;
    }
    *outp = res;
  }
}

// ---------------- fused MLP-in: H = silu(A@Wg) * (A@Wv), W row-stride 4096 ----------------
__global__ __launch_bounds__(256) void mlp_in_k(const float* __restrict__ A,
                                                const float* __restrict__ W,
                                                float* __restrict__ Hout) {
  __shared__ float As[16][68];
  __shared__ float Bg[16][68];
  __shared__ float Bv[16][68];
  const int K = 512, NW = 4096, NH = 2048;
  int tid = threadIdx.x;
  int row0 = blockIdx.y * 64, col0 = blockIdx.x * 64;
  int tx = tid & 15, ty = tid >> 4;
  int am = tid >> 2, ak = (tid & 3) * 4;
  int bk = tid >> 4, bc = (tid & 15) * 4;
  float accg[4][4] = {};
  float accv[4][4] = {};
  for (int k0 = 0; k0 < K; k0 += 16) {
    float4 av = *reinterpret_cast<const float4*>(&A[(size_t)(row0 + am) * K + k0 + ak]);
    As[ak + 0][am] = av.x; As[ak + 1][am] = av.y; As[ak + 2][am] = av.z; As[ak + 3][am] = av.w;
    float4 g4 = *reinterpret_cast<const float4*>(&W[(size_t)(k0 + bk) * NW + col0 + bc]);
    float4 v4 = *reinterpret_cast<const float4*>(&W[(size_t)(k0 + bk) * NW + 2048 + col0 + bc]);
    *reinterpret_cast<float4*>(&Bg[bk][bc]) = g4;
    *reinterpret_cast<float4*>(&Bv[bk][bc]) = v4;
    __syncthreads();
    #pragma unroll
    for (int kk = 0; kk < 16; ++kk) {
      float4 a4 = *reinterpret_cast<const float4*>(&As[kk][ty * 4]);
      float4 bg = *reinterpret_cast<const float4*>(&Bg[kk][tx * 4]);
      float4 bvv = *reinterpret_cast<const float4*>(&Bv[kk][tx * 4]);
      float a[4] = {a4.x, a4.y, a4.z, a4.w};
      float g[4] = {bg.x, bg.y, bg.z, bg.w};
      float v[4] = {bvv.x, bvv.y, bvv.z, bvv.w};
      #pragma unroll
      for (int i = 0; i < 4; ++i)
        #pragma unroll
        for (int j = 0; j < 4; ++j) {
          accg[i][j] += a[i] * g[j];
          accv[i][j] += a[i] * v[j];
        }
    }
    __syncthreads();
  }
  #pragma unroll
  for (int i = 0; i < 4; ++i) {
    int row = row0 + ty * 4 + i;
    float v[4];
    #pragma unroll
    for (int j = 0; j < 4; ++j) {
      float g = accg[i][j];
      float sg = g / (1.f + __expf(-g));
      v[j] = sg * accv[i][j];
    }
    *reinterpret_cast<float4*>(&Hout[(size_t)row * NH + col0 + tx * 4]) =
        make_float4(v[0], v[1], v[2], v[3]);
  }
}

// ---------------- rmsnorm rows (linear rows) ----------------
__global__ __launch_bounds__(128) void rmsnorm_rows_k(const float* __restrict__ in,
                                                      const float* __restrict__ scale,
                                                      float* __restrict__ out) {
  int row = blockIdx.x;
  int tid = threadIdx.x;
  float4 v = *reinterpret_cast<const float4*>(&in[(size_t)row * D_ + tid * 4]);
  float ss = v.x * v.x + v.y * v.y + v.z * v.z + v.w * v.w;
  ss = wave_sum_f(ss);
  __shared__ float red[2];
  if ((tid & 63) == 0) red[tid >> 6] = ss;
  __syncthreads();
  ss = red[0] + red[1];
  float inv = 1.0f / sqrtf(ss / (float)D_ + 1e-6f);
  float4 sc = *reinterpret_cast<const float4*>(&scale[tid * 4]);
  float4 o = make_float4(v.x * inv * sc.x, v.y * inv * sc.y, v.z * inv * sc.z, v.w * inv * sc.w);
  *reinterpret_cast<float4*>(&out[(size_t)row * D_ + tid * 4]) = o;
}

// ---------------- mem rows: rmsnorm(tmp row b*O+o) -> kv row b*TK+o ----------------
__global__ __launch_bounds__(128) void memnorm_k(const float* __restrict__ tmp,
                                                 const float* __restrict__ scale,
                                                 float* __restrict__ kv) {
  int o = blockIdx.x, b = blockIdx.y;
  int tid = threadIdx.x;
  float4 v = *reinterpret_cast<const float4*>(&tmp[(size_t)(b * O_ + o) * D_ + tid * 4]);
  float ss = v.x * v.x + v.y * v.y + v.z * v.z + v.w * v.w;
  ss = wave_sum_f(ss);
  __shared__ float red[2];
  if ((tid & 63) == 0) red[tid >> 6] = ss;
  __syncthreads();
  ss = red[0] + red[1];
  float inv = 1.0f / sqrtf(ss / (float)D_ + 1e-6f);
  float4 sc = *reinterpret_cast<const float4*>(&scale[tid * 4]);
  float4 oo = make_float4(v.x * inv * sc.x, v.y * inv * sc.y, v.z * inv * sc.z, v.w * inv * sc.w);
  *reinterpret_cast<float4*>(&kv[(size_t)(b * TK_ + o) * D_ + tid * 4]) = oo;
}

// ---------------- engram rows -> kv[b, O+t, :] ----------------
__global__ __launch_bounds__(128) void engram_k(const int* __restrict__ tokens,
                                                const int* __restrict__ mem_ids,
                                                const float* __restrict__ etab,
                                                const float* __restrict__ egate,
                                                const float* __restrict__ escale,
                                                float* __restrict__ kv) {
  int t = blockIdx.x, b = blockIdx.y;
  int tid = threadIdx.x;
  unsigned int toks[4];
  #pragma unroll
  for (int i = 0; i < 4; ++i) {
    int idx = t - i;
    toks[i] = (idx >= 0) ? (unsigned int)tokens[b * T_ + idx]
                         : (unsigned int)mem_ids[b * O_ + O_ + idx];
  }
  int c = tid * 4;         // 0..508
  int h = c >> 7;          // head 0..3
  int e = c & 127;
  unsigned int hs = 0;
  #pragma unroll
  for (int i = 0; i < 4; ++i) hs += toks[i] * PRIMES_[h][i];
  int idxh = (int)(hs % (unsigned int)MM_);
  float4 r = *reinterpret_cast<const float4*>(&etab[((size_t)idxh * EH_ + h) * EHD_ + e]);
  float4 g = *reinterpret_cast<const float4*>(&egate[h * EHD_ + e]);
  float4 val;
  val.x = r.x / (1.f + __expf(-g.x));
  val.y = r.y / (1.f + __expf(-g.y));
  val.z = r.z / (1.f + __expf(-g.z));
  val.w = r.w / (1.f + __expf(-g.w));
  float ss = val.x * val.x + val.y * val.y + val.z * val.z + val.w * val.w;
  ss = wave_sum_f(ss);
  __shared__ float red[2];
  if ((tid & 63) == 0) red[tid >> 6] = ss;
  __syncthreads();
  ss = red[0] + red[1];
  float inv = 1.0f / sqrtf(ss / (float)D_ + 1e-6f);
  float4 sc = *reinterpret_cast<const float4*>(&escale[c]);
  float4 oo = make_float4(val.x * inv * sc.x, val.y * inv * sc.y, val.z * inv * sc.z,
                          val.w * inv * sc.w);
  *reinterpret_cast<float4*>(&kv[(size_t)(b * TK_ + O_ + t) * D_ + c]) = oo;
}

// ---------------- embed + ssum inject -> cx and kv[b, O+T+t, :] ----------------
__global__ __launch_bounds__(128) void embed_k(const int* __restrict__ tokens,
                                               const float* __restrict__ etab,
                                               const float* __restrict__ ssp,
                                               const float* __restrict__ alpha_g,
                                               float* __restrict__ cx,
                                               float* __restrict__ kv) {
  int t = blockIdx.x, b = blockIdx.y;
  int tid = threadIdx.x;
  int c = tid * 4;
  int tok = tokens[b * T_ + t];
  float4 e = *reinterpret_cast<const float4*>(&etab[(size_t)tok * D_ + c]);
  float4 sp = *reinterpret_cast<const float4*>(&ssp[b * D_ + c]);
  float4 ag = *reinterpret_cast<const float4*>(&alpha_g[c]);
  float4 x;
  x.x = e.x + sp.x / (1.f + __expf(-ag.x));
  x.y = e.y + sp.y / (1.f + __expf(-ag.y));
  x.z = e.z + sp.z / (1.f + __expf(-ag.z));
  x.w = e.w + sp.w / (1.f + __expf(-ag.w));
  *reinterpret_cast<float4*>(&cx[(size_t)(b * T_ + t) * D_ + c]) = x;
  *reinterpret_cast<float4*>(&kv[(size_t)(b * TK_ + O_ + T_ + t) * D_ + c]) = x;
}

// ---------------- flash attention (f32): 16 queries/block, 4 waves x 4 queries ----------------
__global__ __launch_bounds__(256) void attn_k(const float* __restrict__ qb,
                                              const float* __restrict__ kb,
                                              const float* __restrict__ vb,
                                              const int* __restrict__ tokens,
                                              float* __restrict__ ob) {
  __shared__ float Ks[64][68];
  __shared__ float VsT[64][68]; // [d][k]
  __shared__ float Qs[16][68];
  __shared__ float Ps[16][68];
  int b = blockIdx.z, h = blockIdx.y;
  int qt0 = blockIdx.x * 16;
  int tid = threadIdx.x;
  int wid = tid >> 6, lane = tid & 63;

  {
    int qi = tid >> 4;
    int c0 = (tid & 15) * 4;
    float4 qv = *reinterpret_cast<const float4*>(
        &qb[((size_t)(b * T_) + qt0 + qi) * D_ + h * 64 + c0]);
    *reinterpret_cast<float4*>(&Qs[qi][c0]) = qv;
  }
  float m[4], lsum[4], acc[4];
  #pragma unroll
  for (int p = 0; p < 4; ++p) { m[p] = -3e38f; lsum[p] = 0.f; acc[p] = 0.f; }

  for (int kc = 0; kc < TK_ / 64; ++kc) {
    int pos0 = kc * 64;
    __syncthreads();
    {
      int r = tid >> 2;
      int c0 = (tid & 3) * 16;
      const float* kg = &kb[((size_t)(b * TK_) + pos0 + r) * D_ + h * 64 + c0];
      const float* vg = &vb[((size_t)(b * TK_) + pos0 + r) * D_ + h * 64 + c0];
      #pragma unroll
      for (int j = 0; j < 4; ++j) {
        float4 k4 = *reinterpret_cast<const float4*>(kg + j * 4);
        *reinterpret_cast<float4*>(&Ks[r][c0 + j * 4]) = k4;
        float4 v4 = *reinterpret_cast<const float4*>(vg + j * 4);
        VsT[c0 + j * 4 + 0][r] = v4.x;
        VsT[c0 + j * 4 + 1][r] = v4.y;
        VsT[c0 + j * 4 + 2][r] = v4.z;
        VsT[c0 + j * 4 + 3][r] = v4.w;
      }
    }
    __syncthreads();
    #pragma unroll
    for (int p = 0; p < 4; ++p) {
      int ql = wid * 4 + p;
      int tq = qt0 + ql;
      float s = 0.f;
      #pragma unroll
      for (int d0 = 0; d0 < 64; d0 += 4) {
        float4 k4 = *reinterpret_cast<const float4*>(&Ks[lane][d0]);
        float4 q4 = *reinterpret_cast<const float4*>(&Qs[ql][d0]);
        s += k4.x * q4.x + k4.y * q4.y + k4.z * q4.z + k4.w * q4.w;
      }
      s *= 0.125f;
      int kp = pos0 + lane;
      bool valid = true;
      if (kp >= O_) {
        int tk = kp - O_;
        if (tk >= T_) tk -= T_;
        valid = (tk <= tq) && (tokens[b * T_ + tk] != 0);
      }
      if (!valid) s = -1e30f;
      float sm = wave_max_f(s);
      float mn = fmaxf(m[p], sm);
      float alpha = __expf(m[p] - mn);
      float pe = __expf(s - mn);
      float ps = wave_sum_f(pe);
      lsum[p] = lsum[p] * alpha + ps;
      m[p] = mn;
      acc[p] *= alpha;
      Ps[ql][lane] = pe;
      float a = 0.f;
      #pragma unroll
      for (int k0 = 0; k0 < 64; k0 += 4) {
        float4 v4 = *reinterpret_cast<const float4*>(&VsT[lane][k0]);
        float4 p4 = *reinterpret_cast<const float4*>(&Ps[ql][k0]);
        a += v4.x * p4.x + v4.y * p4.y + v4.z * p4.z + v4.w * p4.w;
      }
      acc[p] += a;
    }
  }
  #pragma unroll
  for (int p = 0; p < 4; ++p) {
    int tq = qt0 + wid * 4 + p;
    ob[((size_t)(b * T_) + tq) * D_ + h * 64 + lane] = acc[p] / lsum[p];
  }
}

extern "C" void kernel_launch(void* const* d_in, const int* in_sizes, int n_in,
                              void* d_out, int out_size, void* d_ws, size_t ws_size,
                              hipStream_t stream) {
  (void)in_sizes; (void)n_in; (void)out_size; (void)ws_size;
  const int* tokens = (const int*)d_in[0];
  const int* mem_ids = (const int*)d_in[1];
  const float* mem_emb = (const float*)d_in[2];
  const float* ssum = (const float*)d_in[3];
  const float* embed = (const float*)d_in[4];
  const float* engram_t = (const float*)d_in[5];
  const float* engram_g = (const float*)d_in[6];
  const float* engram_s = (const float*)d_in[7];
  const float* mem_W = (const float*)d_in[8];
  const float* mem_b = (const float*)d_in[9];
  const float* mem_s = (const float*)d_in[10];
  const float* alpha_g = (const float*)d_in[11];
  const float* ssum_W = (const float*)d_in[12];
  const float* ln1 = (const float*)d_in[13];
  const float* qW = (const float*)d_in[14];
  const float* qbias = (const float*)d_in[15];
  const float* kW = (const float*)d_in[16];
  const float* kbias = (const float*)d_in[17];
  const float* vW = (const float*)d_in[18];
  const float* vbias = (const float*)d_in[19];
  const float* oW = (const float*)d_in[20];
  const float* obias = (const float*)d_in[21];
  const float* ln2 = (const float*)d_in[22];
  const float* w_in = (const float*)d_in[23];
  const float* w_out = (const float*)d_in[24];
  const float* final_s = (const float*)d_in[25];

  float* ws = (float*)d_ws;
  size_t off = 0;
  float* kv = ws + off;   off += (size_t)B_ * TK_ * D_;
  float* cx = ws + off;   off += (size_t)B_ * T_ * D_;
  float* nx = ws + off;   off += (size_t)B_ * T_ * D_;
  float* qb = ws + off;   off += (size_t)B_ * T_ * D_;
  float* kb = ws + off;   off += (size_t)B_ * TK_ * D_;
  float* vb = ws + off;   off += (size_t)B_ * TK_ * D_;
  float* ob = ws + off;   off += (size_t)B_ * T_ * D_;
  float* ssp = ws + off;  off += (size_t)B_ * D_;
  float* rc = ws + off;   off += (size_t)TK_ * 32;
  float* rs = ws + off;   off += (size_t)TK_ * 32;
  float* hb = kb; // alias: MLP hidden (B*T*2048) over kb+vb (no longer needed then)

  // preamble
  rope_table_k<<<TK_, 32, 0, stream>>>(rc, rs);
  ssum_proj_k<<<dim3(2, B_), 256, 0, stream>>>(ssum, ssum_W, ssp);
  sgemm_k<<<dim3(8, 8), 256, 0, stream>>>(mem_emb, mem_W, mem_b, qb, B_ * O_, D_, D_, 0, 0,
                                          nullptr, nullptr);
  memnorm_k<<<dim3(O_, B_), 128, 0, stream>>>(qb, mem_s, kv);
  engram_k<<<dim3(T_, B_), 128, 0, stream>>>(tokens, mem_ids, engram_t, engram_g, engram_s, kv);
  embed_k<<<dim3(T_, B_), 128, 0, stream>>>(tokens, embed, ssp, alpha_g, cx, kv);

  for (int l = 0; l < L_; ++l) {
    const float* qWl = qW + (size_t)l * D_ * D_;
    const float* kWl = kW + (size_t)l * D_ * D_;
    const float* vWl = vW + (size_t)l * D_ * D_;
    const float* oWl = oW + (size_t)l * D_ * D_;
    const float* wil = w_in + (size_t)l * D_ * 8 * D_;
    const float* wol = w_out + (size_t)l * 4 * D_ * D_;

    rmsnorm_rows_k<<<B_ * T_, 128, 0, stream>>>(cx, ln1 + l * D_, nx);
    sgemm_k<<<dim3(8, 64), 256, 0, stream>>>(nx, qWl, qbias + l * D_, qb, B_ * T_, D_, D_, 0,
                                             T_, rc, rs);
    sgemm_k<<<dim3(8, 136), 256, 0, stream>>>(kv, kWl, kbias + l * D_, kb, B_ * TK_, D_, D_, 0,
                                              TK_, rc, rs);
    sgemm_k<<<dim3(8, 136), 256, 0, stream>>>(kv, vWl, vbias + l * D_, vb, B_ * TK_, D_, D_, 0,
                                              0, nullptr, nullptr);
    attn_k<<<dim3(T_ / 16, H_, B_), 256, 0, stream>>>(qb, kb, vb, tokens, ob);
    sgemm_k<<<dim3(8, 64), 256, 0, stream>>>(ob, oWl, obias + l * D_, cx, B_ * T_, D_, D_, 1,
                                             0, nullptr, nullptr);
    rmsnorm_rows_k<<<B_ * T_, 128, 0, stream>>>(cx, ln2 + l * D_, nx);
    mlp_in_k<<<dim3(32, 64), 256, 0, stream>>>(nx, wil, hb);
    sgemm_k<<<dim3(8, 64), 256, 0, stream>>>(hb, wol, nullptr, cx, B_ * T_, D_, 4 * D_, 1,
                                             0, nullptr, nullptr);
  }
  rmsnorm_rows_k<<<B_ * T_, 128, 0, stream>>>(cx, final_s, (float*)d_out);
}

// Round 2
// 4328.954 us; speedup vs baseline: 3.0485x; 3.0485x over previous
//
#include <hip/hip_runtime.h>
#include <hip/hip_bf16.h>
#include <math.h>

#define B_ 4
#define T_ 1024
#define O_ 128
#define D_ 512
#define H_ 8
#define L_ 6
#define TK_ 2176
#define MM_ 100000
#define EH_ 4
#define EHD_ 128
#define HD_ 64

typedef float f32x4 __attribute__((ext_vector_type(4)));
typedef short bf16x8 __attribute__((ext_vector_type(8)));

// PRIMES computed per reference: base=131, x=base+h*1009; row[i]=x; x=x*31+1 (uint32 wrap)
__device__ __constant__ unsigned int PRIMES_[4][4] = {
  {131u,  4062u,  125923u, 3903614u},
  {1140u, 35341u, 1095572u, 33962733u},
  {2149u, 66620u, 2065221u, 64021852u},
  {3158u, 97899u, 3034870u, 94080971u},
};

__device__ __forceinline__ float wave_sum_f(float v) {
  #pragma unroll
  for (int off = 32; off; off >>= 1) v += __shfl_xor(v, off);
  return v;
}

__device__ __forceinline__ short f2bf(float f) {
  unsigned int u = __float_as_uint(f);
  unsigned int r = (u + 0x7fffu + ((u >> 16) & 1u)) >> 16;
  return (short)r;
}

// ---------------- rope tables: cos/sin [TK][32] ----------------
__global__ void rope_table_k(float* __restrict__ rc, float* __restrict__ rs) {
  int t = blockIdx.x;
  int j = threadIdx.x; // 0..31
  float freq = __powf(10000.0f, -(float)j / 32.0f);
  float ang = (float)t * freq;
  rc[t * 32 + j] = cosf(ang);
  rs[t * 32 + j] = sinf(ang);
}

// ---------------- ssum @ ssum_W -> ssp[B][D] ----------------
__global__ __launch_bounds__(256) void ssum_proj_k(const float* __restrict__ ssum,
                                                   const float* __restrict__ sW,
                                                   float* __restrict__ ssp) {
  int col = blockIdx.x * 256 + threadIdx.x;
  int b = blockIdx.y;
  float acc = 0.f;
  for (int d = 0; d < D_; ++d) acc += ssum[b * D_ + d] * sW[(size_t)d * D_ + col];
  ssp[b * D_ + col] = acc;
}

// ---------------- generic tiled f32 GEMM: C = [C +] A@W + bias, optional fused RoPE ----------------
__global__ __launch_bounds__(256) void sgemm_k(const float* __restrict__ A,
                                               const float* __restrict__ W,
                                               const float* __restrict__ bias,
                                               float* __restrict__ C,
                                               int M, int N, int K,
                                               int addC, int posmod,
                                               const float* __restrict__ rc,
                                               const float* __restrict__ rs) {
  __shared__ float As[16][68];
  __shared__ float Bs[16][68];
  int tid = threadIdx.x;
  int row0 = blockIdx.y * 64;
  int col0 = blockIdx.x * 64;
  int tx = tid & 15, ty = tid >> 4;
  int am = tid >> 2, ak = (tid & 3) * 4;
  int bk = tid >> 4, bc = (tid & 15) * 4;
  float acc[4][4] = {};
  for (int k0 = 0; k0 < K; k0 += 16) {
    float4 av = *reinterpret_cast<const float4*>(&A[(size_t)(row0 + am) * K + k0 + ak]);
    As[ak + 0][am] = av.x; As[ak + 1][am] = av.y; As[ak + 2][am] = av.z; As[ak + 3][am] = av.w;
    float4 bv = *reinterpret_cast<const float4*>(&W[(size_t)(k0 + bk) * N + col0 + bc]);
    *reinterpret_cast<float4*>(&Bs[bk][bc]) = bv;
    __syncthreads();
    #pragma unroll
    for (int kk = 0; kk < 16; ++kk) {
      float4 a4 = *reinterpret_cast<const float4*>(&As[kk][ty * 4]);
      float4 b4 = *reinterpret_cast<const float4*>(&Bs[kk][tx * 4]);
      float a[4] = {a4.x, a4.y, a4.z, a4.w};
      float b[4] = {b4.x, b4.y, b4.z, b4.w};
      #pragma unroll
      for (int i = 0; i < 4; ++i)
        #pragma unroll
        for (int j = 0; j < 4; ++j) acc[i][j] += a[i] * b[j];
    }
    __syncthreads();
  }
  int cbase = col0 + tx * 4;
  float bb[4] = {0.f, 0.f, 0.f, 0.f};
  if (bias) {
    float4 b4 = *reinterpret_cast<const float4*>(&bias[cbase]);
    bb[0] = b4.x; bb[1] = b4.y; bb[2] = b4.z; bb[3] = b4.w;
  }
  #pragma unroll
  for (int i = 0; i < 4; ++i) {
    int row = row0 + ty * 4 + i;
    float v[4];
    #pragma unroll
    for (int j = 0; j < 4; ++j) v[j] = acc[i][j] + bb[j];
    if (posmod) {
      int pos = row % posmod;
      #pragma unroll
      for (int pp = 0; pp < 2; ++pp) {
        int d = (cbase + pp * 2) & 63;
        int j = d >> 1;
        float c = rc[(size_t)pos * 32 + j], s = rs[(size_t)pos * 32 + j];
        float x0 = v[2 * pp], x1 = v[2 * pp + 1];
        v[2 * pp] = x0 * c - x1 * s;
        v[2 * pp + 1] = x0 * s + x1 * c;
      }
    }
    float4* outp = reinterpret_cast<float4*>(&C[(size_t)row * N + cbase]);
    float4 res = make_float4(v[0], v[1], v[2], v[3]);
    if (addC) {
      float4 old = *outp;
      res.x += old.x; res.y += old.y; res.z += old.z; res.w += old.w;
    }
    *outp = res;
  }
}

// ---------------- fused MLP-in: H = silu(A@Wg) * (A@Wv), W row-stride 4096 ----------------
__global__ __launch_bounds__(256) void mlp_in_k(const float* __restrict__ A,
                                                const float* __restrict__ W,
                                                float* __restrict__ Hout) {
  __shared__ float As[16][68];
  __shared__ float Bg[16][68];
  __shared__ float Bv[16][68];
  const int K = 512, NW = 4096, NH = 2048;
  int tid = threadIdx.x;
  int row0 = blockIdx.y * 64, col0 = blockIdx.x * 64;
  int tx = tid & 15, ty = tid >> 4;
  int am = tid >> 2, ak = (tid & 3) * 4;
  int bk = tid >> 4, bc = (tid & 15) * 4;
  float accg[4][4] = {};
  float accv[4][4] = {};
  for (int k0 = 0; k0 < K; k0 += 16) {
    float4 av = *reinterpret_cast<const float4*>(&A[(size_t)(row0 + am) * K + k0 + ak]);
    As[ak + 0][am] = av.x; As[ak + 1][am] = av.y; As[ak + 2][am] = av.z; As[ak + 3][am] = av.w;
    float4 g4 = *reinterpret_cast<const float4*>(&W[(size_t)(k0 + bk) * NW + col0 + bc]);
    float4 v4 = *reinterpret_cast<const float4*>(&W[(size_t)(k0 + bk) * NW + 2048 + col0 + bc]);
    *reinterpret_cast<float4*>(&Bg[bk][bc]) = g4;
    *reinterpret_cast<float4*>(&Bv[bk][bc]) = v4;
    __syncthreads();
    #pragma unroll
    for (int kk = 0; kk < 16; ++kk) {
      float4 a4 = *reinterpret_cast<const float4*>(&As[kk][ty * 4]);
      float4 bg = *reinterpret_cast<const float4*>(&Bg[kk][tx * 4]);
      float4 bvv = *reinterpret_cast<const float4*>(&Bv[kk][tx * 4]);
      float a[4] = {a4.x, a4.y, a4.z, a4.w};
      float g[4] = {bg.x, bg.y, bg.z, bg.w};
      float v[4] = {bvv.x, bvv.y, bvv.z, bvv.w};
      #pragma unroll
      for (int i = 0; i < 4; ++i)
        #pragma unroll
        for (int j = 0; j < 4; ++j) {
          accg[i][j] += a[i] * g[j];
          accv[i][j] += a[i] * v[j];
        }
    }
    __syncthreads();
  }
  #pragma unroll
  for (int i = 0; i < 4; ++i) {
    int row = row0 + ty * 4 + i;
    float v[4];
    #pragma unroll
    for (int j = 0; j < 4; ++j) {
      float g = accg[i][j];
      float sg = g / (1.f + __expf(-g));
      v[j] = sg * accv[i][j];
    }
    *reinterpret_cast<float4*>(&Hout[(size_t)row * NH + col0 + tx * 4]) =
        make_float4(v[0], v[1], v[2], v[3]);
  }
}

// ---------------- rmsnorm rows (linear rows) ----------------
__global__ __launch_bounds__(128) void rmsnorm_rows_k(const float* __restrict__ in,
                                                      const float* __restrict__ scale,
                                                      float* __restrict__ out) {
  int row = blockIdx.x;
  int tid = threadIdx.x;
  float4 v = *reinterpret_cast<const float4*>(&in[(size_t)row * D_ + tid * 4]);
  float ss = v.x * v.x + v.y * v.y + v.z * v.z + v.w * v.w;
  ss = wave_sum_f(ss);
  __shared__ float red[2];
  if ((tid & 63) == 0) red[tid >> 6] = ss;
  __syncthreads();
  ss = red[0] + red[1];
  float inv = 1.0f / sqrtf(ss / (float)D_ + 1e-6f);
  float4 sc = *reinterpret_cast<const float4*>(&scale[tid * 4]);
  float4 o = make_float4(v.x * inv * sc.x, v.y * inv * sc.y, v.z * inv * sc.z, v.w * inv * sc.w);
  *reinterpret_cast<float4*>(&out[(size_t)row * D_ + tid * 4]) = o;
}

// ---------------- mem rows: rmsnorm(tmp row b*O+o) -> kv row b*TK+o ----------------
__global__ __launch_bounds__(128) void memnorm_k(const float* __restrict__ tmp,
                                                 const float* __restrict__ scale,
                                                 float* __restrict__ kv) {
  int o = blockIdx.x, b = blockIdx.y;
  int tid = threadIdx.x;
  float4 v = *reinterpret_cast<const float4*>(&tmp[(size_t)(b * O_ + o) * D_ + tid * 4]);
  float ss = v.x * v.x + v.y * v.y + v.z * v.z + v.w * v.w;
  ss = wave_sum_f(ss);
  __shared__ float red[2];
  if ((tid & 63) == 0) red[tid >> 6] = ss;
  __syncthreads();
  ss = red[0] + red[1];
  float inv = 1.0f / sqrtf(ss / (float)D_ + 1e-6f);
  float4 sc = *reinterpret_cast<const float4*>(&scale[tid * 4]);
  float4 oo = make_float4(v.x * inv * sc.x, v.y * inv * sc.y, v.z * inv * sc.z, v.w * inv * sc.w);
  *reinterpret_cast<float4*>(&kv[(size_t)(b * TK_ + o) * D_ + tid * 4]) = oo;
}

// ---------------- engram rows -> kv[b, O+t, :] ----------------
__global__ __launch_bounds__(128) void engram_k(const int* __restrict__ tokens,
                                                const int* __restrict__ mem_ids,
                                                const float* __restrict__ etab,
                                                const float* __restrict__ egate,
                                                const float* __restrict__ escale,
                                                float* __restrict__ kv) {
  int t = blockIdx.x, b = blockIdx.y;
  int tid = threadIdx.x;
  unsigned int toks[4];
  #pragma unroll
  for (int i = 0; i < 4; ++i) {
    int idx = t - i;
    toks[i] = (idx >= 0) ? (unsigned int)tokens[b * T_ + idx]
                         : (unsigned int)mem_ids[b * O_ + O_ + idx];
  }
  int c = tid * 4;         // 0..508
  int h = c >> 7;          // head 0..3
  int e = c & 127;
  unsigned int hs = 0;
  #pragma unroll
  for (int i = 0; i < 4; ++i) hs += toks[i] * PRIMES_[h][i];
  int idxh = (int)(hs % (unsigned int)MM_);
  float4 r = *reinterpret_cast<const float4*>(&etab[((size_t)idxh * EH_ + h) * EHD_ + e]);
  float4 g = *reinterpret_cast<const float4*>(&egate[h * EHD_ + e]);
  float4 val;
  val.x = r.x / (1.f + __expf(-g.x));
  val.y = r.y / (1.f + __expf(-g.y));
  val.z = r.z / (1.f + __expf(-g.z));
  val.w = r.w / (1.f + __expf(-g.w));
  float ss = val.x * val.x + val.y * val.y + val.z * val.z + val.w * val.w;
  ss = wave_sum_f(ss);
  __shared__ float red[2];
  if ((tid & 63) == 0) red[tid >> 6] = ss;
  __syncthreads();
  ss = red[0] + red[1];
  float inv = 1.0f / sqrtf(ss / (float)D_ + 1e-6f);
  float4 sc = *reinterpret_cast<const float4*>(&escale[c]);
  float4 oo = make_float4(val.x * inv * sc.x, val.y * inv * sc.y, val.z * inv * sc.z,
                          val.w * inv * sc.w);
  *reinterpret_cast<float4*>(&kv[(size_t)(b * TK_ + O_ + t) * D_ + c]) = oo;
}

// ---------------- embed + ssum inject -> cx and kv[b, O+T+t, :] ----------------
__global__ __launch_bounds__(128) void embed_k(const int* __restrict__ tokens,
                                               const float* __restrict__ etab,
                                               const float* __restrict__ ssp,
                                               const float* __restrict__ alpha_g,
                                               float* __restrict__ cx,
                                               float* __restrict__ kv) {
  int t = blockIdx.x, b = blockIdx.y;
  int tid = threadIdx.x;
  int c = tid * 4;
  int tok = tokens[b * T_ + t];
  float4 e = *reinterpret_cast<const float4*>(&etab[(size_t)tok * D_ + c]);
  float4 sp = *reinterpret_cast<const float4*>(&ssp[b * D_ + c]);
  float4 ag = *reinterpret_cast<const float4*>(&alpha_g[c]);
  float4 x;
  x.x = e.x + sp.x / (1.f + __expf(-ag.x));
  x.y = e.y + sp.y / (1.f + __expf(-ag.y));
  x.z = e.z + sp.z / (1.f + __expf(-ag.z));
  x.w = e.w + sp.w / (1.f + __expf(-ag.w));
  *reinterpret_cast<float4*>(&cx[(size_t)(b * T_ + t) * D_ + c]) = x;
  *reinterpret_cast<float4*>(&kv[(size_t)(b * TK_ + O_ + T_ + t) * D_ + c]) = x;
}

// ---------------- MFMA flash attention: QBLK=64 (4 waves x 16 q rows), KVBLK=64 ----------------
// swizzled LDS index: row-major [r][c] bf16, 64 cols; byte ^= ((r&7)<<4) -> short idx xor ((r&7)<<3)
#define KIDX(r, c) (((r) << 6) + ((c) ^ (((r) & 7) << 3)))

__global__ __launch_bounds__(256) void attn_mfma_k(const float* __restrict__ qb,
                                                   const float* __restrict__ kb,
                                                   const float* __restrict__ vb,
                                                   const int* __restrict__ tokens,
                                                   float* __restrict__ ob) {
  __shared__ __align__(16) short ks[64 * 64];
  __shared__ __align__(16) short vst[64 * 64];   // transposed: [d][k]
  __shared__ __align__(16) short ps[4][16 * 64]; // per-wave P tile
  __shared__ unsigned char vtok[T_];
  int b = blockIdx.z, h = blockIdx.y;
  int qt0 = blockIdx.x * 64;
  int tid = threadIdx.x;
  int w = tid >> 6, lane = tid & 63;
  int lr = lane & 15;   // fragment row/col
  int lg = lane >> 4;   // fragment k-group
  int qw0 = qt0 + w * 16;

  for (int i = tid; i < T_; i += 256) vtok[i] = (tokens[b * T_ + i] != 0);

  // Q fragments (A-operand): lane holds row lr, d = step*32 + lg*8 .. +7
  bf16x8 aq[2];
  {
    const float* qp = &qb[((size_t)(b * T_) + qw0 + lr) * D_ + h * 64];
    #pragma unroll
    for (int s = 0; s < 2; ++s) {
      float4 f0 = *reinterpret_cast<const float4*>(qp + s * 32 + lg * 8);
      float4 f1 = *reinterpret_cast<const float4*>(qp + s * 32 + lg * 8 + 4);
      bf16x8 v;
      v[0] = f2bf(f0.x); v[1] = f2bf(f0.y); v[2] = f2bf(f0.z); v[3] = f2bf(f0.w);
      v[4] = f2bf(f1.x); v[5] = f2bf(f1.y); v[6] = f2bf(f1.z); v[7] = f2bf(f1.w);
      aq[s] = v;
    }
  }

  float m_[4], lsum[4];
  f32x4 od[4];
  #pragma unroll
  for (int r = 0; r < 4; ++r) { m_[r] = -1e30f; lsum[r] = 0.f; }
  #pragma unroll
  for (int dt = 0; dt < 4; ++dt) od[dt] = (f32x4){0.f, 0.f, 0.f, 0.f};

  int sr = tid >> 2;         // staging row 0..63
  int sc = (tid & 3) * 16;   // staging col base

  for (int tile = 0; tile < TK_ / 64; ++tile) {
    int pos0 = tile * 64;
    __syncthreads();
    {
      const float* kg = &kb[((size_t)(b * TK_) + pos0 + sr) * D_ + h * 64 + sc];
      const float* vg = &vb[((size_t)(b * TK_) + pos0 + sr) * D_ + h * 64 + sc];
      short tmp[16];
      #pragma unroll
      for (int j = 0; j < 4; ++j) {
        float4 f = *reinterpret_cast<const float4*>(kg + j * 4);
        tmp[j * 4 + 0] = f2bf(f.x); tmp[j * 4 + 1] = f2bf(f.y);
        tmp[j * 4 + 2] = f2bf(f.z); tmp[j * 4 + 3] = f2bf(f.w);
      }
      *reinterpret_cast<bf16x8*>(&ks[KIDX(sr, sc)]) = *reinterpret_cast<bf16x8*>(&tmp[0]);
      *reinterpret_cast<bf16x8*>(&ks[KIDX(sr, sc + 8)]) = *reinterpret_cast<bf16x8*>(&tmp[8]);
      #pragma unroll
      for (int j = 0; j < 4; ++j) {
        float4 f = *reinterpret_cast<const float4*>(vg + j * 4);
        int d0 = sc + j * 4;
        vst[KIDX(d0 + 0, sr)] = f2bf(f.x);
        vst[KIDX(d0 + 1, sr)] = f2bf(f.y);
        vst[KIDX(d0 + 2, sr)] = f2bf(f.z);
        vst[KIDX(d0 + 3, sr)] = f2bf(f.w);
      }
    }
    __syncthreads();

    // QK^T: S[16q x 64k] per wave, 4 key-subtiles
    float sv[4][4];
    #pragma unroll
    for (int kt = 0; kt < 4; ++kt) {
      bf16x8 bk0 = *reinterpret_cast<const bf16x8*>(&ks[KIDX(kt * 16 + lr, lg * 8)]);
      bf16x8 bk1 = *reinterpret_cast<const bf16x8*>(&ks[KIDX(kt * 16 + lr, 32 + lg * 8)]);
      f32x4 s = (f32x4){0.f, 0.f, 0.f, 0.f};
      s = __builtin_amdgcn_mfma_f32_16x16x32_bf16(aq[0], bk0, s, 0, 0, 0);
      s = __builtin_amdgcn_mfma_f32_16x16x32_bf16(aq[1], bk1, s, 0, 0, 0);
      int kp = pos0 + kt * 16 + lr;
      int tk = kp - O_;
      if (tk >= T_) tk -= T_;
      int tki = tk < 0 ? 0 : tk;
      bool memk = (kp < O_);
      bool tokv = memk ? true : (vtok[tki] != 0);
      #pragma unroll
      for (int r = 0; r < 4; ++r) {
        int tq = qw0 + lg * 4 + r;
        bool valid = memk || (tokv && tk <= tq);
        sv[kt][r] = valid ? s[r] * 0.125f : -1e30f;
      }
    }
    // online softmax per query row (row r lives in 16-lane group lg, reg r)
    float al[4], mnew[4], psum[4];
    #pragma unroll
    for (int r = 0; r < 4; ++r) {
      float t = fmaxf(fmaxf(sv[0][r], sv[1][r]), fmaxf(sv[2][r], sv[3][r]));
      t = fmaxf(t, __shfl_xor(t, 1)); t = fmaxf(t, __shfl_xor(t, 2));
      t = fmaxf(t, __shfl_xor(t, 4)); t = fmaxf(t, __shfl_xor(t, 8));
      mnew[r] = fmaxf(m_[r], t);
      al[r] = __expf(m_[r] - mnew[r]);
      m_[r] = mnew[r];
      psum[r] = 0.f;
    }
    short* psw = ps[w];
    #pragma unroll
    for (int kt = 0; kt < 4; ++kt) {
      #pragma unroll
      for (int r = 0; r < 4; ++r) {
        float pe = __expf(sv[kt][r] - mnew[r]);
        psum[r] += pe;
        psw[KIDX(lg * 4 + r, kt * 16 + lr)] = f2bf(pe);
      }
    }
    #pragma unroll
    for (int r = 0; r < 4; ++r) {
      float t = psum[r];
      t += __shfl_xor(t, 1); t += __shfl_xor(t, 2);
      t += __shfl_xor(t, 4); t += __shfl_xor(t, 8);
      lsum[r] = lsum[r] * al[r] + t;
    }
    #pragma unroll
    for (int dt = 0; dt < 4; ++dt) {
      f32x4 o = od[dt];
      o[0] *= al[0]; o[1] *= al[1]; o[2] *= al[2]; o[3] *= al[3];
      od[dt] = o;
    }
    // PV: A = P (lane: row lr, k = step*32+lg*8), B = V (lane: col lr -> d, k rows via vst)
    bf16x8 pa0 = *reinterpret_cast<const bf16x8*>(&psw[KIDX(lr, lg * 8)]);
    bf16x8 pa1 = *reinterpret_cast<const bf16x8*>(&psw[KIDX(lr, 32 + lg * 8)]);
    #pragma unroll
    for (int dt = 0; dt < 4; ++dt) {
      bf16x8 bv0 = *reinterpret_cast<const bf16x8*>(&vst[KIDX(dt * 16 + lr, lg * 8)]);
      bf16x8 bv1 = *reinterpret_cast<const bf16x8*>(&vst[KIDX(dt * 16 + lr, 32 + lg * 8)]);
      od[dt] = __builtin_amdgcn_mfma_f32_16x16x32_bf16(pa0, bv0, od[dt], 0, 0, 0);
      od[dt] = __builtin_amdgcn_mfma_f32_16x16x32_bf16(pa1, bv1, od[dt], 0, 0, 0);
    }
  }
  #pragma unroll
  for (int dt = 0; dt < 4; ++dt) {
    #pragma unroll
    for (int r = 0; r < 4; ++r) {
      int q = qw0 + lg * 4 + r;
      ob[((size_t)(b * T_) + q) * D_ + h * 64 + dt * 16 + lr] = od[dt][r] / lsum[r];
    }
  }
}

extern "C" void kernel_launch(void* const* d_in, const int* in_sizes, int n_in,
                              void* d_out, int out_size, void* d_ws, size_t ws_size,
                              hipStream_t stream) {
  (void)in_sizes; (void)n_in; (void)out_size; (void)ws_size;
  const int* tokens = (const int*)d_in[0];
  const int* mem_ids = (const int*)d_in[1];
  const float* mem_emb = (const float*)d_in[2];
  const float* ssum = (const float*)d_in[3];
  const float* embed = (const float*)d_in[4];
  const float* engram_t = (const float*)d_in[5];
  const float* engram_g = (const float*)d_in[6];
  const float* engram_s = (const float*)d_in[7];
  const float* mem_W = (const float*)d_in[8];
  const float* mem_b = (const float*)d_in[9];
  const float* mem_s = (const float*)d_in[10];
  const float* alpha_g = (const float*)d_in[11];
  const float* ssum_W = (const float*)d_in[12];
  const float* ln1 = (const float*)d_in[13];
  const float* qW = (const float*)d_in[14];
  const float* qbias = (const float*)d_in[15];
  const float* kW = (const float*)d_in[16];
  const float* kbias = (const float*)d_in[17];
  const float* vW = (const float*)d_in[18];
  const float* vbias = (const float*)d_in[19];
  const float* oW = (const float*)d_in[20];
  const float* obias = (const float*)d_in[21];
  const float* ln2 = (const float*)d_in[22];
  const float* w_in = (const float*)d_in[23];
  const float* w_out = (const float*)d_in[24];
  const float* final_s = (const float*)d_in[25];

  float* ws = (float*)d_ws;
  size_t off = 0;
  float* kv = ws + off;   off += (size_t)B_ * TK_ * D_;
  float* cx = ws + off;   off += (size_t)B_ * T_ * D_;
  float* nx = ws + off;   off += (size_t)B_ * T_ * D_;
  float* qb = ws + off;   off += (size_t)B_ * T_ * D_;
  float* kb = ws + off;   off += (size_t)B_ * TK_ * D_;
  float* vb = ws + off;   off += (size_t)B_ * TK_ * D_;
  float* ob = ws + off;   off += (size_t)B_ * T_ * D_;
  float* ssp = ws + off;  off += (size_t)B_ * D_;
  float* rc = ws + off;   off += (size_t)TK_ * 32;
  float* rs = ws + off;   off += (size_t)TK_ * 32;
  float* hb = kb; // alias: MLP hidden (B*T*2048) over kb+vb (no longer needed then)

  // preamble
  rope_table_k<<<TK_, 32, 0, stream>>>(rc, rs);
  ssum_proj_k<<<dim3(2, B_), 256, 0, stream>>>(ssum, ssum_W, ssp);
  sgemm_k<<<dim3(8, 8), 256, 0, stream>>>(mem_emb, mem_W, mem_b, qb, B_ * O_, D_, D_, 0, 0,
                                          nullptr, nullptr);
  memnorm_k<<<dim3(O_, B_), 128, 0, stream>>>(qb, mem_s, kv);
  engram_k<<<dim3(T_, B_), 128, 0, stream>>>(tokens, mem_ids, engram_t, engram_g, engram_s, kv);
  embed_k<<<dim3(T_, B_), 128, 0, stream>>>(tokens, embed, ssp, alpha_g, cx, kv);

  for (int l = 0; l < L_; ++l) {
    const float* qWl = qW + (size_t)l * D_ * D_;
    const float* kWl = kW + (size_t)l * D_ * D_;
    const float* vWl = vW + (size_t)l * D_ * D_;
    const float* oWl = oW + (size_t)l * D_ * D_;
    const float* wil = w_in + (size_t)l * D_ * 8 * D_;
    const float* wol = w_out + (size_t)l * 4 * D_ * D_;

    rmsnorm_rows_k<<<B_ * T_, 128, 0, stream>>>(cx, ln1 + l * D_, nx);
    sgemm_k<<<dim3(8, 64), 256, 0, stream>>>(nx, qWl, qbias + l * D_, qb, B_ * T_, D_, D_, 0,
                                             T_, rc, rs);
    sgemm_k<<<dim3(8, 136), 256, 0, stream>>>(kv, kWl, kbias + l * D_, kb, B_ * TK_, D_, D_, 0,
                                              TK_, rc, rs);
    sgemm_k<<<dim3(8, 136), 256, 0, stream>>>(kv, vWl, vbias + l * D_, vb, B_ * TK_, D_, D_, 0,
                                              0, nullptr, nullptr);
    attn_mfma_k<<<dim3(T_ / 64, H_, B_), 256, 0, stream>>>(qb, kb, vb, tokens, ob);
    sgemm_k<<<dim3(8, 64), 256, 0, stream>>>(ob, oWl, obias + l * D_, cx, B_ * T_, D_, D_, 1,
                                             0, nullptr, nullptr);
    rmsnorm_rows_k<<<B_ * T_, 128, 0, stream>>>(cx, ln2 + l * D_, nx);
    mlp_in_k<<<dim3(32, 64), 256, 0, stream>>>(nx, wil, hb);
    sgemm_k<<<dim3(8, 64), 256, 0, stream>>>(hb, wol, nullptr, cx, B_ * T_, D_, 4 * D_, 1,
                                             0, nullptr, nullptr);
  }
  rmsnorm_rows_k<<<B_ * T_, 128, 0, stream>>>(cx, final_s, (float*)d_out);
}

// Round 3
// 1694.493 us; speedup vs baseline: 7.7880x; 2.5547x over previous
//
#include <hip/hip_runtime.h>
#include <hip/hip_bf16.h>
#include <math.h>

#define B_ 4
#define T_ 1024
#define O_ 128
#define D_ 512
#define H_ 8
#define L_ 6
#define TK_ 2176
#define MM_ 100000
#define EH_ 4
#define EHD_ 128
#define HD_ 64

typedef float f32x4 __attribute__((ext_vector_type(4)));
typedef short bf16x8 __attribute__((ext_vector_type(8)));
typedef unsigned short u16;

// PRIMES per reference: base=131, x=base+h*1009; row[i]=x; x=x*31+1 (uint32 wrap)
__device__ __constant__ unsigned int PRIMES_[4][4] = {
  {131u,  4062u,  125923u, 3903614u},
  {1140u, 35341u, 1095572u, 33962733u},
  {2149u, 66620u, 2065221u, 64021852u},
  {3158u, 97899u, 3034870u, 94080971u},
};

__device__ __forceinline__ float wave_sum_f(float v) {
  #pragma unroll
  for (int off = 32; off; off >>= 1) v += __shfl_xor(v, off);
  return v;
}

__device__ __forceinline__ short f2bf(float f) {
  unsigned int u = __float_as_uint(f);
  unsigned int r = (u + 0x7fffu + ((u >> 16) & 1u)) >> 16;
  return (short)r;
}

__device__ __forceinline__ void gload16(const void* g, void* l) {
  __builtin_amdgcn_global_load_lds((const __attribute__((address_space(1))) void*)g,
                                   (__attribute__((address_space(3))) void*)l, 16, 0, 0);
}

// ---------------- rope tables: cos/sin [TK][32] ----------------
__global__ void rope_table_k(float* __restrict__ rc, float* __restrict__ rs) {
  int t = blockIdx.x;
  int j = threadIdx.x;
  float freq = __powf(10000.0f, -(float)j / 32.0f);
  float ang = (float)t * freq;
  rc[t * 32 + j] = cosf(ang);
  rs[t * 32 + j] = sinf(ang);
}

// ---------------- ssum @ ssum_W -> ssp[B][D] ----------------
__global__ __launch_bounds__(256) void ssum_proj_k(const float* __restrict__ ssum,
                                                   const float* __restrict__ sW,
                                                   float* __restrict__ ssp) {
  int col = blockIdx.x * 256 + threadIdx.x;
  int b = blockIdx.y;
  float acc = 0.f;
  for (int d = 0; d < D_; ++d) acc += ssum[b * D_ + d] * sW[(size_t)d * D_ + col];
  ssp[b * D_ + col] = acc;
}

// ---------------- f32 tiled GEMM (preamble mem projection only) ----------------
__global__ __launch_bounds__(256) void sgemm_k(const float* __restrict__ A,
                                               const float* __restrict__ W,
                                               const float* __restrict__ bias,
                                               float* __restrict__ C,
                                               int M, int N, int K) {
  __shared__ float As[16][68];
  __shared__ float Bs[16][68];
  int tid = threadIdx.x;
  int row0 = blockIdx.y * 64;
  int col0 = blockIdx.x * 64;
  int tx = tid & 15, ty = tid >> 4;
  int am = tid >> 2, ak = (tid & 3) * 4;
  int bk = tid >> 4, bc = (tid & 15) * 4;
  float acc[4][4] = {};
  for (int k0 = 0; k0 < K; k0 += 16) {
    float4 av = *reinterpret_cast<const float4*>(&A[(size_t)(row0 + am) * K + k0 + ak]);
    As[ak + 0][am] = av.x; As[ak + 1][am] = av.y; As[ak + 2][am] = av.z; As[ak + 3][am] = av.w;
    float4 bv = *reinterpret_cast<const float4*>(&W[(size_t)(k0 + bk) * N + col0 + bc]);
    *reinterpret_cast<float4*>(&Bs[bk][bc]) = bv;
    __syncthreads();
    #pragma unroll
    for (int kk = 0; kk < 16; ++kk) {
      float4 a4 = *reinterpret_cast<const float4*>(&As[kk][ty * 4]);
      float4 b4 = *reinterpret_cast<const float4*>(&Bs[kk][tx * 4]);
      float a[4] = {a4.x, a4.y, a4.z, a4.w};
      float b[4] = {b4.x, b4.y, b4.z, b4.w};
      #pragma unroll
      for (int i = 0; i < 4; ++i)
        #pragma unroll
        for (int j = 0; j < 4; ++j) acc[i][j] += a[i] * b[j];
    }
    __syncthreads();
  }
  int cbase = col0 + tx * 4;
  float4 b4 = *reinterpret_cast<const float4*>(&bias[cbase]);
  float bb[4] = {b4.x, b4.y, b4.z, b4.w};
  #pragma unroll
  for (int i = 0; i < 4; ++i) {
    int row = row0 + ty * 4 + i;
    *reinterpret_cast<float4*>(&C[(size_t)row * N + cbase]) =
        make_float4(acc[i][0] + bb[0], acc[i][1] + bb[1], acc[i][2] + bb[2], acc[i][3] + bb[3]);
  }
}

// ---------------- weight convert+transpose: W f32 [K][N] -> wT bf16 [N][K] ----------------
__global__ __launch_bounds__(256) void wconv_k(const float* __restrict__ W,
                                               u16* __restrict__ wT, int K, int N) {
  __shared__ float s[64][65];
  int n0 = blockIdx.x * 64, k0 = blockIdx.y * 64;
  int tid = threadIdx.x;
  int kr = tid >> 4, nc = (tid & 15) * 4;
  #pragma unroll
  for (int kk = 0; kk < 4; ++kk) {
    float4 f = *reinterpret_cast<const float4*>(&W[(size_t)(k0 + kr + kk * 16) * N + n0 + nc]);
    s[kr + kk * 16][nc + 0] = f.x; s[kr + kk * 16][nc + 1] = f.y;
    s[kr + kk * 16][nc + 2] = f.z; s[kr + kk * 16][nc + 3] = f.w;
  }
  __syncthreads();
  int nr = tid >> 4, kc = (tid & 15) * 4;
  #pragma unroll
  for (int nn = 0; nn < 4; ++nn) {
    int n = nr + nn * 16;
    ushort4 o;
    o.x = (u16)f2bf(s[kc + 0][n]); o.y = (u16)f2bf(s[kc + 1][n]);
    o.z = (u16)f2bf(s[kc + 2][n]); o.w = (u16)f2bf(s[kc + 3][n]);
    *reinterpret_cast<ushort4*>(&wT[(size_t)(n0 + n) * K + k0 + kc]) = o;
  }
}

// ---------------- MFMA GEMM: C = A@Bt^T (+bias) [+rope] or f32 += ----------------
// A bf16 [M][K], Bt bf16 [N][K]. 128x128 tile, BK=32, 4 waves (each 64x64).
// EPI: 0 = bf16 out (+opt bias), 1 = bf16 out + bias + rope, 2 = f32 += (+opt bias)
template<int EPI>
__global__ __launch_bounds__(256) void gemm_bf16_k(const u16* __restrict__ A,
                                                   const u16* __restrict__ Bt,
                                                   const float* __restrict__ bias,
                                                   void* __restrict__ Cout,
                                                   int M, int N, int K, int posmod,
                                                   const float* __restrict__ rc,
                                                   const float* __restrict__ rs) {
  __shared__ __align__(16) u16 As[2][128 * 32];
  __shared__ __align__(16) u16 Bs[2][128 * 32];
  int tid = threadIdx.x;
  int w = tid >> 6, lane = tid & 63;
  int lr = lane & 15, lg = lane >> 4;
  int row0 = blockIdx.y * 128, col0 = blockIdx.x * 128;
  int wr = w >> 1, wc = w & 1;
  f32x4 acc[4][4] = {};

  int srow = lane >> 2;          // row within 16-row chunk
  int skel = (lane & 3) * 8;     // k element within 32

  auto stage = [&](int buf, int k0) {
    #pragma unroll
    for (int ci = 0; ci < 2; ++ci) {
      int c = w * 2 + ci;
      gload16(A + (size_t)(row0 + c * 16 + srow) * K + k0 + skel, &As[buf][c * 512]);
      gload16(Bt + (size_t)(col0 + c * 16 + srow) * K + k0 + skel, &Bs[buf][c * 512]);
    }
  };

  stage(0, 0);
  __syncthreads();
  int nk = K >> 5;
  int buf = 0;
  for (int t = 0; t < nk; ++t) {
    if (t + 1 < nk) stage(buf ^ 1, (t + 1) * 32);
    bf16x8 af[4], bfr[4];
    #pragma unroll
    for (int i = 0; i < 4; ++i)
      af[i] = *reinterpret_cast<const bf16x8*>(&As[buf][(wr * 64 + i * 16 + lr) * 32 + lg * 8]);
    #pragma unroll
    for (int j = 0; j < 4; ++j)
      bfr[j] = *reinterpret_cast<const bf16x8*>(&Bs[buf][(wc * 64 + j * 16 + lr) * 32 + lg * 8]);
    #pragma unroll
    for (int i = 0; i < 4; ++i)
      #pragma unroll
      for (int j = 0; j < 4; ++j)
        acc[i][j] = __builtin_amdgcn_mfma_f32_16x16x32_bf16(af[i], bfr[j], acc[i][j], 0, 0, 0);
    __syncthreads();
    buf ^= 1;
  }

  #pragma unroll
  for (int j = 0; j < 4; ++j) {
    int col = col0 + wc * 64 + j * 16 + lr;
    float bs = bias ? bias[col] : 0.f;
    #pragma unroll
    for (int i = 0; i < 4; ++i) {
      #pragma unroll
      for (int r = 0; r < 4; ++r) {
        int row = row0 + wr * 64 + i * 16 + lg * 4 + r;
        float v = acc[i][j][r] + bs;
        if (EPI == 1) {
          int pos = row % posmod;
          int d = col & 63;
          float c = rc[(size_t)pos * 32 + (d >> 1)];
          float s = rs[(size_t)pos * 32 + (d >> 1)];
          float partner = __shfl_xor(v, 1);
          v = (d & 1) ? (partner * s + v * c) : (v * c - partner * s);
        }
        if (EPI == 2) {
          float* Cf = (float*)Cout;
          Cf[(size_t)row * N + col] += v;
        } else {
          u16* Cb = (u16*)Cout;
          Cb[(size_t)row * N + col] = (u16)f2bf(v);
        }
      }
    }
  }
}

// ---------------- fused MLP-in MFMA: H = silu(A@Wg^T) * (A@Wv^T), bf16 out ----------------
// A bf16 [M][512]; wiT bf16 [4096][512] (rows 0..2047 gate, 2048..4095 val).
// tile: 128 rows x 64 hidden cols. 4 waves: wave = 64 rows x 32 cols (g and v).
__global__ __launch_bounds__(256) void mlp_in_mfma_k(const u16* __restrict__ A,
                                                     const u16* __restrict__ wiT,
                                                     u16* __restrict__ Hout) {
  __shared__ __align__(16) u16 As[2][128 * 32];
  __shared__ __align__(16) u16 Bg[2][64 * 32];
  __shared__ __align__(16) u16 Bv[2][64 * 32];
  int tid = threadIdx.x;
  int w = tid >> 6, lane = tid & 63;
  int lr = lane & 15, lg = lane >> 4;
  int hc0 = blockIdx.x * 64, row0 = blockIdx.y * 128;
  int wr = w >> 1, wc = w & 1;
  f32x4 ag[4][2] = {};
  f32x4 av[4][2] = {};
  const int K = 512;

  int srow = lane >> 2;
  int skel = (lane & 3) * 8;

  auto stage = [&](int buf, int k0) {
    #pragma unroll
    for (int ci = 0; ci < 2; ++ci) {
      int c = w * 2 + ci;
      gload16(A + (size_t)(row0 + c * 16 + srow) * K + k0 + skel, &As[buf][c * 512]);
    }
    gload16(wiT + (size_t)(hc0 + w * 16 + srow) * K + k0 + skel, &Bg[buf][w * 512]);
    gload16(wiT + (size_t)(2048 + hc0 + w * 16 + srow) * K + k0 + skel, &Bv[buf][w * 512]);
  };

  stage(0, 0);
  __syncthreads();
  int buf = 0;
  for (int t = 0; t < 16; ++t) {
    if (t + 1 < 16) stage(buf ^ 1, (t + 1) * 32);
    bf16x8 af[4], bg[2], bv[2];
    #pragma unroll
    for (int i = 0; i < 4; ++i)
      af[i] = *reinterpret_cast<const bf16x8*>(&As[buf][(wr * 64 + i * 16 + lr) * 32 + lg * 8]);
    #pragma unroll
    for (int j = 0; j < 2; ++j) {
      bg[j] = *reinterpret_cast<const bf16x8*>(&Bg[buf][(wc * 32 + j * 16 + lr) * 32 + lg * 8]);
      bv[j] = *reinterpret_cast<const bf16x8*>(&Bv[buf][(wc * 32 + j * 16 + lr) * 32 + lg * 8]);
    }
    #pragma unroll
    for (int i = 0; i < 4; ++i)
      #pragma unroll
      for (int j = 0; j < 2; ++j) {
        ag[i][j] = __builtin_amdgcn_mfma_f32_16x16x32_bf16(af[i], bg[j], ag[i][j], 0, 0, 0);
        av[i][j] = __builtin_amdgcn_mfma_f32_16x16x32_bf16(af[i], bv[j], av[i][j], 0, 0, 0);
      }
    __syncthreads();
    buf ^= 1;
  }

  #pragma unroll
  for (int j = 0; j < 2; ++j) {
    int col = hc0 + wc * 32 + j * 16 + lr;
    #pragma unroll
    for (int i = 0; i < 4; ++i) {
      #pragma unroll
      for (int r = 0; r < 4; ++r) {
        int row = row0 + wr * 64 + i * 16 + lg * 4 + r;
        float g = ag[i][j][r];
        float sg = g / (1.f + __expf(-g));
        Hout[(size_t)row * 2048 + col] = (u16)f2bf(sg * av[i][j][r]);
      }
    }
  }
}

// ---------------- rmsnorm rows: f32 in -> bf16 (OUTBF=1) or f32 (OUTBF=0) out ----------------
template<int OUTBF>
__global__ __launch_bounds__(128) void rmsnorm_k(const float* __restrict__ in,
                                                 const float* __restrict__ scale,
                                                 void* __restrict__ out) {
  int row = blockIdx.x;
  int tid = threadIdx.x;
  float4 v = *reinterpret_cast<const float4*>(&in[(size_t)row * D_ + tid * 4]);
  float ss = v.x * v.x + v.y * v.y + v.z * v.z + v.w * v.w;
  ss = wave_sum_f(ss);
  __shared__ float red[2];
  if ((tid & 63) == 0) red[tid >> 6] = ss;
  __syncthreads();
  ss = red[0] + red[1];
  float inv = 1.0f / sqrtf(ss / (float)D_ + 1e-6f);
  float4 sc = *reinterpret_cast<const float4*>(&scale[tid * 4]);
  float o0 = v.x * inv * sc.x, o1 = v.y * inv * sc.y, o2 = v.z * inv * sc.z, o3 = v.w * inv * sc.w;
  if (OUTBF) {
    ushort4 o;
    o.x = (u16)f2bf(o0); o.y = (u16)f2bf(o1); o.z = (u16)f2bf(o2); o.w = (u16)f2bf(o3);
    *reinterpret_cast<ushort4*>((u16*)out + (size_t)row * D_ + tid * 4) = o;
  } else {
    *reinterpret_cast<float4*>((float*)out + (size_t)row * D_ + tid * 4) =
        make_float4(o0, o1, o2, o3);
  }
}

// ---------------- mem rows: rmsnorm(tmp row b*O+o) -> kv bf16 row b*TK+o ----------------
__global__ __launch_bounds__(128) void memnorm_k(const float* __restrict__ tmp,
                                                 const float* __restrict__ scale,
                                                 u16* __restrict__ kv) {
  int o = blockIdx.x, b = blockIdx.y;
  int tid = threadIdx.x;
  float4 v = *reinterpret_cast<const float4*>(&tmp[(size_t)(b * O_ + o) * D_ + tid * 4]);
  float ss = v.x * v.x + v.y * v.y + v.z * v.z + v.w * v.w;
  ss = wave_sum_f(ss);
  __shared__ float red[2];
  if ((tid & 63) == 0) red[tid >> 6] = ss;
  __syncthreads();
  ss = red[0] + red[1];
  float inv = 1.0f / sqrtf(ss / (float)D_ + 1e-6f);
  float4 sc = *reinterpret_cast<const float4*>(&scale[tid * 4]);
  ushort4 oo;
  oo.x = (u16)f2bf(v.x * inv * sc.x); oo.y = (u16)f2bf(v.y * inv * sc.y);
  oo.z = (u16)f2bf(v.z * inv * sc.z); oo.w = (u16)f2bf(v.w * inv * sc.w);
  *reinterpret_cast<ushort4*>(&kv[(size_t)(b * TK_ + o) * D_ + tid * 4]) = oo;
}

// ---------------- engram rows -> kv bf16 [b, O+t, :] ----------------
__global__ __launch_bounds__(128) void engram_k(const int* __restrict__ tokens,
                                                const int* __restrict__ mem_ids,
                                                const float* __restrict__ etab,
                                                const float* __restrict__ egate,
                                                const float* __restrict__ escale,
                                                u16* __restrict__ kv) {
  int t = blockIdx.x, b = blockIdx.y;
  int tid = threadIdx.x;
  unsigned int toks[4];
  #pragma unroll
  for (int i = 0; i < 4; ++i) {
    int idx = t - i;
    toks[i] = (idx >= 0) ? (unsigned int)tokens[b * T_ + idx]
                         : (unsigned int)mem_ids[b * O_ + O_ + idx];
  }
  int c = tid * 4;
  int h = c >> 7;
  int e = c & 127;
  unsigned int hs = 0;
  #pragma unroll
  for (int i = 0; i < 4; ++i) hs += toks[i] * PRIMES_[h][i];
  int idxh = (int)(hs % (unsigned int)MM_);
  float4 r = *reinterpret_cast<const float4*>(&etab[((size_t)idxh * EH_ + h) * EHD_ + e]);
  float4 g = *reinterpret_cast<const float4*>(&egate[h * EHD_ + e]);
  float4 val;
  val.x = r.x / (1.f + __expf(-g.x));
  val.y = r.y / (1.f + __expf(-g.y));
  val.z = r.z / (1.f + __expf(-g.z));
  val.w = r.w / (1.f + __expf(-g.w));
  float ss = val.x * val.x + val.y * val.y + val.z * val.z + val.w * val.w;
  ss = wave_sum_f(ss);
  __shared__ float red[2];
  if ((tid & 63) == 0) red[tid >> 6] = ss;
  __syncthreads();
  ss = red[0] + red[1];
  float inv = 1.0f / sqrtf(ss / (float)D_ + 1e-6f);
  float4 sc = *reinterpret_cast<const float4*>(&escale[c]);
  ushort4 oo;
  oo.x = (u16)f2bf(val.x * inv * sc.x); oo.y = (u16)f2bf(val.y * inv * sc.y);
  oo.z = (u16)f2bf(val.z * inv * sc.z); oo.w = (u16)f2bf(val.w * inv * sc.w);
  *reinterpret_cast<ushort4*>(&kv[(size_t)(b * TK_ + O_ + t) * D_ + c]) = oo;
}

// ---------------- embed + ssum inject -> cx f32 and kv bf16 [b, O+T+t, :] ----------------
__global__ __launch_bounds__(128) void embed_k(const int* __restrict__ tokens,
                                               const float* __restrict__ etab,
                                               const float* __restrict__ ssp,
                                               const float* __restrict__ alpha_g,
                                               float* __restrict__ cx,
                                               u16* __restrict__ kv) {
  int t = blockIdx.x, b = blockIdx.y;
  int tid = threadIdx.x;
  int c = tid * 4;
  int tok = tokens[b * T_ + t];
  float4 e = *reinterpret_cast<const float4*>(&etab[(size_t)tok * D_ + c]);
  float4 sp = *reinterpret_cast<const float4*>(&ssp[b * D_ + c]);
  float4 ag = *reinterpret_cast<const float4*>(&alpha_g[c]);
  float4 x;
  x.x = e.x + sp.x / (1.f + __expf(-ag.x));
  x.y = e.y + sp.y / (1.f + __expf(-ag.y));
  x.z = e.z + sp.z / (1.f + __expf(-ag.z));
  x.w = e.w + sp.w / (1.f + __expf(-ag.w));
  *reinterpret_cast<float4*>(&cx[(size_t)(b * T_ + t) * D_ + c]) = x;
  ushort4 oo;
  oo.x = (u16)f2bf(x.x); oo.y = (u16)f2bf(x.y);
  oo.z = (u16)f2bf(x.z); oo.w = (u16)f2bf(x.w);
  *reinterpret_cast<ushort4*>(&kv[(size_t)(b * TK_ + O_ + T_ + t) * D_ + c]) = oo;
}

// ---------------- MFMA flash attention (bf16 IO): QBLK=64, KVBLK=64 ----------------
#define KIDX(r, c) (((r) << 6) + ((c) ^ (((r) & 7) << 3)))

__global__ __launch_bounds__(256) void attn_mfma_k(const u16* __restrict__ qb,
                                                   const u16* __restrict__ kb,
                                                   const u16* __restrict__ vb,
                                                   const int* __restrict__ tokens,
                                                   u16* __restrict__ ob) {
  __shared__ __align__(16) short ks[64 * 64];
  __shared__ __align__(16) short vst[64 * 64];   // transposed: [d][k]
  __shared__ __align__(16) short ps[4][16 * 64]; // per-wave P tile
  __shared__ unsigned char vtok[T_];
  int b = blockIdx.z, h = blockIdx.y;
  int qt0 = blockIdx.x * 64;
  int tid = threadIdx.x;
  int w = tid >> 6, lane = tid & 63;
  int lr = lane & 15;
  int lg = lane >> 4;
  int qw0 = qt0 + w * 16;

  for (int i = tid; i < T_; i += 256) vtok[i] = (tokens[b * T_ + i] != 0);

  bf16x8 aq[2];
  {
    const u16* qp = &qb[((size_t)(b * T_) + qw0 + lr) * D_ + h * 64];
    aq[0] = *reinterpret_cast<const bf16x8*>(qp + lg * 8);
    aq[1] = *reinterpret_cast<const bf16x8*>(qp + 32 + lg * 8);
  }

  float m_[4], lsum[4];
  f32x4 od[4];
  #pragma unroll
  for (int r = 0; r < 4; ++r) { m_[r] = -1e30f; lsum[r] = 0.f; }
  #pragma unroll
  for (int dt = 0; dt < 4; ++dt) od[dt] = (f32x4){0.f, 0.f, 0.f, 0.f};

  int sr = tid >> 2;
  int sc = (tid & 3) * 16;

  for (int tile = 0; tile < TK_ / 64; ++tile) {
    int pos0 = tile * 64;
    __syncthreads();
    {
      const u16* kg = &kb[((size_t)(b * TK_) + pos0 + sr) * D_ + h * 64 + sc];
      const u16* vg = &vb[((size_t)(b * TK_) + pos0 + sr) * D_ + h * 64 + sc];
      bf16x8 k0 = *reinterpret_cast<const bf16x8*>(kg);
      bf16x8 k1 = *reinterpret_cast<const bf16x8*>(kg + 8);
      *reinterpret_cast<bf16x8*>(&ks[KIDX(sr, sc)]) = k0;
      *reinterpret_cast<bf16x8*>(&ks[KIDX(sr, sc + 8)]) = k1;
      bf16x8 v0 = *reinterpret_cast<const bf16x8*>(vg);
      bf16x8 v1 = *reinterpret_cast<const bf16x8*>(vg + 8);
      #pragma unroll
      for (int j = 0; j < 8; ++j) vst[KIDX(sc + j, sr)] = v0[j];
      #pragma unroll
      for (int j = 0; j < 8; ++j) vst[KIDX(sc + 8 + j, sr)] = v1[j];
    }
    __syncthreads();

    float sv[4][4];
    #pragma unroll
    for (int kt = 0; kt < 4; ++kt) {
      bf16x8 bk0 = *reinterpret_cast<const bf16x8*>(&ks[KIDX(kt * 16 + lr, lg * 8)]);
      bf16x8 bk1 = *reinterpret_cast<const bf16x8*>(&ks[KIDX(kt * 16 + lr, 32 + lg * 8)]);
      f32x4 s = (f32x4){0.f, 0.f, 0.f, 0.f};
      s = __builtin_amdgcn_mfma_f32_16x16x32_bf16(aq[0], bk0, s, 0, 0, 0);
      s = __builtin_amdgcn_mfma_f32_16x16x32_bf16(aq[1], bk1, s, 0, 0, 0);
      int kp = pos0 + kt * 16 + lr;
      int tk = kp - O_;
      if (tk >= T_) tk -= T_;
      int tki = tk < 0 ? 0 : tk;
      bool memk = (kp < O_);
      bool tokv = memk ? true : (vtok[tki] != 0);
      #pragma unroll
      for (int r = 0; r < 4; ++r) {
        int tq = qw0 + lg * 4 + r;
        bool valid = memk || (tokv && tk <= tq);
        sv[kt][r] = valid ? s[r] * 0.125f : -1e30f;
      }
    }
    float al[4], mnew[4], psum[4];
    #pragma unroll
    for (int r = 0; r < 4; ++r) {
      float t = fmaxf(fmaxf(sv[0][r], sv[1][r]), fmaxf(sv[2][r], sv[3][r]));
      t = fmaxf(t, __shfl_xor(t, 1)); t = fmaxf(t, __shfl_xor(t, 2));
      t = fmaxf(t, __shfl_xor(t, 4)); t = fmaxf(t, __shfl_xor(t, 8));
      mnew[r] = fmaxf(m_[r], t);
      al[r] = __expf(m_[r] - mnew[r]);
      m_[r] = mnew[r];
      psum[r] = 0.f;
    }
    short* psw = ps[w];
    #pragma unroll
    for (int kt = 0; kt < 4; ++kt) {
      #pragma unroll
      for (int r = 0; r < 4; ++r) {
        float pe = __expf(sv[kt][r] - mnew[r]);
        psum[r] += pe;
        psw[KIDX(lg * 4 + r, kt * 16 + lr)] = f2bf(pe);
      }
    }
    #pragma unroll
    for (int r = 0; r < 4; ++r) {
      float t = psum[r];
      t += __shfl_xor(t, 1); t += __shfl_xor(t, 2);
      t += __shfl_xor(t, 4); t += __shfl_xor(t, 8);
      lsum[r] = lsum[r] * al[r] + t;
    }
    #pragma unroll
    for (int dt = 0; dt < 4; ++dt) {
      f32x4 o = od[dt];
      o[0] *= al[0]; o[1] *= al[1]; o[2] *= al[2]; o[3] *= al[3];
      od[dt] = o;
    }
    bf16x8 pa0 = *reinterpret_cast<const bf16x8*>(&psw[KIDX(lr, lg * 8)]);
    bf16x8 pa1 = *reinterpret_cast<const bf16x8*>(&psw[KIDX(lr, 32 + lg * 8)]);
    #pragma unroll
    for (int dt = 0; dt < 4; ++dt) {
      bf16x8 bv0 = *reinterpret_cast<const bf16x8*>(&vst[KIDX(dt * 16 + lr, lg * 8)]);
      bf16x8 bv1 = *reinterpret_cast<const bf16x8*>(&vst[KIDX(dt * 16 + lr, 32 + lg * 8)]);
      od[dt] = __builtin_amdgcn_mfma_f32_16x16x32_bf16(pa0, bv0, od[dt], 0, 0, 0);
      od[dt] = __builtin_amdgcn_mfma_f32_16x16x32_bf16(pa1, bv1, od[dt], 0, 0, 0);
    }
  }
  #pragma unroll
  for (int dt = 0; dt < 4; ++dt) {
    #pragma unroll
    for (int r = 0; r < 4; ++r) {
      int q = qw0 + lg * 4 + r;
      ob[((size_t)(b * T_) + q) * D_ + h * 64 + dt * 16 + lr] = (u16)f2bf(od[dt][r] / lsum[r]);
    }
  }
}

extern "C" void kernel_launch(void* const* d_in, const int* in_sizes, int n_in,
                              void* d_out, int out_size, void* d_ws, size_t ws_size,
                              hipStream_t stream) {
  (void)in_sizes; (void)n_in; (void)out_size; (void)ws_size;
  const int* tokens = (const int*)d_in[0];
  const int* mem_ids = (const int*)d_in[1];
  const float* mem_emb = (const float*)d_in[2];
  const float* ssum = (const float*)d_in[3];
  const float* embed = (const float*)d_in[4];
  const float* engram_t = (const float*)d_in[5];
  const float* engram_g = (const float*)d_in[6];
  const float* engram_s = (const float*)d_in[7];
  const float* mem_W = (const float*)d_in[8];
  const float* mem_b = (const float*)d_in[9];
  const float* mem_s = (const float*)d_in[10];
  const float* alpha_g = (const float*)d_in[11];
  const float* ssum_W = (const float*)d_in[12];
  const float* ln1 = (const float*)d_in[13];
  const float* qW = (const float*)d_in[14];
  const float* qbias = (const float*)d_in[15];
  const float* kW = (const float*)d_in[16];
  const float* kbias = (const float*)d_in[17];
  const float* vW = (const float*)d_in[18];
  const float* vbias = (const float*)d_in[19];
  const float* oW = (const float*)d_in[20];
  const float* obias = (const float*)d_in[21];
  const float* ln2 = (const float*)d_in[22];
  const float* w_in = (const float*)d_in[23];
  const float* w_out = (const float*)d_in[24];
  const float* final_s = (const float*)d_in[25];

  char* p = (char*)d_ws;
  auto alloc = [&](size_t bytes) { char* r = p; p += (bytes + 255) & ~(size_t)255; return r; };
  u16* kv_b   = (u16*)alloc((size_t)B_ * TK_ * D_ * 2);
  float* cx   = (float*)alloc((size_t)B_ * T_ * D_ * 4);
  u16* nx_b   = (u16*)alloc((size_t)B_ * T_ * D_ * 2);   // also ob (attn out)
  u16* qb_b   = (u16*)alloc((size_t)B_ * T_ * D_ * 2);   // also mem_tmp f32 (1MB < 4.2MB)
  u16* kb_b   = (u16*)alloc((size_t)B_ * TK_ * D_ * 2);  // hb spans kb_b+vb_b
  u16* vb_b   = (u16*)alloc((size_t)B_ * TK_ * D_ * 2);
  u16* wqT    = (u16*)alloc((size_t)D_ * D_ * 2);
  u16* wkT    = (u16*)alloc((size_t)D_ * D_ * 2);
  u16* wvT    = (u16*)alloc((size_t)D_ * D_ * 2);
  u16* woT    = (u16*)alloc((size_t)D_ * D_ * 2);
  u16* wiT    = (u16*)alloc((size_t)4096 * 512 * 2);
  u16* woutT  = (u16*)alloc((size_t)512 * 2048 * 2);
  float* ssp  = (float*)alloc((size_t)B_ * D_ * 4);
  float* rc   = (float*)alloc((size_t)TK_ * 32 * 4);
  float* rs   = (float*)alloc((size_t)TK_ * 32 * 4);
  float* mem_tmp = (float*)qb_b;
  u16* ob_b = nx_b;
  u16* hb = kb_b;
  (void)vb_b;

  // preamble
  rope_table_k<<<TK_, 32, 0, stream>>>(rc, rs);
  ssum_proj_k<<<dim3(2, B_), 256, 0, stream>>>(ssum, ssum_W, ssp);
  sgemm_k<<<dim3(8, 8), 256, 0, stream>>>(mem_emb, mem_W, mem_b, mem_tmp, B_ * O_, D_, D_);
  memnorm_k<<<dim3(O_, B_), 128, 0, stream>>>(mem_tmp, mem_s, kv_b);
  engram_k<<<dim3(T_, B_), 128, 0, stream>>>(tokens, mem_ids, engram_t, engram_g, engram_s, kv_b);
  embed_k<<<dim3(T_, B_), 128, 0, stream>>>(tokens, embed, ssp, alpha_g, cx, kv_b);

  for (int l = 0; l < L_; ++l) {
    wconv_k<<<dim3(8, 8), 256, 0, stream>>>(qW + (size_t)l * D_ * D_, wqT, D_, D_);
    wconv_k<<<dim3(8, 8), 256, 0, stream>>>(kW + (size_t)l * D_ * D_, wkT, D_, D_);
    wconv_k<<<dim3(8, 8), 256, 0, stream>>>(vW + (size_t)l * D_ * D_, wvT, D_, D_);
    wconv_k<<<dim3(8, 8), 256, 0, stream>>>(oW + (size_t)l * D_ * D_, woT, D_, D_);
    wconv_k<<<dim3(64, 8), 256, 0, stream>>>(w_in + (size_t)l * D_ * 8 * D_, wiT, 512, 4096);
    wconv_k<<<dim3(8, 32), 256, 0, stream>>>(w_out + (size_t)l * 4 * D_ * D_, woutT, 2048, 512);

    rmsnorm_k<1><<<B_ * T_, 128, 0, stream>>>(cx, ln1 + l * D_, nx_b);
    gemm_bf16_k<1><<<dim3(4, 32), 256, 0, stream>>>(nx_b, wqT, qbias + l * D_, qb_b,
                                                    B_ * T_, D_, D_, T_, rc, rs);
    gemm_bf16_k<1><<<dim3(4, 68), 256, 0, stream>>>(kv_b, wkT, kbias + l * D_, kb_b,
                                                    B_ * TK_, D_, D_, TK_, rc, rs);
    gemm_bf16_k<0><<<dim3(4, 68), 256, 0, stream>>>(kv_b, wvT, vbias + l * D_, vb_b,
                                                    B_ * TK_, D_, D_, 0, nullptr, nullptr);
    attn_mfma_k<<<dim3(T_ / 64, H_, B_), 256, 0, stream>>>(qb_b, kb_b, vb_b, tokens, ob_b);
    gemm_bf16_k<2><<<dim3(4, 32), 256, 0, stream>>>(ob_b, woT, obias + l * D_, cx,
                                                    B_ * T_, D_, D_, 0, nullptr, nullptr);
    rmsnorm_k<1><<<B_ * T_, 128, 0, stream>>>(cx, ln2 + l * D_, nx_b);
    mlp_in_mfma_k<<<dim3(32, 32), 256, 0, stream>>>(nx_b, wiT, hb);
    gemm_bf16_k<2><<<dim3(4, 32), 256, 0, stream>>>(hb, woutT, nullptr, cx,
                                                    B_ * T_, D_, 2048, 0, nullptr, nullptr);
  }
  rmsnorm_k<0><<<B_ * T_, 128, 0, stream>>>(cx, final_s, d_out);
}

// Round 4
// 1549.920 us; speedup vs baseline: 8.5144x; 1.0933x over previous
//
#include <hip/hip_runtime.h>
#include <hip/hip_bf16.h>
#include <math.h>

#define B_ 4
#define T_ 1024
#define O_ 128
#define D_ 512
#define H_ 8
#define L_ 6
#define TK_ 2176
#define MM_ 100000
#define EH_ 4
#define EHD_ 128
#define HD_ 64

typedef float f32x4 __attribute__((ext_vector_type(4)));
typedef short bf16x8 __attribute__((ext_vector_type(8)));
typedef unsigned short u16;

// PRIMES per reference: base=131, x=base+h*1009; row[i]=x; x=x*31+1 (uint32 wrap)
__device__ __constant__ unsigned int PRIMES_[4][4] = {
  {131u,  4062u,  125923u, 3903614u},
  {1140u, 35341u, 1095572u, 33962733u},
  {2149u, 66620u, 2065221u, 64021852u},
  {3158u, 97899u, 3034870u, 94080971u},
};

__device__ __forceinline__ float wave_sum_f(float v) {
  #pragma unroll
  for (int off = 32; off; off >>= 1) v += __shfl_xor(v, off);
  return v;
}

__device__ __forceinline__ short f2bf(float f) {
  unsigned int u = __float_as_uint(f);
  unsigned int r = (u + 0x7fffu + ((u >> 16) & 1u)) >> 16;
  return (short)r;
}

__device__ __forceinline__ void gload16(const void* g, void* l) {
  __builtin_amdgcn_global_load_lds((const __attribute__((address_space(1))) void*)g,
                                   (__attribute__((address_space(3))) void*)l, 16, 0, 0);
}

// ---------------- rope tables: cos/sin [TK][32] ----------------
__global__ __launch_bounds__(64) void rope_table_k(float* __restrict__ rc,
                                                   float* __restrict__ rs) {
  int i = blockIdx.x * 64 + threadIdx.x;
  int t = i >> 5, j = i & 31;
  float freq = __powf(10000.0f, -(float)j / 32.0f);
  float ang = (float)t * freq;
  rc[i] = cosf(ang);
  rs[i] = sinf(ang);
}

// ---------------- ssum @ ssum_W -> ssp[B][D] ----------------
__global__ __launch_bounds__(256) void ssum_proj_k(const float* __restrict__ ssum,
                                                   const float* __restrict__ sW,
                                                   float* __restrict__ ssp) {
  int col = blockIdx.x * 256 + threadIdx.x;
  int b = blockIdx.y;
  float acc = 0.f;
  for (int d = 0; d < D_; ++d) acc += ssum[b * D_ + d] * sW[(size_t)d * D_ + col];
  ssp[b * D_ + col] = acc;
}

// ---------------- f32 tiled GEMM (preamble mem projection only) ----------------
__global__ __launch_bounds__(256) void sgemm_k(const float* __restrict__ A,
                                               const float* __restrict__ W,
                                               const float* __restrict__ bias,
                                               float* __restrict__ C,
                                               int M, int N, int K) {
  __shared__ float As[16][68];
  __shared__ float Bs[16][68];
  int tid = threadIdx.x;
  int row0 = blockIdx.y * 64;
  int col0 = blockIdx.x * 64;
  int tx = tid & 15, ty = tid >> 4;
  int am = tid >> 2, ak = (tid & 3) * 4;
  int bk = tid >> 4, bc = (tid & 15) * 4;
  float acc[4][4] = {};
  for (int k0 = 0; k0 < K; k0 += 16) {
    float4 av = *reinterpret_cast<const float4*>(&A[(size_t)(row0 + am) * K + k0 + ak]);
    As[ak + 0][am] = av.x; As[ak + 1][am] = av.y; As[ak + 2][am] = av.z; As[ak + 3][am] = av.w;
    float4 bv = *reinterpret_cast<const float4*>(&W[(size_t)(k0 + bk) * N + col0 + bc]);
    *reinterpret_cast<float4*>(&Bs[bk][bc]) = bv;
    __syncthreads();
    #pragma unroll
    for (int kk = 0; kk < 16; ++kk) {
      float4 a4 = *reinterpret_cast<const float4*>(&As[kk][ty * 4]);
      float4 b4 = *reinterpret_cast<const float4*>(&Bs[kk][tx * 4]);
      float a[4] = {a4.x, a4.y, a4.z, a4.w};
      float b[4] = {b4.x, b4.y, b4.z, b4.w};
      #pragma unroll
      for (int i = 0; i < 4; ++i)
        #pragma unroll
        for (int j = 0; j < 4; ++j) acc[i][j] += a[i] * b[j];
    }
    __syncthreads();
  }
  int cbase = col0 + tx * 4;
  float4 b4 = *reinterpret_cast<const float4*>(&bias[cbase]);
  float bb[4] = {b4.x, b4.y, b4.z, b4.w};
  #pragma unroll
  for (int i = 0; i < 4; ++i) {
    int row = row0 + ty * 4 + i;
    *reinterpret_cast<float4*>(&C[(size_t)row * N + cbase]) =
        make_float4(acc[i][0] + bb[0], acc[i][1] + bb[1], acc[i][2] + bb[2], acc[i][3] + bb[3]);
  }
}

// ---------------- batched weight convert+transpose: f32 [K][N] -> bf16 [N][K] ----------------
// one 64x64 tile per block; z selects (layer, matrix) via caller-specific mapping.
__device__ __forceinline__ void wconv_tile(const float* __restrict__ W, u16* __restrict__ wT,
                                           int K, int N) {
  __shared__ float s[64][65];
  int n0 = blockIdx.x * 64, k0 = blockIdx.y * 64;
  int tid = threadIdx.x;
  int kr = tid >> 4, nc = (tid & 15) * 4;
  #pragma unroll
  for (int kk = 0; kk < 4; ++kk) {
    float4 f = *reinterpret_cast<const float4*>(&W[(size_t)(k0 + kr + kk * 16) * N + n0 + nc]);
    s[kr + kk * 16][nc + 0] = f.x; s[kr + kk * 16][nc + 1] = f.y;
    s[kr + kk * 16][nc + 2] = f.z; s[kr + kk * 16][nc + 3] = f.w;
  }
  __syncthreads();
  int nr = tid >> 4, kc = (tid & 15) * 4;
  #pragma unroll
  for (int nn = 0; nn < 4; ++nn) {
    int n = nr + nn * 16;
    ushort4 o;
    o.x = (u16)f2bf(s[kc + 0][n]); o.y = (u16)f2bf(s[kc + 1][n]);
    o.z = (u16)f2bf(s[kc + 2][n]); o.w = (u16)f2bf(s[kc + 3][n]);
    *reinterpret_cast<ushort4*>(&wT[(size_t)(n0 + n) * K + k0 + kc]) = o;
  }
}

// z = l*4 + which(0..3: q,k,v,o); each weight 512x512
__global__ __launch_bounds__(256) void wconv_qkvo_k(const float* __restrict__ qW,
                                                    const float* __restrict__ kW,
                                                    const float* __restrict__ vW,
                                                    const float* __restrict__ oW,
                                                    u16* __restrict__ dst) {
  int z = blockIdx.z;
  int l = z >> 2, which = z & 3;
  const float* src = which == 0 ? qW : which == 1 ? kW : which == 2 ? vW : oW;
  wconv_tile(src + (size_t)l * D_ * D_, dst + (size_t)z * D_ * D_, D_, D_);
}

// z = layer; w_in 512x4096 -> [4096][512]
__global__ __launch_bounds__(256) void wconv_win_k(const float* __restrict__ w_in,
                                                   u16* __restrict__ dst) {
  int l = blockIdx.z;
  wconv_tile(w_in + (size_t)l * 512 * 4096, dst + (size_t)l * 4096 * 512, 512, 4096);
}

// z = layer; w_out 2048x512 -> [512][2048]
__global__ __launch_bounds__(256) void wconv_wout_k(const float* __restrict__ w_out,
                                                    u16* __restrict__ dst) {
  int l = blockIdx.z;
  wconv_tile(w_out + (size_t)l * 2048 * 512, dst + (size_t)l * 512 * 2048, 2048, 512);
}

// ---------------- MFMA GEMM: C = A@Bt^T (+bias) [+rope | f32 +=] ----------------
// A bf16 [M][K], Bt bf16 [N][K]. Tile BM=MI*32 x 128, BK=32, 4 waves (wave MI*16 x 64).
// EPI: 1 = bf16 out + bias + rope, 2 = f32 += (+opt bias)
template<int EPI, int MI>
__global__ __launch_bounds__(256) void gemm_bf16_k(const u16* __restrict__ A,
                                                   const u16* __restrict__ Bt,
                                                   const float* __restrict__ bias,
                                                   void* __restrict__ Cout,
                                                   int M, int N, int K, int posmod,
                                                   const float* __restrict__ rc,
                                                   const float* __restrict__ rs) {
  __shared__ __align__(16) u16 As[2][MI * 32 * 32];
  __shared__ __align__(16) u16 Bs[2][128 * 32];
  int tid = threadIdx.x;
  int w = tid >> 6, lane = tid & 63;
  int lr = lane & 15, lg = lane >> 4;
  int row0 = blockIdx.y * (MI * 32), col0 = blockIdx.x * 128;
  int wr = w >> 1, wc = w & 1;
  f32x4 acc[MI][4] = {};

  int srow = lane >> 2;
  int skel = (lane & 3) * 8;

  auto stage = [&](int buf, int k0) {
    if constexpr (MI == 4) {
      #pragma unroll
      for (int ci = 0; ci < 2; ++ci) {
        int c = w * 2 + ci;
        gload16(A + (size_t)(row0 + c * 16 + srow) * K + k0 + skel, &As[buf][c * 512]);
      }
    } else {
      gload16(A + (size_t)(row0 + w * 16 + srow) * K + k0 + skel, &As[buf][w * 512]);
    }
    #pragma unroll
    for (int ci = 0; ci < 2; ++ci) {
      int c = w * 2 + ci;
      gload16(Bt + (size_t)(col0 + c * 16 + srow) * K + k0 + skel, &Bs[buf][c * 512]);
    }
  };

  stage(0, 0);
  __syncthreads();
  int nk = K >> 5;
  int buf = 0;
  for (int t = 0; t < nk; ++t) {
    if (t + 1 < nk) stage(buf ^ 1, (t + 1) * 32);
    bf16x8 af[MI], bfr[4];
    #pragma unroll
    for (int i = 0; i < MI; ++i)
      af[i] = *reinterpret_cast<const bf16x8*>(
          &As[buf][(wr * (16 * MI) + i * 16 + lr) * 32 + lg * 8]);
    #pragma unroll
    for (int j = 0; j < 4; ++j)
      bfr[j] = *reinterpret_cast<const bf16x8*>(&Bs[buf][(wc * 64 + j * 16 + lr) * 32 + lg * 8]);
    #pragma unroll
    for (int i = 0; i < MI; ++i)
      #pragma unroll
      for (int j = 0; j < 4; ++j)
        acc[i][j] = __builtin_amdgcn_mfma_f32_16x16x32_bf16(af[i], bfr[j], acc[i][j], 0, 0, 0);
    __syncthreads();
    buf ^= 1;
  }

  #pragma unroll
  for (int j = 0; j < 4; ++j) {
    int col = col0 + wc * 64 + j * 16 + lr;
    float bs = bias ? bias[col] : 0.f;
    #pragma unroll
    for (int i = 0; i < MI; ++i) {
      #pragma unroll
      for (int r = 0; r < 4; ++r) {
        int row = row0 + wr * (16 * MI) + i * 16 + lg * 4 + r;
        float v = acc[i][j][r] + bs;
        if (EPI == 1) {
          int pos = row % posmod;
          int d = col & 63;
          float c = rc[(size_t)pos * 32 + (d >> 1)];
          float s = rs[(size_t)pos * 32 + (d >> 1)];
          float partner = __shfl_xor(v, 1);
          v = (d & 1) ? (partner * s + v * c) : (v * c - partner * s);
        }
        if (EPI == 2) {
          float* Cf = (float*)Cout;
          Cf[(size_t)row * N + col] += v;
        } else {
          u16* Cb = (u16*)Cout;
          Cb[(size_t)row * N + col] = (u16)f2bf(v);
        }
      }
    }
  }
}

// ---------------- fused K+V projection: kb = rope(A@Wk^T + kb_), vb = A@Wv^T + vb_ ----------------
// A bf16 [M][512] (kv seq), tile 128 rows x 64 cols per output. 4 waves: 64x32 each.
__global__ __launch_bounds__(256) void kv_gemm_k(const u16* __restrict__ A,
                                                 const u16* __restrict__ wkT,
                                                 const u16* __restrict__ wvT,
                                                 const float* __restrict__ kbias,
                                                 const float* __restrict__ vbias,
                                                 u16* __restrict__ kb,
                                                 u16* __restrict__ vb,
                                                 const float* __restrict__ rc,
                                                 const float* __restrict__ rs) {
  __shared__ __align__(16) u16 As[2][128 * 32];
  __shared__ __align__(16) u16 Bk[2][64 * 32];
  __shared__ __align__(16) u16 Bv[2][64 * 32];
  const int K = 512, N = 512;
  int tid = threadIdx.x;
  int w = tid >> 6, lane = tid & 63;
  int lr = lane & 15, lg = lane >> 4;
  int row0 = blockIdx.y * 128, col0 = blockIdx.x * 64;
  int wr = w >> 1, wc = w & 1;
  f32x4 ak_[4][2] = {};
  f32x4 av_[4][2] = {};

  int srow = lane >> 2;
  int skel = (lane & 3) * 8;

  auto stage = [&](int buf, int k0) {
    #pragma unroll
    for (int ci = 0; ci < 2; ++ci) {
      int c = w * 2 + ci;
      gload16(A + (size_t)(row0 + c * 16 + srow) * K + k0 + skel, &As[buf][c * 512]);
    }
    gload16(wkT + (size_t)(col0 + w * 16 + srow) * K + k0 + skel, &Bk[buf][w * 512]);
    gload16(wvT + (size_t)(col0 + w * 16 + srow) * K + k0 + skel, &Bv[buf][w * 512]);
  };

  stage(0, 0);
  __syncthreads();
  int buf = 0;
  for (int t = 0; t < 16; ++t) {
    if (t + 1 < 16) stage(buf ^ 1, (t + 1) * 32);
    bf16x8 af[4], bk[2], bv[2];
    #pragma unroll
    for (int i = 0; i < 4; ++i)
      af[i] = *reinterpret_cast<const bf16x8*>(&As[buf][(wr * 64 + i * 16 + lr) * 32 + lg * 8]);
    #pragma unroll
    for (int j = 0; j < 2; ++j) {
      bk[j] = *reinterpret_cast<const bf16x8*>(&Bk[buf][(wc * 32 + j * 16 + lr) * 32 + lg * 8]);
      bv[j] = *reinterpret_cast<const bf16x8*>(&Bv[buf][(wc * 32 + j * 16 + lr) * 32 + lg * 8]);
    }
    #pragma unroll
    for (int i = 0; i < 4; ++i)
      #pragma unroll
      for (int j = 0; j < 2; ++j) {
        ak_[i][j] = __builtin_amdgcn_mfma_f32_16x16x32_bf16(af[i], bk[j], ak_[i][j], 0, 0, 0);
        av_[i][j] = __builtin_amdgcn_mfma_f32_16x16x32_bf16(af[i], bv[j], av_[i][j], 0, 0, 0);
      }
    __syncthreads();
    buf ^= 1;
  }

  #pragma unroll
  for (int j = 0; j < 2; ++j) {
    int col = col0 + wc * 32 + j * 16 + lr;
    float kbs = kbias[col], vbs = vbias[col];
    int d = col & 63;
    #pragma unroll
    for (int i = 0; i < 4; ++i) {
      #pragma unroll
      for (int r = 0; r < 4; ++r) {
        int row = row0 + wr * 64 + i * 16 + lg * 4 + r;
        int pos = row % TK_;
        float vk = ak_[i][j][r] + kbs;
        float c = rc[(size_t)pos * 32 + (d >> 1)];
        float s = rs[(size_t)pos * 32 + (d >> 1)];
        float partner = __shfl_xor(vk, 1);
        vk = (d & 1) ? (partner * s + vk * c) : (vk * c - partner * s);
        kb[(size_t)row * N + col] = (u16)f2bf(vk);
        vb[(size_t)row * N + col] = (u16)f2bf(av_[i][j][r] + vbs);
      }
    }
  }
}

// ---------------- fused MLP-in MFMA: H = silu(A@Wg^T) * (A@Wv^T), bf16 out ----------------
__global__ __launch_bounds__(256) void mlp_in_mfma_k(const u16* __restrict__ A,
                                                     const u16* __restrict__ wiT,
                                                     u16* __restrict__ Hout) {
  __shared__ __align__(16) u16 As[2][128 * 32];
  __shared__ __align__(16) u16 Bg[2][64 * 32];
  __shared__ __align__(16) u16 Bv[2][64 * 32];
  int tid = threadIdx.x;
  int w = tid >> 6, lane = tid & 63;
  int lr = lane & 15, lg = lane >> 4;
  int hc0 = blockIdx.x * 64, row0 = blockIdx.y * 128;
  int wr = w >> 1, wc = w & 1;
  f32x4 ag[4][2] = {};
  f32x4 av[4][2] = {};
  const int K = 512;

  int srow = lane >> 2;
  int skel = (lane & 3) * 8;

  auto stage = [&](int buf, int k0) {
    #pragma unroll
    for (int ci = 0; ci < 2; ++ci) {
      int c = w * 2 + ci;
      gload16(A + (size_t)(row0 + c * 16 + srow) * K + k0 + skel, &As[buf][c * 512]);
    }
    gload16(wiT + (size_t)(hc0 + w * 16 + srow) * K + k0 + skel, &Bg[buf][w * 512]);
    gload16(wiT + (size_t)(2048 + hc0 + w * 16 + srow) * K + k0 + skel, &Bv[buf][w * 512]);
  };

  stage(0, 0);
  __syncthreads();
  int buf = 0;
  for (int t = 0; t < 16; ++t) {
    if (t + 1 < 16) stage(buf ^ 1, (t + 1) * 32);
    bf16x8 af[4], bg[2], bv[2];
    #pragma unroll
    for (int i = 0; i < 4; ++i)
      af[i] = *reinterpret_cast<const bf16x8*>(&As[buf][(wr * 64 + i * 16 + lr) * 32 + lg * 8]);
    #pragma unroll
    for (int j = 0; j < 2; ++j) {
      bg[j] = *reinterpret_cast<const bf16x8*>(&Bg[buf][(wc * 32 + j * 16 + lr) * 32 + lg * 8]);
      bv[j] = *reinterpret_cast<const bf16x8*>(&Bv[buf][(wc * 32 + j * 16 + lr) * 32 + lg * 8]);
    }
    #pragma unroll
    for (int i = 0; i < 4; ++i)
      #pragma unroll
      for (int j = 0; j < 2; ++j) {
        ag[i][j] = __builtin_amdgcn_mfma_f32_16x16x32_bf16(af[i], bg[j], ag[i][j], 0, 0, 0);
        av[i][j] = __builtin_amdgcn_mfma_f32_16x16x32_bf16(af[i], bv[j], av[i][j], 0, 0, 0);
      }
    __syncthreads();
    buf ^= 1;
  }

  #pragma unroll
  for (int j = 0; j < 2; ++j) {
    int col = hc0 + wc * 32 + j * 16 + lr;
    #pragma unroll
    for (int i = 0; i < 4; ++i) {
      #pragma unroll
      for (int r = 0; r < 4; ++r) {
        int row = row0 + wr * 64 + i * 16 + lg * 4 + r;
        float g = ag[i][j][r];
        float sg = g / (1.f + __expf(-g));
        Hout[(size_t)row * 2048 + col] = (u16)f2bf(sg * av[i][j][r]);
      }
    }
  }
}

// ---------------- rmsnorm rows: f32 in -> bf16 (OUTBF=1) or f32 (OUTBF=0) out ----------------
template<int OUTBF>
__global__ __launch_bounds__(128) void rmsnorm_k(const float* __restrict__ in,
                                                 const float* __restrict__ scale,
                                                 void* __restrict__ out) {
  int row = blockIdx.x;
  int tid = threadIdx.x;
  float4 v = *reinterpret_cast<const float4*>(&in[(size_t)row * D_ + tid * 4]);
  float ss = v.x * v.x + v.y * v.y + v.z * v.z + v.w * v.w;
  ss = wave_sum_f(ss);
  __shared__ float red[2];
  if ((tid & 63) == 0) red[tid >> 6] = ss;
  __syncthreads();
  ss = red[0] + red[1];
  float inv = 1.0f / sqrtf(ss / (float)D_ + 1e-6f);
  float4 sc = *reinterpret_cast<const float4*>(&scale[tid * 4]);
  float o0 = v.x * inv * sc.x, o1 = v.y * inv * sc.y, o2 = v.z * inv * sc.z, o3 = v.w * inv * sc.w;
  if (OUTBF) {
    ushort4 o;
    o.x = (u16)f2bf(o0); o.y = (u16)f2bf(o1); o.z = (u16)f2bf(o2); o.w = (u16)f2bf(o3);
    *reinterpret_cast<ushort4*>((u16*)out + (size_t)row * D_ + tid * 4) = o;
  } else {
    *reinterpret_cast<float4*>((float*)out + (size_t)row * D_ + tid * 4) =
        make_float4(o0, o1, o2, o3);
  }
}

// ---------------- mem rows: rmsnorm(tmp row b*O+o) -> kv bf16 row b*TK+o ----------------
__global__ __launch_bounds__(128) void memnorm_k(const float* __restrict__ tmp,
                                                 const float* __restrict__ scale,
                                                 u16* __restrict__ kv) {
  int o = blockIdx.x, b = blockIdx.y;
  int tid = threadIdx.x;
  float4 v = *reinterpret_cast<const float4*>(&tmp[(size_t)(b * O_ + o) * D_ + tid * 4]);
  float ss = v.x * v.x + v.y * v.y + v.z * v.z + v.w * v.w;
  ss = wave_sum_f(ss);
  __shared__ float red[2];
  if ((tid & 63) == 0) red[tid >> 6] = ss;
  __syncthreads();
  ss = red[0] + red[1];
  float inv = 1.0f / sqrtf(ss / (float)D_ + 1e-6f);
  float4 sc = *reinterpret_cast<const float4*>(&scale[tid * 4]);
  ushort4 oo;
  oo.x = (u16)f2bf(v.x * inv * sc.x); oo.y = (u16)f2bf(v.y * inv * sc.y);
  oo.z = (u16)f2bf(v.z * inv * sc.z); oo.w = (u16)f2bf(v.w * inv * sc.w);
  *reinterpret_cast<ushort4*>(&kv[(size_t)(b * TK_ + o) * D_ + tid * 4]) = oo;
}

// ---------------- engram rows -> kv bf16 [b, O+t, :] ----------------
__global__ __launch_bounds__(128) void engram_k(const int* __restrict__ tokens,
                                                const int* __restrict__ mem_ids,
                                                const float* __restrict__ etab,
                                                const float* __restrict__ egate,
                                                const float* __restrict__ escale,
                                                u16* __restrict__ kv) {
  int t = blockIdx.x, b = blockIdx.y;
  int tid = threadIdx.x;
  unsigned int toks[4];
  #pragma unroll
  for (int i = 0; i < 4; ++i) {
    int idx = t - i;
    toks[i] = (idx >= 0) ? (unsigned int)tokens[b * T_ + idx]
                         : (unsigned int)mem_ids[b * O_ + O_ + idx];
  }
  int c = tid * 4;
  int h = c >> 7;
  int e = c & 127;
  unsigned int hs = 0;
  #pragma unroll
  for (int i = 0; i < 4; ++i) hs += toks[i] * PRIMES_[h][i];
  int idxh = (int)(hs % (unsigned int)MM_);
  float4 r = *reinterpret_cast<const float4*>(&etab[((size_t)idxh * EH_ + h) * EHD_ + e]);
  float4 g = *reinterpret_cast<const float4*>(&egate[h * EHD_ + e]);
  float4 val;
  val.x = r.x / (1.f + __expf(-g.x));
  val.y = r.y / (1.f + __expf(-g.y));
  val.z = r.z / (1.f + __expf(-g.z));
  val.w = r.w / (1.f + __expf(-g.w));
  float ss = val.x * val.x + val.y * val.y + val.z * val.z + val.w * val.w;
  ss = wave_sum_f(ss);
  __shared__ float red[2];
  if ((tid & 63) == 0) red[tid >> 6] = ss;
  __syncthreads();
  ss = red[0] + red[1];
  float inv = 1.0f / sqrtf(ss / (float)D_ + 1e-6f);
  float4 sc = *reinterpret_cast<const float4*>(&escale[c]);
  ushort4 oo;
  oo.x = (u16)f2bf(val.x * inv * sc.x); oo.y = (u16)f2bf(val.y * inv * sc.y);
  oo.z = (u16)f2bf(val.z * inv * sc.z); oo.w = (u16)f2bf(val.w * inv * sc.w);
  *reinterpret_cast<ushort4*>(&kv[(size_t)(b * TK_ + O_ + t) * D_ + c]) = oo;
}

// ---------------- embed + ssum inject -> cx f32 and kv bf16 [b, O+T+t, :] ----------------
__global__ __launch_bounds__(128) void embed_k(const int* __restrict__ tokens,
                                               const float* __restrict__ etab,
                                               const float* __restrict__ ssp,
                                               const float* __restrict__ alpha_g,
                                               float* __restrict__ cx,
                                               u16* __restrict__ kv) {
  int t = blockIdx.x, b = blockIdx.y;
  int tid = threadIdx.x;
  int c = tid * 4;
  int tok = tokens[b * T_ + t];
  float4 e = *reinterpret_cast<const float4*>(&etab[(size_t)tok * D_ + c]);
  float4 sp = *reinterpret_cast<const float4*>(&ssp[b * D_ + c]);
  float4 ag = *reinterpret_cast<const float4*>(&alpha_g[c]);
  float4 x;
  x.x = e.x + sp.x / (1.f + __expf(-ag.x));
  x.y = e.y + sp.y / (1.f + __expf(-ag.y));
  x.z = e.z + sp.z / (1.f + __expf(-ag.z));
  x.w = e.w + sp.w / (1.f + __expf(-ag.w));
  *reinterpret_cast<float4*>(&cx[(size_t)(b * T_ + t) * D_ + c]) = x;
  ushort4 oo;
  oo.x = (u16)f2bf(x.x); oo.y = (u16)f2bf(x.y);
  oo.z = (u16)f2bf(x.z); oo.w = (u16)f2bf(x.w);
  *reinterpret_cast<ushort4*>(&kv[(size_t)(b * TK_ + O_ + T_ + t) * D_ + c]) = oo;
}

// ---------------- MFMA flash attention (bf16 IO, causal tile skipping) ----------------
#define KIDX(r, c) (((r) << 6) + ((c) ^ (((r) & 7) << 3)))

__global__ __launch_bounds__(256) void attn_mfma_k(const u16* __restrict__ qb,
                                                   const u16* __restrict__ kb,
                                                   const u16* __restrict__ vb,
                                                   const int* __restrict__ tokens,
                                                   u16* __restrict__ ob) {
  __shared__ __align__(16) short ks[64 * 64];
  __shared__ __align__(16) short vst[64 * 64];   // transposed: [d][k]
  __shared__ __align__(16) short ps[4][16 * 64]; // per-wave P tile
  __shared__ unsigned char vtok[T_];
  int b = blockIdx.z, h = blockIdx.y;
  int bx = blockIdx.x;
  int qt0 = bx * 64;
  int tid = threadIdx.x;
  int w = tid >> 6, lane = tid & 63;
  int lr = lane & 15;
  int lg = lane >> 4;
  int qw0 = qt0 + w * 16;

  for (int i = tid; i < T_; i += 256) vtok[i] = (tokens[b * T_ + i] != 0);

  bf16x8 aq[2];
  {
    const u16* qp = &qb[((size_t)(b * T_) + qw0 + lr) * D_ + h * 64];
    aq[0] = *reinterpret_cast<const bf16x8*>(qp + lg * 8);
    aq[1] = *reinterpret_cast<const bf16x8*>(qp + 32 + lg * 8);
  }

  float m_[4], lsum[4];
  f32x4 od[4];
  #pragma unroll
  for (int r = 0; r < 4; ++r) { m_[r] = -1e30f; lsum[r] = 0.f; }
  #pragma unroll
  for (int dt = 0; dt < 4; ++dt) od[dt] = (f32x4){0.f, 0.f, 0.f, 0.f};

  int sr = tid >> 2;
  int sc = (tid & 3) * 16;

  auto proc_tile = [&](int pos0, int base, bool masked) {
    __syncthreads();
    {
      const u16* kg = &kb[((size_t)(b * TK_) + pos0 + sr) * D_ + h * 64 + sc];
      const u16* vg = &vb[((size_t)(b * TK_) + pos0 + sr) * D_ + h * 64 + sc];
      bf16x8 k0 = *reinterpret_cast<const bf16x8*>(kg);
      bf16x8 k1 = *reinterpret_cast<const bf16x8*>(kg + 8);
      *reinterpret_cast<bf16x8*>(&ks[KIDX(sr, sc)]) = k0;
      *reinterpret_cast<bf16x8*>(&ks[KIDX(sr, sc + 8)]) = k1;
      bf16x8 v0 = *reinterpret_cast<const bf16x8*>(vg);
      bf16x8 v1 = *reinterpret_cast<const bf16x8*>(vg + 8);
      #pragma unroll
      for (int j = 0; j < 8; ++j) vst[KIDX(sc + j, sr)] = v0[j];
      #pragma unroll
      for (int j = 0; j < 8; ++j) vst[KIDX(sc + 8 + j, sr)] = v1[j];
    }
    __syncthreads();

    float sv[4][4];
    #pragma unroll
    for (int kt = 0; kt < 4; ++kt) {
      bf16x8 bk0 = *reinterpret_cast<const bf16x8*>(&ks[KIDX(kt * 16 + lr, lg * 8)]);
      bf16x8 bk1 = *reinterpret_cast<const bf16x8*>(&ks[KIDX(kt * 16 + lr, 32 + lg * 8)]);
      f32x4 s = (f32x4){0.f, 0.f, 0.f, 0.f};
      s = __builtin_amdgcn_mfma_f32_16x16x32_bf16(aq[0], bk0, s, 0, 0, 0);
      s = __builtin_amdgcn_mfma_f32_16x16x32_bf16(aq[1], bk1, s, 0, 0, 0);
      if (masked) {
        int tk = pos0 + kt * 16 + lr - base;
        bool tokv = (vtok[tk] != 0);
        #pragma unroll
        for (int r = 0; r < 4; ++r) {
          int tq = qw0 + lg * 4 + r;
          sv[kt][r] = (tokv && tk <= tq) ? s[r] * 0.125f : -1e30f;
        }
      } else {
        #pragma unroll
        for (int r = 0; r < 4; ++r) sv[kt][r] = s[r] * 0.125f;
      }
    }
    float al[4], mnew[4], psum[4];
    #pragma unroll
    for (int r = 0; r < 4; ++r) {
      float t = fmaxf(fmaxf(sv[0][r], sv[1][r]), fmaxf(sv[2][r], sv[3][r]));
      t = fmaxf(t, __shfl_xor(t, 1)); t = fmaxf(t, __shfl_xor(t, 2));
      t = fmaxf(t, __shfl_xor(t, 4)); t = fmaxf(t, __shfl_xor(t, 8));
      mnew[r] = fmaxf(m_[r], t);
      al[r] = __expf(m_[r] - mnew[r]);
      m_[r] = mnew[r];
      psum[r] = 0.f;
    }
    short* psw = ps[w];
    #pragma unroll
    for (int kt = 0; kt < 4; ++kt) {
      #pragma unroll
      for (int r = 0; r < 4; ++r) {
        float pe = __expf(sv[kt][r] - mnew[r]);
        psum[r] += pe;
        psw[KIDX(lg * 4 + r, kt * 16 + lr)] = f2bf(pe);
      }
    }
    #pragma unroll
    for (int r = 0; r < 4; ++r) {
      float t = psum[r];
      t += __shfl_xor(t, 1); t += __shfl_xor(t, 2);
      t += __shfl_xor(t, 4); t += __shfl_xor(t, 8);
      lsum[r] = lsum[r] * al[r] + t;
    }
    #pragma unroll
    for (int dt = 0; dt < 4; ++dt) {
      f32x4 o = od[dt];
      o[0] *= al[0]; o[1] *= al[1]; o[2] *= al[2]; o[3] *= al[3];
      od[dt] = o;
    }
    bf16x8 pa0 = *reinterpret_cast<const bf16x8*>(&psw[KIDX(lr, lg * 8)]);
    bf16x8 pa1 = *reinterpret_cast<const bf16x8*>(&psw[KIDX(lr, 32 + lg * 8)]);
    #pragma unroll
    for (int dt = 0; dt < 4; ++dt) {
      bf16x8 bv0 = *reinterpret_cast<const bf16x8*>(&vst[KIDX(dt * 16 + lr, lg * 8)]);
      bf16x8 bv1 = *reinterpret_cast<const bf16x8*>(&vst[KIDX(dt * 16 + lr, 32 + lg * 8)]);
      od[dt] = __builtin_amdgcn_mfma_f32_16x16x32_bf16(pa0, bv0, od[dt], 0, 0, 0);
      od[dt] = __builtin_amdgcn_mfma_f32_16x16x32_bf16(pa1, bv1, od[dt], 0, 0, 0);
    }
  };

  // mem segment: keys [0,128), always valid
  proc_tile(0, 0, false);
  proc_tile(64, 0, false);
  // engram segment: keys [128, 128+T), causal (tk <= tq) — only tiles with tk0 <= qt0+63
  for (int t = 0; t <= bx; ++t) proc_tile(O_ + t * 64, O_, true);
  // x segment: keys [1152, 1152+T), causal
  for (int t = 0; t <= bx; ++t) proc_tile(O_ + T_ + t * 64, O_ + T_, true);

  #pragma unroll
  for (int dt = 0; dt < 4; ++dt) {
    #pragma unroll
    for (int r = 0; r < 4; ++r) {
      int q = qw0 + lg * 4 + r;
      ob[((size_t)(b * T_) + q) * D_ + h * 64 + dt * 16 + lr] = (u16)f2bf(od[dt][r] / lsum[r]);
    }
  }
}

extern "C" void kernel_launch(void* const* d_in, const int* in_sizes, int n_in,
                              void* d_out, int out_size, void* d_ws, size_t ws_size,
                              hipStream_t stream) {
  (void)in_sizes; (void)n_in; (void)out_size; (void)ws_size;
  const int* tokens = (const int*)d_in[0];
  const int* mem_ids = (const int*)d_in[1];
  const float* mem_emb = (const float*)d_in[2];
  const float* ssum = (const float*)d_in[3];
  const float* embed = (const float*)d_in[4];
  const float* engram_t = (const float*)d_in[5];
  const float* engram_g = (const float*)d_in[6];
  const float* engram_s = (const float*)d_in[7];
  const float* mem_W = (const float*)d_in[8];
  const float* mem_b = (const float*)d_in[9];
  const float* mem_s = (const float*)d_in[10];
  const float* alpha_g = (const float*)d_in[11];
  const float* ssum_W = (const float*)d_in[12];
  const float* ln1 = (const float*)d_in[13];
  const float* qW = (const float*)d_in[14];
  const float* qbias = (const float*)d_in[15];
  const float* kW = (const float*)d_in[16];
  const float* kbias = (const float*)d_in[17];
  const float* vW = (const float*)d_in[18];
  const float* vbias = (const float*)d_in[19];
  const float* oW = (const float*)d_in[20];
  const float* obias = (const float*)d_in[21];
  const float* ln2 = (const float*)d_in[22];
  const float* w_in = (const float*)d_in[23];
  const float* w_out = (const float*)d_in[24];
  const float* final_s = (const float*)d_in[25];

  char* p = (char*)d_ws;
  auto alloc = [&](size_t bytes) { char* r = p; p += (bytes + 255) & ~(size_t)255; return r; };
  u16* kv_b   = (u16*)alloc((size_t)B_ * TK_ * D_ * 2);
  float* cx   = (float*)alloc((size_t)B_ * T_ * D_ * 4);
  u16* nx_b   = (u16*)alloc((size_t)B_ * T_ * D_ * 2);   // also ob (attn out)
  u16* qb_b   = (u16*)alloc((size_t)B_ * T_ * D_ * 2);   // also mem_tmp f32
  u16* kb_b   = (u16*)alloc((size_t)B_ * TK_ * D_ * 2);  // hb spans kb_b+vb_b
  u16* vb_b   = (u16*)alloc((size_t)B_ * TK_ * D_ * 2);
  u16* wqkvoT = (u16*)alloc((size_t)L_ * 4 * D_ * D_ * 2); // [l][q,k,v,o][512][512]
  u16* wiT    = (u16*)alloc((size_t)L_ * 4096 * 512 * 2);
  u16* woutT  = (u16*)alloc((size_t)L_ * 512 * 2048 * 2);
  float* ssp  = (float*)alloc((size_t)B_ * D_ * 4);
  float* rc   = (float*)alloc((size_t)TK_ * 32 * 4);
  float* rs   = (float*)alloc((size_t)TK_ * 32 * 4);
  float* mem_tmp = (float*)qb_b;
  u16* ob_b = nx_b;
  u16* hb = kb_b;
  (void)vb_b;

  // preamble + batched weight conversion
  rope_table_k<<<TK_ * 32 / 64, 64, 0, stream>>>(rc, rs);
  wconv_qkvo_k<<<dim3(8, 8, L_ * 4), 256, 0, stream>>>(qW, kW, vW, oW, wqkvoT);
  wconv_win_k<<<dim3(64, 8, L_), 256, 0, stream>>>(w_in, wiT);
  wconv_wout_k<<<dim3(8, 32, L_), 256, 0, stream>>>(w_out, woutT);
  ssum_proj_k<<<dim3(2, B_), 256, 0, stream>>>(ssum, ssum_W, ssp);
  sgemm_k<<<dim3(8, 8), 256, 0, stream>>>(mem_emb, mem_W, mem_b, mem_tmp, B_ * O_, D_, D_);
  memnorm_k<<<dim3(O_, B_), 128, 0, stream>>>(mem_tmp, mem_s, kv_b);
  engram_k<<<dim3(T_, B_), 128, 0, stream>>>(tokens, mem_ids, engram_t, engram_g, engram_s, kv_b);
  embed_k<<<dim3(T_, B_), 128, 0, stream>>>(tokens, embed, ssp, alpha_g, cx, kv_b);

  const size_t WSZ = (size_t)D_ * D_;
  for (int l = 0; l < L_; ++l) {
    const u16* wqT = wqkvoT + ((size_t)l * 4 + 0) * WSZ;
    const u16* wkT = wqkvoT + ((size_t)l * 4 + 1) * WSZ;
    const u16* wvT = wqkvoT + ((size_t)l * 4 + 2) * WSZ;
    const u16* woT = wqkvoT + ((size_t)l * 4 + 3) * WSZ;
    const u16* wil = wiT + (size_t)l * 4096 * 512;
    const u16* wol = woutT + (size_t)l * 512 * 2048;

    rmsnorm_k<1><<<B_ * T_, 128, 0, stream>>>(cx, ln1 + l * D_, nx_b);
    gemm_bf16_k<1, 2><<<dim3(4, 64), 256, 0, stream>>>(nx_b, wqT, qbias + l * D_, qb_b,
                                                       B_ * T_, D_, D_, T_, rc, rs);
    kv_gemm_k<<<dim3(8, 68), 256, 0, stream>>>(kv_b, wkT, wvT, kbias + l * D_, vbias + l * D_,
                                               kb_b, vb_b, rc, rs);
    attn_mfma_k<<<dim3(T_ / 64, H_, B_), 256, 0, stream>>>(qb_b, kb_b, vb_b, tokens, ob_b);
    gemm_bf16_k<2, 2><<<dim3(4, 64), 256, 0, stream>>>(ob_b, woT, obias + l * D_, cx,
                                                       B_ * T_, D_, D_, 0, nullptr, nullptr);
    rmsnorm_k<1><<<B_ * T_, 128, 0, stream>>>(cx, ln2 + l * D_, nx_b);
    mlp_in_mfma_k<<<dim3(32, 32), 256, 0, stream>>>(nx_b, wil, hb);
    gemm_bf16_k<2, 2><<<dim3(4, 64), 256, 0, stream>>>(hb, wol, nullptr, cx,
                                                       B_ * T_, D_, 2048, 0, nullptr, nullptr);
  }
  rmsnorm_k<0><<<B_ * T_, 128, 0, stream>>>(cx, final_s, d_out);
}

// Round 5
// 1369.768 us; speedup vs baseline: 9.6342x; 1.1315x over previous
//
#include <hip/hip_runtime.h>
#include <hip/hip_bf16.h>
#include <math.h>

#define B_ 4
#define T_ 1024
#define O_ 128
#define D_ 512
#define H_ 8
#define L_ 6
#define TK_ 2176
#define MM_ 100000
#define EH_ 4
#define EHD_ 128
#define HD_ 64

typedef float f32x4 __attribute__((ext_vector_type(4)));
typedef short bf16x8 __attribute__((ext_vector_type(8)));
typedef unsigned short u16;

// PRIMES per reference: base=131, x=base+h*1009; row[i]=x; x=x*31+1 (uint32 wrap)
__device__ __constant__ unsigned int PRIMES_[4][4] = {
  {131u,  4062u,  125923u, 3903614u},
  {1140u, 35341u, 1095572u, 33962733u},
  {2149u, 66620u, 2065221u, 64021852u},
  {3158u, 97899u, 3034870u, 94080971u},
};

__device__ __forceinline__ float wave_sum_f(float v) {
  #pragma unroll
  for (int off = 32; off; off >>= 1) v += __shfl_xor(v, off);
  return v;
}

__device__ __forceinline__ short f2bf(float f) {
  unsigned int u = __float_as_uint(f);
  unsigned int r = (u + 0x7fffu + ((u >> 16) & 1u)) >> 16;
  return (short)r;
}

__device__ __forceinline__ void gload16(const void* g, void* l) {
  __builtin_amdgcn_global_load_lds((const __attribute__((address_space(1))) void*)g,
                                   (__attribute__((address_space(3))) void*)l, 16, 0, 0);
}

// ---------------- rope tables: cos/sin [TK][32] ----------------
__global__ __launch_bounds__(64) void rope_table_k(float* __restrict__ rc,
                                                   float* __restrict__ rs) {
  int i = blockIdx.x * 64 + threadIdx.x;
  int t = i >> 5, j = i & 31;
  float freq = __powf(10000.0f, -(float)j / 32.0f);
  float ang = (float)t * freq;
  rc[i] = cosf(ang);
  rs[i] = sinf(ang);
}

// ---------------- ssum @ ssum_W -> ssp[B][D] ----------------
__global__ __launch_bounds__(256) void ssum_proj_k(const float* __restrict__ ssum,
                                                   const float* __restrict__ sW,
                                                   float* __restrict__ ssp) {
  int col = blockIdx.x * 256 + threadIdx.x;
  int b = blockIdx.y;
  float acc = 0.f;
  for (int d = 0; d < D_; ++d) acc += ssum[b * D_ + d] * sW[(size_t)d * D_ + col];
  ssp[b * D_ + col] = acc;
}

// ---------------- f32 tiled GEMM (preamble mem projection only) ----------------
__global__ __launch_bounds__(256) void sgemm_k(const float* __restrict__ A,
                                               const float* __restrict__ W,
                                               const float* __restrict__ bias,
                                               float* __restrict__ C,
                                               int M, int N, int K) {
  __shared__ float As[16][68];
  __shared__ float Bs[16][68];
  int tid = threadIdx.x;
  int row0 = blockIdx.y * 64;
  int col0 = blockIdx.x * 64;
  int tx = tid & 15, ty = tid >> 4;
  int am = tid >> 2, ak = (tid & 3) * 4;
  int bk = tid >> 4, bc = (tid & 15) * 4;
  float acc[4][4] = {};
  for (int k0 = 0; k0 < K; k0 += 16) {
    float4 av = *reinterpret_cast<const float4*>(&A[(size_t)(row0 + am) * K + k0 + ak]);
    As[ak + 0][am] = av.x; As[ak + 1][am] = av.y; As[ak + 2][am] = av.z; As[ak + 3][am] = av.w;
    float4 bv = *reinterpret_cast<const float4*>(&W[(size_t)(k0 + bk) * N + col0 + bc]);
    *reinterpret_cast<float4*>(&Bs[bk][bc]) = bv;
    __syncthreads();
    #pragma unroll
    for (int kk = 0; kk < 16; ++kk) {
      float4 a4 = *reinterpret_cast<const float4*>(&As[kk][ty * 4]);
      float4 b4 = *reinterpret_cast<const float4*>(&Bs[kk][tx * 4]);
      float a[4] = {a4.x, a4.y, a4.z, a4.w};
      float b[4] = {b4.x, b4.y, b4.z, b4.w};
      #pragma unroll
      for (int i = 0; i < 4; ++i)
        #pragma unroll
        for (int j = 0; j < 4; ++j) acc[i][j] += a[i] * b[j];
    }
    __syncthreads();
  }
  int cbase = col0 + tx * 4;
  float4 b4 = *reinterpret_cast<const float4*>(&bias[cbase]);
  float bb[4] = {b4.x, b4.y, b4.z, b4.w};
  #pragma unroll
  for (int i = 0; i < 4; ++i) {
    int row = row0 + ty * 4 + i;
    *reinterpret_cast<float4*>(&C[(size_t)row * N + cbase]) =
        make_float4(acc[i][0] + bb[0], acc[i][1] + bb[1], acc[i][2] + bb[2], acc[i][3] + bb[3]);
  }
}

// ---------------- batched weight convert+transpose: f32 [K][N] -> bf16 [N][K] ----------------
__device__ __forceinline__ void wconv_tile(const float* __restrict__ W, u16* __restrict__ wT,
                                           int K, int N) {
  __shared__ float s[64][65];
  int n0 = blockIdx.x * 64, k0 = blockIdx.y * 64;
  int tid = threadIdx.x;
  int kr = tid >> 4, nc = (tid & 15) * 4;
  #pragma unroll
  for (int kk = 0; kk < 4; ++kk) {
    float4 f = *reinterpret_cast<const float4*>(&W[(size_t)(k0 + kr + kk * 16) * N + n0 + nc]);
    s[kr + kk * 16][nc + 0] = f.x; s[kr + kk * 16][nc + 1] = f.y;
    s[kr + kk * 16][nc + 2] = f.z; s[kr + kk * 16][nc + 3] = f.w;
  }
  __syncthreads();
  int nr = tid >> 4, kc = (tid & 15) * 4;
  #pragma unroll
  for (int nn = 0; nn < 4; ++nn) {
    int n = nr + nn * 16;
    ushort4 o;
    o.x = (u16)f2bf(s[kc + 0][n]); o.y = (u16)f2bf(s[kc + 1][n]);
    o.z = (u16)f2bf(s[kc + 2][n]); o.w = (u16)f2bf(s[kc + 3][n]);
    *reinterpret_cast<ushort4*>(&wT[(size_t)(n0 + n) * K + k0 + kc]) = o;
  }
}

__global__ __launch_bounds__(256) void wconv_qkvo_k(const float* __restrict__ qW,
                                                    const float* __restrict__ kW,
                                                    const float* __restrict__ vW,
                                                    const float* __restrict__ oW,
                                                    u16* __restrict__ dst) {
  int z = blockIdx.z;
  int l = z >> 2, which = z & 3;
  const float* src = which == 0 ? qW : which == 1 ? kW : which == 2 ? vW : oW;
  wconv_tile(src + (size_t)l * D_ * D_, dst + (size_t)z * D_ * D_, D_, D_);
}

__global__ __launch_bounds__(256) void wconv_win_k(const float* __restrict__ w_in,
                                                   u16* __restrict__ dst) {
  int l = blockIdx.z;
  wconv_tile(w_in + (size_t)l * 512 * 4096, dst + (size_t)l * 4096 * 512, 512, 4096);
}

__global__ __launch_bounds__(256) void wconv_wout_k(const float* __restrict__ w_out,
                                                    u16* __restrict__ dst) {
  int l = blockIdx.z;
  wconv_tile(w_out + (size_t)l * 2048 * 512, dst + (size_t)l * 512 * 2048, 2048, 512);
}

// ---------------- MFMA GEMM: C = A@Bt^T (+bias) [+rope | f32 +=] ----------------
template<int EPI, int MI>
__global__ __launch_bounds__(256) void gemm_bf16_k(const u16* __restrict__ A,
                                                   const u16* __restrict__ Bt,
                                                   const float* __restrict__ bias,
                                                   void* __restrict__ Cout,
                                                   int M, int N, int K, int posmod,
                                                   const float* __restrict__ rc,
                                                   const float* __restrict__ rs) {
  __shared__ __align__(16) u16 As[2][MI * 32 * 32];
  __shared__ __align__(16) u16 Bs[2][128 * 32];
  int tid = threadIdx.x;
  int w = tid >> 6, lane = tid & 63;
  int lr = lane & 15, lg = lane >> 4;
  int row0 = blockIdx.y * (MI * 32), col0 = blockIdx.x * 128;
  int wr = w >> 1, wc = w & 1;
  f32x4 acc[MI][4] = {};

  int srow = lane >> 2;
  int skel = (lane & 3) * 8;

  auto stage = [&](int buf, int k0) {
    if constexpr (MI == 4) {
      #pragma unroll
      for (int ci = 0; ci < 2; ++ci) {
        int c = w * 2 + ci;
        gload16(A + (size_t)(row0 + c * 16 + srow) * K + k0 + skel, &As[buf][c * 512]);
      }
    } else {
      gload16(A + (size_t)(row0 + w * 16 + srow) * K + k0 + skel, &As[buf][w * 512]);
    }
    #pragma unroll
    for (int ci = 0; ci < 2; ++ci) {
      int c = w * 2 + ci;
      gload16(Bt + (size_t)(col0 + c * 16 + srow) * K + k0 + skel, &Bs[buf][c * 512]);
    }
  };

  stage(0, 0);
  __syncthreads();
  int nk = K >> 5;
  int buf = 0;
  for (int t = 0; t < nk; ++t) {
    if (t + 1 < nk) stage(buf ^ 1, (t + 1) * 32);
    bf16x8 af[MI], bfr[4];
    #pragma unroll
    for (int i = 0; i < MI; ++i)
      af[i] = *reinterpret_cast<const bf16x8*>(
          &As[buf][(wr * (16 * MI) + i * 16 + lr) * 32 + lg * 8]);
    #pragma unroll
    for (int j = 0; j < 4; ++j)
      bfr[j] = *reinterpret_cast<const bf16x8*>(&Bs[buf][(wc * 64 + j * 16 + lr) * 32 + lg * 8]);
    #pragma unroll
    for (int i = 0; i < MI; ++i)
      #pragma unroll
      for (int j = 0; j < 4; ++j)
        acc[i][j] = __builtin_amdgcn_mfma_f32_16x16x32_bf16(af[i], bfr[j], acc[i][j], 0, 0, 0);
    __syncthreads();
    buf ^= 1;
  }

  #pragma unroll
  for (int j = 0; j < 4; ++j) {
    int col = col0 + wc * 64 + j * 16 + lr;
    float bs = bias ? bias[col] : 0.f;
    #pragma unroll
    for (int i = 0; i < MI; ++i) {
      #pragma unroll
      for (int r = 0; r < 4; ++r) {
        int row = row0 + wr * (16 * MI) + i * 16 + lg * 4 + r;
        float v = acc[i][j][r] + bs;
        if (EPI == 1) {
          int pos = row % posmod;
          int d = col & 63;
          float c = rc[(size_t)pos * 32 + (d >> 1)];
          float s = rs[(size_t)pos * 32 + (d >> 1)];
          float partner = __shfl_xor(v, 1);
          v = (d & 1) ? (partner * s + v * c) : (v * c - partner * s);
        }
        if (EPI == 2) {
          float* Cf = (float*)Cout;
          Cf[(size_t)row * N + col] += v;
        } else {
          u16* Cb = (u16*)Cout;
          Cb[(size_t)row * N + col] = (u16)f2bf(v);
        }
      }
    }
  }
}

// ---------------- fused K+V projection ----------------
__global__ __launch_bounds__(256) void kv_gemm_k(const u16* __restrict__ A,
                                                 const u16* __restrict__ wkT,
                                                 const u16* __restrict__ wvT,
                                                 const float* __restrict__ kbias,
                                                 const float* __restrict__ vbias,
                                                 u16* __restrict__ kb,
                                                 u16* __restrict__ vb,
                                                 const float* __restrict__ rc,
                                                 const float* __restrict__ rs) {
  __shared__ __align__(16) u16 As[2][128 * 32];
  __shared__ __align__(16) u16 Bk[2][64 * 32];
  __shared__ __align__(16) u16 Bv[2][64 * 32];
  const int K = 512, N = 512;
  int tid = threadIdx.x;
  int w = tid >> 6, lane = tid & 63;
  int lr = lane & 15, lg = lane >> 4;
  int row0 = blockIdx.y * 128, col0 = blockIdx.x * 64;
  int wr = w >> 1, wc = w & 1;
  f32x4 ak_[4][2] = {};
  f32x4 av_[4][2] = {};

  int srow = lane >> 2;
  int skel = (lane & 3) * 8;

  auto stage = [&](int buf, int k0) {
    #pragma unroll
    for (int ci = 0; ci < 2; ++ci) {
      int c = w * 2 + ci;
      gload16(A + (size_t)(row0 + c * 16 + srow) * K + k0 + skel, &As[buf][c * 512]);
    }
    gload16(wkT + (size_t)(col0 + w * 16 + srow) * K + k0 + skel, &Bk[buf][w * 512]);
    gload16(wvT + (size_t)(col0 + w * 16 + srow) * K + k0 + skel, &Bv[buf][w * 512]);
  };

  stage(0, 0);
  __syncthreads();
  int buf = 0;
  for (int t = 0; t < 16; ++t) {
    if (t + 1 < 16) stage(buf ^ 1, (t + 1) * 32);
    bf16x8 af[4], bk[2], bv[2];
    #pragma unroll
    for (int i = 0; i < 4; ++i)
      af[i] = *reinterpret_cast<const bf16x8*>(&As[buf][(wr * 64 + i * 16 + lr) * 32 + lg * 8]);
    #pragma unroll
    for (int j = 0; j < 2; ++j) {
      bk[j] = *reinterpret_cast<const bf16x8*>(&Bk[buf][(wc * 32 + j * 16 + lr) * 32 + lg * 8]);
      bv[j] = *reinterpret_cast<const bf16x8*>(&Bv[buf][(wc * 32 + j * 16 + lr) * 32 + lg * 8]);
    }
    #pragma unroll
    for (int i = 0; i < 4; ++i)
      #pragma unroll
      for (int j = 0; j < 2; ++j) {
        ak_[i][j] = __builtin_amdgcn_mfma_f32_16x16x32_bf16(af[i], bk[j], ak_[i][j], 0, 0, 0);
        av_[i][j] = __builtin_amdgcn_mfma_f32_16x16x32_bf16(af[i], bv[j], av_[i][j], 0, 0, 0);
      }
    __syncthreads();
    buf ^= 1;
  }

  #pragma unroll
  for (int j = 0; j < 2; ++j) {
    int col = col0 + wc * 32 + j * 16 + lr;
    float kbs = kbias[col], vbs = vbias[col];
    int d = col & 63;
    #pragma unroll
    for (int i = 0; i < 4; ++i) {
      #pragma unroll
      for (int r = 0; r < 4; ++r) {
        int row = row0 + wr * 64 + i * 16 + lg * 4 + r;
        int pos = row % TK_;
        float vk = ak_[i][j][r] + kbs;
        float c = rc[(size_t)pos * 32 + (d >> 1)];
        float s = rs[(size_t)pos * 32 + (d >> 1)];
        float partner = __shfl_xor(vk, 1);
        vk = (d & 1) ? (partner * s + vk * c) : (vk * c - partner * s);
        kb[(size_t)row * N + col] = (u16)f2bf(vk);
        vb[(size_t)row * N + col] = (u16)f2bf(av_[i][j][r] + vbs);
      }
    }
  }
}

// ---------------- fused MLP-in MFMA ----------------
__global__ __launch_bounds__(256) void mlp_in_mfma_k(const u16* __restrict__ A,
                                                     const u16* __restrict__ wiT,
                                                     u16* __restrict__ Hout) {
  __shared__ __align__(16) u16 As[2][128 * 32];
  __shared__ __align__(16) u16 Bg[2][64 * 32];
  __shared__ __align__(16) u16 Bv[2][64 * 32];
  int tid = threadIdx.x;
  int w = tid >> 6, lane = tid & 63;
  int lr = lane & 15, lg = lane >> 4;
  int hc0 = blockIdx.x * 64, row0 = blockIdx.y * 128;
  int wr = w >> 1, wc = w & 1;
  f32x4 ag[4][2] = {};
  f32x4 av[4][2] = {};
  const int K = 512;

  int srow = lane >> 2;
  int skel = (lane & 3) * 8;

  auto stage = [&](int buf, int k0) {
    #pragma unroll
    for (int ci = 0; ci < 2; ++ci) {
      int c = w * 2 + ci;
      gload16(A + (size_t)(row0 + c * 16 + srow) * K + k0 + skel, &As[buf][c * 512]);
    }
    gload16(wiT + (size_t)(hc0 + w * 16 + srow) * K + k0 + skel, &Bg[buf][w * 512]);
    gload16(wiT + (size_t)(2048 + hc0 + w * 16 + srow) * K + k0 + skel, &Bv[buf][w * 512]);
  };

  stage(0, 0);
  __syncthreads();
  int buf = 0;
  for (int t = 0; t < 16; ++t) {
    if (t + 1 < 16) stage(buf ^ 1, (t + 1) * 32);
    bf16x8 af[4], bg[2], bv[2];
    #pragma unroll
    for (int i = 0; i < 4; ++i)
      af[i] = *reinterpret_cast<const bf16x8*>(&As[buf][(wr * 64 + i * 16 + lr) * 32 + lg * 8]);
    #pragma unroll
    for (int j = 0; j < 2; ++j) {
      bg[j] = *reinterpret_cast<const bf16x8*>(&Bg[buf][(wc * 32 + j * 16 + lr) * 32 + lg * 8]);
      bv[j] = *reinterpret_cast<const bf16x8*>(&Bv[buf][(wc * 32 + j * 16 + lr) * 32 + lg * 8]);
    }
    #pragma unroll
    for (int i = 0; i < 4; ++i)
      #pragma unroll
      for (int j = 0; j < 2; ++j) {
        ag[i][j] = __builtin_amdgcn_mfma_f32_16x16x32_bf16(af[i], bg[j], ag[i][j], 0, 0, 0);
        av[i][j] = __builtin_amdgcn_mfma_f32_16x16x32_bf16(af[i], bv[j], av[i][j], 0, 0, 0);
      }
    __syncthreads();
    buf ^= 1;
  }

  #pragma unroll
  for (int j = 0; j < 2; ++j) {
    int col = hc0 + wc * 32 + j * 16 + lr;
    #pragma unroll
    for (int i = 0; i < 4; ++i) {
      #pragma unroll
      for (int r = 0; r < 4; ++r) {
        int row = row0 + wr * 64 + i * 16 + lg * 4 + r;
        float g = ag[i][j][r];
        float sg = g / (1.f + __expf(-g));
        Hout[(size_t)row * 2048 + col] = (u16)f2bf(sg * av[i][j][r]);
      }
    }
  }
}

// ---------------- rmsnorm rows ----------------
template<int OUTBF>
__global__ __launch_bounds__(128) void rmsnorm_k(const float* __restrict__ in,
                                                 const float* __restrict__ scale,
                                                 void* __restrict__ out) {
  int row = blockIdx.x;
  int tid = threadIdx.x;
  float4 v = *reinterpret_cast<const float4*>(&in[(size_t)row * D_ + tid * 4]);
  float ss = v.x * v.x + v.y * v.y + v.z * v.z + v.w * v.w;
  ss = wave_sum_f(ss);
  __shared__ float red[2];
  if ((tid & 63) == 0) red[tid >> 6] = ss;
  __syncthreads();
  ss = red[0] + red[1];
  float inv = 1.0f / sqrtf(ss / (float)D_ + 1e-6f);
  float4 sc = *reinterpret_cast<const float4*>(&scale[tid * 4]);
  float o0 = v.x * inv * sc.x, o1 = v.y * inv * sc.y, o2 = v.z * inv * sc.z, o3 = v.w * inv * sc.w;
  if (OUTBF) {
    ushort4 o;
    o.x = (u16)f2bf(o0); o.y = (u16)f2bf(o1); o.z = (u16)f2bf(o2); o.w = (u16)f2bf(o3);
    *reinterpret_cast<ushort4*>((u16*)out + (size_t)row * D_ + tid * 4) = o;
  } else {
    *reinterpret_cast<float4*>((float*)out + (size_t)row * D_ + tid * 4) =
        make_float4(o0, o1, o2, o3);
  }
}

// ---------------- mem rows ----------------
__global__ __launch_bounds__(128) void memnorm_k(const float* __restrict__ tmp,
                                                 const float* __restrict__ scale,
                                                 u16* __restrict__ kv) {
  int o = blockIdx.x, b = blockIdx.y;
  int tid = threadIdx.x;
  float4 v = *reinterpret_cast<const float4*>(&tmp[(size_t)(b * O_ + o) * D_ + tid * 4]);
  float ss = v.x * v.x + v.y * v.y + v.z * v.z + v.w * v.w;
  ss = wave_sum_f(ss);
  __shared__ float red[2];
  if ((tid & 63) == 0) red[tid >> 6] = ss;
  __syncthreads();
  ss = red[0] + red[1];
  float inv = 1.0f / sqrtf(ss / (float)D_ + 1e-6f);
  float4 sc = *reinterpret_cast<const float4*>(&scale[tid * 4]);
  ushort4 oo;
  oo.x = (u16)f2bf(v.x * inv * sc.x); oo.y = (u16)f2bf(v.y * inv * sc.y);
  oo.z = (u16)f2bf(v.z * inv * sc.z); oo.w = (u16)f2bf(v.w * inv * sc.w);
  *reinterpret_cast<ushort4*>(&kv[(size_t)(b * TK_ + o) * D_ + tid * 4]) = oo;
}

// ---------------- engram rows ----------------
__global__ __launch_bounds__(128) void engram_k(const int* __restrict__ tokens,
                                                const int* __restrict__ mem_ids,
                                                const float* __restrict__ etab,
                                                const float* __restrict__ egate,
                                                const float* __restrict__ escale,
                                                u16* __restrict__ kv) {
  int t = blockIdx.x, b = blockIdx.y;
  int tid = threadIdx.x;
  unsigned int toks[4];
  #pragma unroll
  for (int i = 0; i < 4; ++i) {
    int idx = t - i;
    toks[i] = (idx >= 0) ? (unsigned int)tokens[b * T_ + idx]
                         : (unsigned int)mem_ids[b * O_ + O_ + idx];
  }
  int c = tid * 4;
  int h = c >> 7;
  int e = c & 127;
  unsigned int hs = 0;
  #pragma unroll
  for (int i = 0; i < 4; ++i) hs += toks[i] * PRIMES_[h][i];
  int idxh = (int)(hs % (unsigned int)MM_);
  float4 r = *reinterpret_cast<const float4*>(&etab[((size_t)idxh * EH_ + h) * EHD_ + e]);
  float4 g = *reinterpret_cast<const float4*>(&egate[h * EHD_ + e]);
  float4 val;
  val.x = r.x / (1.f + __expf(-g.x));
  val.y = r.y / (1.f + __expf(-g.y));
  val.z = r.z / (1.f + __expf(-g.z));
  val.w = r.w / (1.f + __expf(-g.w));
  float ss = val.x * val.x + val.y * val.y + val.z * val.z + val.w * val.w;
  ss = wave_sum_f(ss);
  __shared__ float red[2];
  if ((tid & 63) == 0) red[tid >> 6] = ss;
  __syncthreads();
  ss = red[0] + red[1];
  float inv = 1.0f / sqrtf(ss / (float)D_ + 1e-6f);
  float4 sc = *reinterpret_cast<const float4*>(&escale[c]);
  ushort4 oo;
  oo.x = (u16)f2bf(val.x * inv * sc.x); oo.y = (u16)f2bf(val.y * inv * sc.y);
  oo.z = (u16)f2bf(val.z * inv * sc.z); oo.w = (u16)f2bf(val.w * inv * sc.w);
  *reinterpret_cast<ushort4*>(&kv[(size_t)(b * TK_ + O_ + t) * D_ + c]) = oo;
}

// ---------------- embed + ssum inject ----------------
__global__ __launch_bounds__(128) void embed_k(const int* __restrict__ tokens,
                                               const float* __restrict__ etab,
                                               const float* __restrict__ ssp,
                                               const float* __restrict__ alpha_g,
                                               float* __restrict__ cx,
                                               u16* __restrict__ kv) {
  int t = blockIdx.x, b = blockIdx.y;
  int tid = threadIdx.x;
  int c = tid * 4;
  int tok = tokens[b * T_ + t];
  float4 e = *reinterpret_cast<const float4*>(&etab[(size_t)tok * D_ + c]);
  float4 sp = *reinterpret_cast<const float4*>(&ssp[b * D_ + c]);
  float4 ag = *reinterpret_cast<const float4*>(&alpha_g[c]);
  float4 x;
  x.x = e.x + sp.x / (1.f + __expf(-ag.x));
  x.y = e.y + sp.y / (1.f + __expf(-ag.y));
  x.z = e.z + sp.z / (1.f + __expf(-ag.z));
  x.w = e.w + sp.w / (1.f + __expf(-ag.w));
  *reinterpret_cast<float4*>(&cx[(size_t)(b * T_ + t) * D_ + c]) = x;
  ushort4 oo;
  oo.x = (u16)f2bf(x.x); oo.y = (u16)f2bf(x.y);
  oo.z = (u16)f2bf(x.z); oo.w = (u16)f2bf(x.w);
  *reinterpret_cast<ushort4*>(&kv[(size_t)(b * TK_ + O_ + T_ + t) * D_ + c]) = oo;
}

// ---------------- MFMA flash attention v2 ----------------
// XCD-local head mapping, balanced bx pairing, double-buffered staging with
// early global->reg issue, register 4x4 V-transpose (b64 LDS writes).
#define KIDX8(r, c) (((r) << 6) + ((c) ^ (((r) & 7) << 3)))
#define KIDX4(r, c) (((r) << 6) + ((c) ^ (((r) & 15) << 2)))

__global__ __launch_bounds__(256) void attn_mfma_k(const u16* __restrict__ qb,
                                                   const u16* __restrict__ kb,
                                                   const u16* __restrict__ vb,
                                                   const int* __restrict__ tokens,
                                                   u16* __restrict__ ob) {
  __shared__ __align__(16) short ks[2][64 * 64];
  __shared__ __align__(16) short vst[2][64 * 64];   // transposed: [d][k]
  __shared__ __align__(16) short ps[4][16 * 64];    // per-wave P tile
  __shared__ unsigned char vtok[T_];

  // fid -> (b, h, bx): h = fid&7 pins each head to one XCD (L2 locality for K/V);
  // slots s and s+32 get complementary bx so co-resident pairs have equal work.
  int fid = blockIdx.x;
  int h = fid & 7;
  int s = fid >> 3;
  int b, bx;
  if (s < 32) { bx = s >> 1; b = s & 1; }
  else { int s2 = s - 32; bx = 15 - (s2 >> 1); b = 2 + (s2 & 1); }

  int qt0 = bx * 64;
  int tid = threadIdx.x;
  int w = tid >> 6, lane = tid & 63;
  int lr = lane & 15;
  int lg = lane >> 4;
  int qw0 = qt0 + w * 16;

  for (int i = tid; i < T_; i += 256) vtok[i] = (tokens[b * T_ + i] != 0);

  bf16x8 aq[2];
  {
    const u16* qp = &qb[((size_t)(b * T_) + qw0 + lr) * D_ + h * 64];
    aq[0] = *reinterpret_cast<const bf16x8*>(qp + lg * 8);
    aq[1] = *reinterpret_cast<const bf16x8*>(qp + 32 + lg * 8);
  }

  float m_[4], lsum[4];
  f32x4 od[4];
  #pragma unroll
  for (int r = 0; r < 4; ++r) { m_[r] = -1e30f; lsum[r] = 0.f; }
  #pragma unroll
  for (int dt = 0; dt < 4; ++dt) od[dt] = (f32x4){0.f, 0.f, 0.f, 0.f};

  // K staging map: row sr (0..63), 16-col chunk sc
  int sr = tid >> 2;
  int sc = (tid & 3) * 16;
  // V staging map: 4x4 block (rows vr..vr+3, cols vc..vc+3)
  int vr = (tid >> 4) * 4;
  int vc = (tid & 15) * 4;

  int nt = 2 + 2 * (bx + 1);
  auto tile_pos = [&](int i, int& pos0, int& base, bool& masked) {
    if (i < 2) { pos0 = i * 64; base = 0; masked = false; }
    else if (i < 2 + (bx + 1)) { pos0 = O_ + (i - 2) * 64; base = O_; masked = true; }
    else { pos0 = O_ + T_ + (i - 2 - (bx + 1)) * 64; base = O_ + T_; masked = true; }
  };

  bf16x8 pk0, pk1;          // prefetched K regs
  short4 pv0, pv1, pv2, pv3; // prefetched V regs (4 rows x 4 cols)

  auto load_regs = [&](int pos0) {
    const u16* kg = &kb[((size_t)(b * TK_) + pos0 + sr) * D_ + h * 64 + sc];
    pk0 = *reinterpret_cast<const bf16x8*>(kg);
    pk1 = *reinterpret_cast<const bf16x8*>(kg + 8);
    const u16* vg = &vb[((size_t)(b * TK_) + pos0 + vr) * D_ + h * 64 + vc];
    pv0 = *reinterpret_cast<const short4*>(vg);
    pv1 = *reinterpret_cast<const short4*>(vg + D_);
    pv2 = *reinterpret_cast<const short4*>(vg + 2 * D_);
    pv3 = *reinterpret_cast<const short4*>(vg + 3 * D_);
  };

  auto write_lds = [&](int buf) {
    *reinterpret_cast<bf16x8*>(&ks[buf][KIDX8(sr, sc)]) = pk0;
    *reinterpret_cast<bf16x8*>(&ks[buf][KIDX8(sr, sc + 8)]) = pk1;
    short4 t0 = make_short4(pv0.x, pv1.x, pv2.x, pv3.x);
    short4 t1 = make_short4(pv0.y, pv1.y, pv2.y, pv3.y);
    short4 t2 = make_short4(pv0.z, pv1.z, pv2.z, pv3.z);
    short4 t3 = make_short4(pv0.w, pv1.w, pv2.w, pv3.w);
    *reinterpret_cast<short4*>(&vst[buf][KIDX4(vc + 0, vr)]) = t0;
    *reinterpret_cast<short4*>(&vst[buf][KIDX4(vc + 1, vr)]) = t1;
    *reinterpret_cast<short4*>(&vst[buf][KIDX4(vc + 2, vr)]) = t2;
    *reinterpret_cast<short4*>(&vst[buf][KIDX4(vc + 3, vr)]) = t3;
  };

  auto compute = [&](int buf, int pos0, int base, bool masked) {
    float sv[4][4];
    #pragma unroll
    for (int kt = 0; kt < 4; ++kt) {
      bf16x8 bk0 = *reinterpret_cast<const bf16x8*>(&ks[buf][KIDX8(kt * 16 + lr, lg * 8)]);
      bf16x8 bk1 = *reinterpret_cast<const bf16x8*>(&ks[buf][KIDX8(kt * 16 + lr, 32 + lg * 8)]);
      f32x4 sf = (f32x4){0.f, 0.f, 0.f, 0.f};
      sf = __builtin_amdgcn_mfma_f32_16x16x32_bf16(aq[0], bk0, sf, 0, 0, 0);
      sf = __builtin_amdgcn_mfma_f32_16x16x32_bf16(aq[1], bk1, sf, 0, 0, 0);
      if (masked) {
        int tk = pos0 + kt * 16 + lr - base;
        bool tokv = (vtok[tk] != 0);
        #pragma unroll
        for (int r = 0; r < 4; ++r) {
          int tq = qw0 + lg * 4 + r;
          sv[kt][r] = (tokv && tk <= tq) ? sf[r] * 0.125f : -1e30f;
        }
      } else {
        #pragma unroll
        for (int r = 0; r < 4; ++r) sv[kt][r] = sf[r] * 0.125f;
      }
    }
    float al[4], mnew[4], psum[4];
    #pragma unroll
    for (int r = 0; r < 4; ++r) {
      float t = fmaxf(fmaxf(sv[0][r], sv[1][r]), fmaxf(sv[2][r], sv[3][r]));
      t = fmaxf(t, __shfl_xor(t, 1)); t = fmaxf(t, __shfl_xor(t, 2));
      t = fmaxf(t, __shfl_xor(t, 4)); t = fmaxf(t, __shfl_xor(t, 8));
      mnew[r] = fmaxf(m_[r], t);
      al[r] = __expf(m_[r] - mnew[r]);
      m_[r] = mnew[r];
      psum[r] = 0.f;
    }
    short* psw = ps[w];
    #pragma unroll
    for (int kt = 0; kt < 4; ++kt) {
      #pragma unroll
      for (int r = 0; r < 4; ++r) {
        float pe = __expf(sv[kt][r] - mnew[r]);
        psum[r] += pe;
        psw[KIDX8(lg * 4 + r, kt * 16 + lr)] = f2bf(pe);
      }
    }
    #pragma unroll
    for (int r = 0; r < 4; ++r) {
      float t = psum[r];
      t += __shfl_xor(t, 1); t += __shfl_xor(t, 2);
      t += __shfl_xor(t, 4); t += __shfl_xor(t, 8);
      lsum[r] = lsum[r] * al[r] + t;
    }
    #pragma unroll
    for (int dt = 0; dt < 4; ++dt) {
      f32x4 o = od[dt];
      o[0] *= al[0]; o[1] *= al[1]; o[2] *= al[2]; o[3] *= al[3];
      od[dt] = o;
    }
    bf16x8 pa0 = *reinterpret_cast<const bf16x8*>(&psw[KIDX8(lr, lg * 8)]);
    bf16x8 pa1 = *reinterpret_cast<const bf16x8*>(&psw[KIDX8(lr, 32 + lg * 8)]);
    #pragma unroll
    for (int dt = 0; dt < 4; ++dt) {
      short4 lo0 = *reinterpret_cast<const short4*>(&vst[buf][KIDX4(dt * 16 + lr, lg * 8)]);
      short4 hi0 = *reinterpret_cast<const short4*>(&vst[buf][KIDX4(dt * 16 + lr, lg * 8 + 4)]);
      short4 lo1 = *reinterpret_cast<const short4*>(&vst[buf][KIDX4(dt * 16 + lr, 32 + lg * 8)]);
      short4 hi1 = *reinterpret_cast<const short4*>(&vst[buf][KIDX4(dt * 16 + lr, 36 + lg * 8)]);
      bf16x8 bv0 = {lo0.x, lo0.y, lo0.z, lo0.w, hi0.x, hi0.y, hi0.z, hi0.w};
      bf16x8 bv1 = {lo1.x, lo1.y, lo1.z, lo1.w, hi1.x, hi1.y, hi1.z, hi1.w};
      od[dt] = __builtin_amdgcn_mfma_f32_16x16x32_bf16(pa0, bv0, od[dt], 0, 0, 0);
      od[dt] = __builtin_amdgcn_mfma_f32_16x16x32_bf16(pa1, bv1, od[dt], 0, 0, 0);
    }
  };

  // prologue: stage tile 0
  {
    int pos0, base; bool masked;
    tile_pos(0, pos0, base, masked);
    load_regs(pos0);
    write_lds(0);
  }
  __syncthreads();

  for (int i = 0; i < nt; ++i) {
    if (i + 1 < nt) {
      int npos, nbase; bool nmask;
      tile_pos(i + 1, npos, nbase, nmask);
      load_regs(npos);  // loads in flight during compute
    }
    int pos0, base; bool masked;
    tile_pos(i, pos0, base, masked);
    compute(i & 1, pos0, base, masked);
    __syncthreads();
    if (i + 1 < nt) {
      write_lds((i + 1) & 1);
      __syncthreads();
    }
  }

  #pragma unroll
  for (int dt = 0; dt < 4; ++dt) {
    #pragma unroll
    for (int r = 0; r < 4; ++r) {
      int q = qw0 + lg * 4 + r;
      ob[((size_t)(b * T_) + q) * D_ + h * 64 + dt * 16 + lr] = (u16)f2bf(od[dt][r] / lsum[r]);
    }
  }
}

extern "C" void kernel_launch(void* const* d_in, const int* in_sizes, int n_in,
                              void* d_out, int out_size, void* d_ws, size_t ws_size,
                              hipStream_t stream) {
  (void)in_sizes; (void)n_in; (void)out_size; (void)ws_size;
  const int* tokens = (const int*)d_in[0];
  const int* mem_ids = (const int*)d_in[1];
  const float* mem_emb = (const float*)d_in[2];
  const float* ssum = (const float*)d_in[3];
  const float* embed = (const float*)d_in[4];
  const float* engram_t = (const float*)d_in[5];
  const float* engram_g = (const float*)d_in[6];
  const float* engram_s = (const float*)d_in[7];
  const float* mem_W = (const float*)d_in[8];
  const float* mem_b = (const float*)d_in[9];
  const float* mem_s = (const float*)d_in[10];
  const float* alpha_g = (const float*)d_in[11];
  const float* ssum_W = (const float*)d_in[12];
  const float* ln1 = (const float*)d_in[13];
  const float* qW = (const float*)d_in[14];
  const float* qbias = (const float*)d_in[15];
  const float* kW = (const float*)d_in[16];
  const float* kbias = (const float*)d_in[17];
  const float* vW = (const float*)d_in[18];
  const float* vbias = (const float*)d_in[19];
  const float* oW = (const float*)d_in[20];
  const float* obias = (const float*)d_in[21];
  const float* ln2 = (const float*)d_in[22];
  const float* w_in = (const float*)d_in[23];
  const float* w_out = (const float*)d_in[24];
  const float* final_s = (const float*)d_in[25];

  char* p = (char*)d_ws;
  auto alloc = [&](size_t bytes) { char* r = p; p += (bytes + 255) & ~(size_t)255; return r; };
  u16* kv_b   = (u16*)alloc((size_t)B_ * TK_ * D_ * 2);
  float* cx   = (float*)alloc((size_t)B_ * T_ * D_ * 4);
  u16* nx_b   = (u16*)alloc((size_t)B_ * T_ * D_ * 2);   // also ob (attn out)
  u16* qb_b   = (u16*)alloc((size_t)B_ * T_ * D_ * 2);   // also mem_tmp f32
  u16* kb_b   = (u16*)alloc((size_t)B_ * TK_ * D_ * 2);  // hb spans kb_b+vb_b
  u16* vb_b   = (u16*)alloc((size_t)B_ * TK_ * D_ * 2);
  u16* wqkvoT = (u16*)alloc((size_t)L_ * 4 * D_ * D_ * 2);
  u16* wiT    = (u16*)alloc((size_t)L_ * 4096 * 512 * 2);
  u16* woutT  = (u16*)alloc((size_t)L_ * 512 * 2048 * 2);
  float* ssp  = (float*)alloc((size_t)B_ * D_ * 4);
  float* rc   = (float*)alloc((size_t)TK_ * 32 * 4);
  float* rs   = (float*)alloc((size_t)TK_ * 32 * 4);
  float* mem_tmp = (float*)qb_b;
  u16* ob_b = nx_b;
  u16* hb = kb_b;
  (void)vb_b;

  // preamble + batched weight conversion
  rope_table_k<<<TK_ * 32 / 64, 64, 0, stream>>>(rc, rs);
  wconv_qkvo_k<<<dim3(8, 8, L_ * 4), 256, 0, stream>>>(qW, kW, vW, oW, wqkvoT);
  wconv_win_k<<<dim3(64, 8, L_), 256, 0, stream>>>(w_in, wiT);
  wconv_wout_k<<<dim3(8, 32, L_), 256, 0, stream>>>(w_out, woutT);
  ssum_proj_k<<<dim3(2, B_), 256, 0, stream>>>(ssum, ssum_W, ssp);
  sgemm_k<<<dim3(8, 8), 256, 0, stream>>>(mem_emb, mem_W, mem_b, mem_tmp, B_ * O_, D_, D_);
  memnorm_k<<<dim3(O_, B_), 128, 0, stream>>>(mem_tmp, mem_s, kv_b);
  engram_k<<<dim3(T_, B_), 128, 0, stream>>>(tokens, mem_ids, engram_t, engram_g, engram_s, kv_b);
  embed_k<<<dim3(T_, B_), 128, 0, stream>>>(tokens, embed, ssp, alpha_g, cx, kv_b);

  const size_t WSZ = (size_t)D_ * D_;
  for (int l = 0; l < L_; ++l) {
    const u16* wqT = wqkvoT + ((size_t)l * 4 + 0) * WSZ;
    const u16* wkT = wqkvoT + ((size_t)l * 4 + 1) * WSZ;
    const u16* wvT = wqkvoT + ((size_t)l * 4 + 2) * WSZ;
    const u16* woT = wqkvoT + ((size_t)l * 4 + 3) * WSZ;
    const u16* wil = wiT + (size_t)l * 4096 * 512;
    const u16* wol = woutT + (size_t)l * 512 * 2048;

    rmsnorm_k<1><<<B_ * T_, 128, 0, stream>>>(cx, ln1 + l * D_, nx_b);
    gemm_bf16_k<1, 2><<<dim3(4, 64), 256, 0, stream>>>(nx_b, wqT, qbias + l * D_, qb_b,
                                                       B_ * T_, D_, D_, T_, rc, rs);
    kv_gemm_k<<<dim3(8, 68), 256, 0, stream>>>(kv_b, wkT, wvT, kbias + l * D_, vbias + l * D_,
                                               kb_b, vb_b, rc, rs);
    attn_mfma_k<<<dim3(512), 256, 0, stream>>>(qb_b, kb_b, vb_b, tokens, ob_b);
    gemm_bf16_k<2, 2><<<dim3(4, 64), 256, 0, stream>>>(ob_b, woT, obias + l * D_, cx,
                                                       B_ * T_, D_, D_, 0, nullptr, nullptr);
    rmsnorm_k<1><<<B_ * T_, 128, 0, stream>>>(cx, ln2 + l * D_, nx_b);
    mlp_in_mfma_k<<<dim3(32, 32), 256, 0, stream>>>(nx_b, wil, hb);
    gemm_bf16_k<2, 2><<<dim3(4, 64), 256, 0, stream>>>(hb, wol, nullptr, cx,
                                                       B_ * T_, D_, 2048, 0, nullptr, nullptr);
  }
  rmsnorm_k<0><<<B_ * T_, 128, 0, stream>>>(cx, final_s, d_out);
}

// Round 6
// 1284.530 us; speedup vs baseline: 10.2735x; 1.0664x over previous
//
#include <hip/hip_runtime.h>
#include <hip/hip_bf16.h>
#include <math.h>

#define B_ 4
#define T_ 1024
#define O_ 128
#define D_ 512
#define H_ 8
#define L_ 6
#define TK_ 2176
#define MM_ 100000
#define EH_ 4
#define EHD_ 128
#define HD_ 64

typedef float f32x4 __attribute__((ext_vector_type(4)));
typedef short bf16x8 __attribute__((ext_vector_type(8)));
typedef unsigned short u16;

// PRIMES per reference: base=131, x=base+h*1009; row[i]=x; x=x*31+1 (uint32 wrap)
__device__ __constant__ unsigned int PRIMES_[4][4] = {
  {131u,  4062u,  125923u, 3903614u},
  {1140u, 35341u, 1095572u, 33962733u},
  {2149u, 66620u, 2065221u, 64021852u},
  {3158u, 97899u, 3034870u, 94080971u},
};

__device__ __forceinline__ float wave_sum_f(float v) {
  #pragma unroll
  for (int off = 32; off; off >>= 1) v += __shfl_xor(v, off);
  return v;
}

__device__ __forceinline__ short f2bf(float f) {
  unsigned int u = __float_as_uint(f);
  unsigned int r = (u + 0x7fffu + ((u >> 16) & 1u)) >> 16;
  return (short)r;
}

__device__ __forceinline__ void gload16(const void* g, void* l) {
  __builtin_amdgcn_global_load_lds((const __attribute__((address_space(1))) void*)g,
                                   (__attribute__((address_space(3))) void*)l, 16, 0, 0);
}

// ---------------- rope tables: cos/sin [TK][32] ----------------
__global__ __launch_bounds__(64) void rope_table_k(float* __restrict__ rc,
                                                   float* __restrict__ rs) {
  int i = blockIdx.x * 64 + threadIdx.x;
  int t = i >> 5, j = i & 31;
  float freq = __powf(10000.0f, -(float)j / 32.0f);
  float ang = (float)t * freq;
  rc[i] = cosf(ang);
  rs[i] = sinf(ang);
}

// ---------------- ssum @ ssum_W -> ssp[B][D] ----------------
__global__ __launch_bounds__(256) void ssum_proj_k(const float* __restrict__ ssum,
                                                   const float* __restrict__ sW,
                                                   float* __restrict__ ssp) {
  int col = blockIdx.x * 256 + threadIdx.x;
  int b = blockIdx.y;
  float acc = 0.f;
  for (int d = 0; d < D_; ++d) acc += ssum[b * D_ + d] * sW[(size_t)d * D_ + col];
  ssp[b * D_ + col] = acc;
}

// ---------------- f32 tiled GEMM (preamble mem projection only) ----------------
__global__ __launch_bounds__(256) void sgemm_k(const float* __restrict__ A,
                                               const float* __restrict__ W,
                                               const float* __restrict__ bias,
                                               float* __restrict__ C,
                                               int M, int N, int K) {
  __shared__ float As[16][68];
  __shared__ float Bs[16][68];
  int tid = threadIdx.x;
  int row0 = blockIdx.y * 64;
  int col0 = blockIdx.x * 64;
  int tx = tid & 15, ty = tid >> 4;
  int am = tid >> 2, ak = (tid & 3) * 4;
  int bk = tid >> 4, bc = (tid & 15) * 4;
  float acc[4][4] = {};
  for (int k0 = 0; k0 < K; k0 += 16) {
    float4 av = *reinterpret_cast<const float4*>(&A[(size_t)(row0 + am) * K + k0 + ak]);
    As[ak + 0][am] = av.x; As[ak + 1][am] = av.y; As[ak + 2][am] = av.z; As[ak + 3][am] = av.w;
    float4 bv = *reinterpret_cast<const float4*>(&W[(size_t)(k0 + bk) * N + col0 + bc]);
    *reinterpret_cast<float4*>(&Bs[bk][bc]) = bv;
    __syncthreads();
    #pragma unroll
    for (int kk = 0; kk < 16; ++kk) {
      float4 a4 = *reinterpret_cast<const float4*>(&As[kk][ty * 4]);
      float4 b4 = *reinterpret_cast<const float4*>(&Bs[kk][tx * 4]);
      float a[4] = {a4.x, a4.y, a4.z, a4.w};
      float b[4] = {b4.x, b4.y, b4.z, b4.w};
      #pragma unroll
      for (int i = 0; i < 4; ++i)
        #pragma unroll
        for (int j = 0; j < 4; ++j) acc[i][j] += a[i] * b[j];
    }
    __syncthreads();
  }
  int cbase = col0 + tx * 4;
  float4 b4 = *reinterpret_cast<const float4*>(&bias[cbase]);
  float bb[4] = {b4.x, b4.y, b4.z, b4.w};
  #pragma unroll
  for (int i = 0; i < 4; ++i) {
    int row = row0 + ty * 4 + i;
    *reinterpret_cast<float4*>(&C[(size_t)row * N + cbase]) =
        make_float4(acc[i][0] + bb[0], acc[i][1] + bb[1], acc[i][2] + bb[2], acc[i][3] + bb[3]);
  }
}

// ---------------- batched weight convert+transpose: f32 [K][N] -> bf16 [N][K] ----------------
__device__ __forceinline__ void wconv_tile(const float* __restrict__ W, u16* __restrict__ wT,
                                           int K, int N) {
  __shared__ float s[64][65];
  int n0 = blockIdx.x * 64, k0 = blockIdx.y * 64;
  int tid = threadIdx.x;
  int kr = tid >> 4, nc = (tid & 15) * 4;
  #pragma unroll
  for (int kk = 0; kk < 4; ++kk) {
    float4 f = *reinterpret_cast<const float4*>(&W[(size_t)(k0 + kr + kk * 16) * N + n0 + nc]);
    s[kr + kk * 16][nc + 0] = f.x; s[kr + kk * 16][nc + 1] = f.y;
    s[kr + kk * 16][nc + 2] = f.z; s[kr + kk * 16][nc + 3] = f.w;
  }
  __syncthreads();
  int nr = tid >> 4, kc = (tid & 15) * 4;
  #pragma unroll
  for (int nn = 0; nn < 4; ++nn) {
    int n = nr + nn * 16;
    ushort4 o;
    o.x = (u16)f2bf(s[kc + 0][n]); o.y = (u16)f2bf(s[kc + 1][n]);
    o.z = (u16)f2bf(s[kc + 2][n]); o.w = (u16)f2bf(s[kc + 3][n]);
    *reinterpret_cast<ushort4*>(&wT[(size_t)(n0 + n) * K + k0 + kc]) = o;
  }
}

__global__ __launch_bounds__(256) void wconv_qkvo_k(const float* __restrict__ qW,
                                                    const float* __restrict__ kW,
                                                    const float* __restrict__ vW,
                                                    const float* __restrict__ oW,
                                                    u16* __restrict__ dst) {
  int z = blockIdx.z;
  int l = z >> 2, which = z & 3;
  const float* src = which == 0 ? qW : which == 1 ? kW : which == 2 ? vW : oW;
  wconv_tile(src + (size_t)l * D_ * D_, dst + (size_t)z * D_ * D_, D_, D_);
}

__global__ __launch_bounds__(256) void wconv_win_k(const float* __restrict__ w_in,
                                                   u16* __restrict__ dst) {
  int l = blockIdx.z;
  wconv_tile(w_in + (size_t)l * 512 * 4096, dst + (size_t)l * 4096 * 512, 512, 4096);
}

__global__ __launch_bounds__(256) void wconv_wout_k(const float* __restrict__ w_out,
                                                    u16* __restrict__ dst) {
  int l = blockIdx.z;
  wconv_tile(w_out + (size_t)l * 2048 * 512, dst + (size_t)l * 512 * 2048, 2048, 512);
}

// ---------------- MFMA GEMM: C = A@Bt^T (+bias) [+rope | f32 +=] ----------------
template<int EPI, int MI>
__global__ __launch_bounds__(256) void gemm_bf16_k(const u16* __restrict__ A,
                                                   const u16* __restrict__ Bt,
                                                   const float* __restrict__ bias,
                                                   void* __restrict__ Cout,
                                                   int M, int N, int K, int posmod,
                                                   const float* __restrict__ rc,
                                                   const float* __restrict__ rs) {
  __shared__ __align__(16) u16 As[2][MI * 32 * 32];
  __shared__ __align__(16) u16 Bs[2][128 * 32];
  int tid = threadIdx.x;
  int w = tid >> 6, lane = tid & 63;
  int lr = lane & 15, lg = lane >> 4;
  int row0 = blockIdx.y * (MI * 32), col0 = blockIdx.x * 128;
  int wr = w >> 1, wc = w & 1;
  f32x4 acc[MI][4] = {};

  int srow = lane >> 2;
  int skel = (lane & 3) * 8;

  auto stage = [&](int buf, int k0) {
    if constexpr (MI == 4) {
      #pragma unroll
      for (int ci = 0; ci < 2; ++ci) {
        int c = w * 2 + ci;
        gload16(A + (size_t)(row0 + c * 16 + srow) * K + k0 + skel, &As[buf][c * 512]);
      }
    } else {
      gload16(A + (size_t)(row0 + w * 16 + srow) * K + k0 + skel, &As[buf][w * 512]);
    }
    #pragma unroll
    for (int ci = 0; ci < 2; ++ci) {
      int c = w * 2 + ci;
      gload16(Bt + (size_t)(col0 + c * 16 + srow) * K + k0 + skel, &Bs[buf][c * 512]);
    }
  };

  stage(0, 0);
  __syncthreads();
  int nk = K >> 5;
  int buf = 0;
  for (int t = 0; t < nk; ++t) {
    if (t + 1 < nk) stage(buf ^ 1, (t + 1) * 32);
    bf16x8 af[MI], bfr[4];
    #pragma unroll
    for (int i = 0; i < MI; ++i)
      af[i] = *reinterpret_cast<const bf16x8*>(
          &As[buf][(wr * (16 * MI) + i * 16 + lr) * 32 + lg * 8]);
    #pragma unroll
    for (int j = 0; j < 4; ++j)
      bfr[j] = *reinterpret_cast<const bf16x8*>(&Bs[buf][(wc * 64 + j * 16 + lr) * 32 + lg * 8]);
    #pragma unroll
    for (int i = 0; i < MI; ++i)
      #pragma unroll
      for (int j = 0; j < 4; ++j)
        acc[i][j] = __builtin_amdgcn_mfma_f32_16x16x32_bf16(af[i], bfr[j], acc[i][j], 0, 0, 0);
    __syncthreads();
    buf ^= 1;
  }

  #pragma unroll
  for (int j = 0; j < 4; ++j) {
    int col = col0 + wc * 64 + j * 16 + lr;
    float bs = bias ? bias[col] : 0.f;
    #pragma unroll
    for (int i = 0; i < MI; ++i) {
      #pragma unroll
      for (int r = 0; r < 4; ++r) {
        int row = row0 + wr * (16 * MI) + i * 16 + lg * 4 + r;
        float v = acc[i][j][r] + bs;
        if (EPI == 1) {
          int pos = row % posmod;
          int d = col & 63;
          float c = rc[(size_t)pos * 32 + (d >> 1)];
          float s = rs[(size_t)pos * 32 + (d >> 1)];
          float partner = __shfl_xor(v, 1);
          v = (d & 1) ? (partner * s + v * c) : (v * c - partner * s);
        }
        if (EPI == 2) {
          float* Cf = (float*)Cout;
          Cf[(size_t)row * N + col] += v;
        } else {
          u16* Cb = (u16*)Cout;
          Cb[(size_t)row * N + col] = (u16)f2bf(v);
        }
      }
    }
  }
}

// ---------------- fused K+V projection ----------------
__global__ __launch_bounds__(256) void kv_gemm_k(const u16* __restrict__ A,
                                                 const u16* __restrict__ wkT,
                                                 const u16* __restrict__ wvT,
                                                 const float* __restrict__ kbias,
                                                 const float* __restrict__ vbias,
                                                 u16* __restrict__ kb,
                                                 u16* __restrict__ vb,
                                                 const float* __restrict__ rc,
                                                 const float* __restrict__ rs) {
  __shared__ __align__(16) u16 As[2][128 * 32];
  __shared__ __align__(16) u16 Bk[2][64 * 32];
  __shared__ __align__(16) u16 Bv[2][64 * 32];
  const int K = 512, N = 512;
  int tid = threadIdx.x;
  int w = tid >> 6, lane = tid & 63;
  int lr = lane & 15, lg = lane >> 4;
  int row0 = blockIdx.y * 128, col0 = blockIdx.x * 64;
  int wr = w >> 1, wc = w & 1;
  f32x4 ak_[4][2] = {};
  f32x4 av_[4][2] = {};

  int srow = lane >> 2;
  int skel = (lane & 3) * 8;

  auto stage = [&](int buf, int k0) {
    #pragma unroll
    for (int ci = 0; ci < 2; ++ci) {
      int c = w * 2 + ci;
      gload16(A + (size_t)(row0 + c * 16 + srow) * K + k0 + skel, &As[buf][c * 512]);
    }
    gload16(wkT + (size_t)(col0 + w * 16 + srow) * K + k0 + skel, &Bk[buf][w * 512]);
    gload16(wvT + (size_t)(col0 + w * 16 + srow) * K + k0 + skel, &Bv[buf][w * 512]);
  };

  stage(0, 0);
  __syncthreads();
  int buf = 0;
  for (int t = 0; t < 16; ++t) {
    if (t + 1 < 16) stage(buf ^ 1, (t + 1) * 32);
    bf16x8 af[4], bk[2], bv[2];
    #pragma unroll
    for (int i = 0; i < 4; ++i)
      af[i] = *reinterpret_cast<const bf16x8*>(&As[buf][(wr * 64 + i * 16 + lr) * 32 + lg * 8]);
    #pragma unroll
    for (int j = 0; j < 2; ++j) {
      bk[j] = *reinterpret_cast<const bf16x8*>(&Bk[buf][(wc * 32 + j * 16 + lr) * 32 + lg * 8]);
      bv[j] = *reinterpret_cast<const bf16x8*>(&Bv[buf][(wc * 32 + j * 16 + lr) * 32 + lg * 8]);
    }
    #pragma unroll
    for (int i = 0; i < 4; ++i)
      #pragma unroll
      for (int j = 0; j < 2; ++j) {
        ak_[i][j] = __builtin_amdgcn_mfma_f32_16x16x32_bf16(af[i], bk[j], ak_[i][j], 0, 0, 0);
        av_[i][j] = __builtin_amdgcn_mfma_f32_16x16x32_bf16(af[i], bv[j], av_[i][j], 0, 0, 0);
      }
    __syncthreads();
    buf ^= 1;
  }

  #pragma unroll
  for (int j = 0; j < 2; ++j) {
    int col = col0 + wc * 32 + j * 16 + lr;
    float kbs = kbias[col], vbs = vbias[col];
    int d = col & 63;
    #pragma unroll
    for (int i = 0; i < 4; ++i) {
      #pragma unroll
      for (int r = 0; r < 4; ++r) {
        int row = row0 + wr * 64 + i * 16 + lg * 4 + r;
        int pos = row % TK_;
        float vk = ak_[i][j][r] + kbs;
        float c = rc[(size_t)pos * 32 + (d >> 1)];
        float s = rs[(size_t)pos * 32 + (d >> 1)];
        float partner = __shfl_xor(vk, 1);
        vk = (d & 1) ? (partner * s + vk * c) : (vk * c - partner * s);
        kb[(size_t)row * N + col] = (u16)f2bf(vk);
        vb[(size_t)row * N + col] = (u16)f2bf(av_[i][j][r] + vbs);
      }
    }
  }
}

// ---------------- fused MLP-in MFMA ----------------
__global__ __launch_bounds__(256) void mlp_in_mfma_k(const u16* __restrict__ A,
                                                     const u16* __restrict__ wiT,
                                                     u16* __restrict__ Hout) {
  __shared__ __align__(16) u16 As[2][128 * 32];
  __shared__ __align__(16) u16 Bg[2][64 * 32];
  __shared__ __align__(16) u16 Bv[2][64 * 32];
  int tid = threadIdx.x;
  int w = tid >> 6, lane = tid & 63;
  int lr = lane & 15, lg = lane >> 4;
  int hc0 = blockIdx.x * 64, row0 = blockIdx.y * 128;
  int wr = w >> 1, wc = w & 1;
  f32x4 ag[4][2] = {};
  f32x4 av[4][2] = {};
  const int K = 512;

  int srow = lane >> 2;
  int skel = (lane & 3) * 8;

  auto stage = [&](int buf, int k0) {
    #pragma unroll
    for (int ci = 0; ci < 2; ++ci) {
      int c = w * 2 + ci;
      gload16(A + (size_t)(row0 + c * 16 + srow) * K + k0 + skel, &As[buf][c * 512]);
    }
    gload16(wiT + (size_t)(hc0 + w * 16 + srow) * K + k0 + skel, &Bg[buf][w * 512]);
    gload16(wiT + (size_t)(2048 + hc0 + w * 16 + srow) * K + k0 + skel, &Bv[buf][w * 512]);
  };

  stage(0, 0);
  __syncthreads();
  int buf = 0;
  for (int t = 0; t < 16; ++t) {
    if (t + 1 < 16) stage(buf ^ 1, (t + 1) * 32);
    bf16x8 af[4], bg[2], bv[2];
    #pragma unroll
    for (int i = 0; i < 4; ++i)
      af[i] = *reinterpret_cast<const bf16x8*>(&As[buf][(wr * 64 + i * 16 + lr) * 32 + lg * 8]);
    #pragma unroll
    for (int j = 0; j < 2; ++j) {
      bg[j] = *reinterpret_cast<const bf16x8*>(&Bg[buf][(wc * 32 + j * 16 + lr) * 32 + lg * 8]);
      bv[j] = *reinterpret_cast<const bf16x8*>(&Bv[buf][(wc * 32 + j * 16 + lr) * 32 + lg * 8]);
    }
    #pragma unroll
    for (int i = 0; i < 4; ++i)
      #pragma unroll
      for (int j = 0; j < 2; ++j) {
        ag[i][j] = __builtin_amdgcn_mfma_f32_16x16x32_bf16(af[i], bg[j], ag[i][j], 0, 0, 0);
        av[i][j] = __builtin_amdgcn_mfma_f32_16x16x32_bf16(af[i], bv[j], av[i][j], 0, 0, 0);
      }
    __syncthreads();
    buf ^= 1;
  }

  #pragma unroll
  for (int j = 0; j < 2; ++j) {
    int col = hc0 + wc * 32 + j * 16 + lr;
    #pragma unroll
    for (int i = 0; i < 4; ++i) {
      #pragma unroll
      for (int r = 0; r < 4; ++r) {
        int row = row0 + wr * 64 + i * 16 + lg * 4 + r;
        float g = ag[i][j][r];
        float sg = g / (1.f + __expf(-g));
        Hout[(size_t)row * 2048 + col] = (u16)f2bf(sg * av[i][j][r]);
      }
    }
  }
}

// ---------------- rmsnorm rows ----------------
template<int OUTBF>
__global__ __launch_bounds__(128) void rmsnorm_k(const float* __restrict__ in,
                                                 const float* __restrict__ scale,
                                                 void* __restrict__ out) {
  int row = blockIdx.x;
  int tid = threadIdx.x;
  float4 v = *reinterpret_cast<const float4*>(&in[(size_t)row * D_ + tid * 4]);
  float ss = v.x * v.x + v.y * v.y + v.z * v.z + v.w * v.w;
  ss = wave_sum_f(ss);
  __shared__ float red[2];
  if ((tid & 63) == 0) red[tid >> 6] = ss;
  __syncthreads();
  ss = red[0] + red[1];
  float inv = 1.0f / sqrtf(ss / (float)D_ + 1e-6f);
  float4 sc = *reinterpret_cast<const float4*>(&scale[tid * 4]);
  float o0 = v.x * inv * sc.x, o1 = v.y * inv * sc.y, o2 = v.z * inv * sc.z, o3 = v.w * inv * sc.w;
  if (OUTBF) {
    ushort4 o;
    o.x = (u16)f2bf(o0); o.y = (u16)f2bf(o1); o.z = (u16)f2bf(o2); o.w = (u16)f2bf(o3);
    *reinterpret_cast<ushort4*>((u16*)out + (size_t)row * D_ + tid * 4) = o;
  } else {
    *reinterpret_cast<float4*>((float*)out + (size_t)row * D_ + tid * 4) =
        make_float4(o0, o1, o2, o3);
  }
}

// ---------------- mem rows ----------------
__global__ __launch_bounds__(128) void memnorm_k(const float* __restrict__ tmp,
                                                 const float* __restrict__ scale,
                                                 u16* __restrict__ kv) {
  int o = blockIdx.x, b = blockIdx.y;
  int tid = threadIdx.x;
  float4 v = *reinterpret_cast<const float4*>(&tmp[(size_t)(b * O_ + o) * D_ + tid * 4]);
  float ss = v.x * v.x + v.y * v.y + v.z * v.z + v.w * v.w;
  ss = wave_sum_f(ss);
  __shared__ float red[2];
  if ((tid & 63) == 0) red[tid >> 6] = ss;
  __syncthreads();
  ss = red[0] + red[1];
  float inv = 1.0f / sqrtf(ss / (float)D_ + 1e-6f);
  float4 sc = *reinterpret_cast<const float4*>(&scale[tid * 4]);
  ushort4 oo;
  oo.x = (u16)f2bf(v.x * inv * sc.x); oo.y = (u16)f2bf(v.y * inv * sc.y);
  oo.z = (u16)f2bf(v.z * inv * sc.z); oo.w = (u16)f2bf(v.w * inv * sc.w);
  *reinterpret_cast<ushort4*>(&kv[(size_t)(b * TK_ + o) * D_ + tid * 4]) = oo;
}

// ---------------- engram rows ----------------
__global__ __launch_bounds__(128) void engram_k(const int* __restrict__ tokens,
                                                const int* __restrict__ mem_ids,
                                                const float* __restrict__ etab,
                                                const float* __restrict__ egate,
                                                const float* __restrict__ escale,
                                                u16* __restrict__ kv) {
  int t = blockIdx.x, b = blockIdx.y;
  int tid = threadIdx.x;
  unsigned int toks[4];
  #pragma unroll
  for (int i = 0; i < 4; ++i) {
    int idx = t - i;
    toks[i] = (idx >= 0) ? (unsigned int)tokens[b * T_ + idx]
                         : (unsigned int)mem_ids[b * O_ + O_ + idx];
  }
  int c = tid * 4;
  int h = c >> 7;
  int e = c & 127;
  unsigned int hs = 0;
  #pragma unroll
  for (int i = 0; i < 4; ++i) hs += toks[i] * PRIMES_[h][i];
  int idxh = (int)(hs % (unsigned int)MM_);
  float4 r = *reinterpret_cast<const float4*>(&etab[((size_t)idxh * EH_ + h) * EHD_ + e]);
  float4 g = *reinterpret_cast<const float4*>(&egate[h * EHD_ + e]);
  float4 val;
  val.x = r.x / (1.f + __expf(-g.x));
  val.y = r.y / (1.f + __expf(-g.y));
  val.z = r.z / (1.f + __expf(-g.z));
  val.w = r.w / (1.f + __expf(-g.w));
  float ss = val.x * val.x + val.y * val.y + val.z * val.z + val.w * val.w;
  ss = wave_sum_f(ss);
  __shared__ float red[2];
  if ((tid & 63) == 0) red[tid >> 6] = ss;
  __syncthreads();
  ss = red[0] + red[1];
  float inv = 1.0f / sqrtf(ss / (float)D_ + 1e-6f);
  float4 sc = *reinterpret_cast<const float4*>(&escale[c]);
  ushort4 oo;
  oo.x = (u16)f2bf(val.x * inv * sc.x); oo.y = (u16)f2bf(val.y * inv * sc.y);
  oo.z = (u16)f2bf(val.z * inv * sc.z); oo.w = (u16)f2bf(val.w * inv * sc.w);
  *reinterpret_cast<ushort4*>(&kv[(size_t)(b * TK_ + O_ + t) * D_ + c]) = oo;
}

// ---------------- embed + ssum inject ----------------
__global__ __launch_bounds__(128) void embed_k(const int* __restrict__ tokens,
                                               const float* __restrict__ etab,
                                               const float* __restrict__ ssp,
                                               const float* __restrict__ alpha_g,
                                               float* __restrict__ cx,
                                               u16* __restrict__ kv) {
  int t = blockIdx.x, b = blockIdx.y;
  int tid = threadIdx.x;
  int c = tid * 4;
  int tok = tokens[b * T_ + t];
  float4 e = *reinterpret_cast<const float4*>(&etab[(size_t)tok * D_ + c]);
  float4 sp = *reinterpret_cast<const float4*>(&ssp[b * D_ + c]);
  float4 ag = *reinterpret_cast<const float4*>(&alpha_g[c]);
  float4 x;
  x.x = e.x + sp.x / (1.f + __expf(-ag.x));
  x.y = e.y + sp.y / (1.f + __expf(-ag.y));
  x.z = e.z + sp.z / (1.f + __expf(-ag.z));
  x.w = e.w + sp.w / (1.f + __expf(-ag.w));
  *reinterpret_cast<float4*>(&cx[(size_t)(b * T_ + t) * D_ + c]) = x;
  ushort4 oo;
  oo.x = (u16)f2bf(x.x); oo.y = (u16)f2bf(x.y);
  oo.z = (u16)f2bf(x.z); oo.w = (u16)f2bf(x.w);
  *reinterpret_cast<ushort4*>(&kv[(size_t)(b * TK_ + O_ + T_ + t) * D_ + c]) = oo;
}

// ---------------- MFMA flash attention v3: swapped-operand (lane owns one query) ----------------
// S^T = mfma(A=K, B=Q): lane holds q=lr (col), keys kt*16+lg*4+r (rows).
// O^T = mfma(A=V^T, B=P^T): od[dt] lane holds q=lr (col), d=dt*16+lg*4+r (rows).
// P^T B-frag built via v_cvt_pk_bf16_f32 + per-wave swizzled LDS u32 buffer.
#define KIDX8(r, c) (((r) << 6) + ((c) ^ (((r) & 7) << 3)))
#define KIDX4(r, c) (((r) << 6) + ((c) ^ (((r) & 15) << 2)))
#define PIDX(q, o) (((q) << 5) + ((o) ^ (((q) & 7) << 2)))

__global__ __launch_bounds__(256) void attn_mfma_k(const u16* __restrict__ qb,
                                                   const u16* __restrict__ kb,
                                                   const u16* __restrict__ vb,
                                                   const int* __restrict__ tokens,
                                                   u16* __restrict__ ob) {
  __shared__ __align__(16) short ks[2][64 * 64];
  __shared__ __align__(16) short vst[2][64 * 64];        // transposed: [d][k]
  __shared__ __align__(16) unsigned int pbuf[4][16 * 32]; // per-wave P^T packed pairs
  __shared__ unsigned char vtok[T_];

  // fid -> (b, h, bx): h = fid&7 pins each head to one XCD (L2 locality for K/V);
  // slots s and s+32 get complementary bx so co-resident pairs have equal work.
  int fid = blockIdx.x;
  int h = fid & 7;
  int s = fid >> 3;
  int b, bx;
  if (s < 32) { bx = s >> 1; b = s & 1; }
  else { int s2 = s - 32; bx = 15 - (s2 >> 1); b = 2 + (s2 & 1); }

  int qt0 = bx * 64;
  int tid = threadIdx.x;
  int w = tid >> 6, lane = tid & 63;
  int lr = lane & 15;
  int lg = lane >> 4;
  int qw0 = qt0 + w * 16;
  int tq = qw0 + lr;  // this lane's query row

  for (int i = tid; i < T_; i += 256) vtok[i] = (tokens[b * T_ + i] != 0);

  bf16x8 aq[2];  // Q for this lane's q row: B-operand (col=lr, d=lg*8..)
  {
    const u16* qp = &qb[((size_t)(b * T_) + tq) * D_ + h * 64];
    aq[0] = *reinterpret_cast<const bf16x8*>(qp + lg * 8);
    aq[1] = *reinterpret_cast<const bf16x8*>(qp + 32 + lg * 8);
  }

  float m_ = -1e30f, lsum = 0.f;
  f32x4 od[4];
  #pragma unroll
  for (int dt = 0; dt < 4; ++dt) od[dt] = (f32x4){0.f, 0.f, 0.f, 0.f};

  // K staging map: row sr (0..63), 16-col chunk sc
  int sr = tid >> 2;
  int sc = (tid & 3) * 16;
  // V staging map: 4x4 block
  int vr = (tid >> 4) * 4;
  int vc = (tid & 15) * 4;

  int nt = 2 + 2 * (bx + 1);
  auto tile_pos = [&](int i, int& pos0, int& base, bool& masked) {
    if (i < 2) { pos0 = i * 64; base = 0; masked = false; }
    else if (i < 2 + (bx + 1)) { pos0 = O_ + (i - 2) * 64; base = O_; masked = true; }
    else { pos0 = O_ + T_ + (i - 2 - (bx + 1)) * 64; base = O_ + T_; masked = true; }
  };

  bf16x8 pk0, pk1;
  short4 pv0, pv1, pv2, pv3;

  auto load_regs = [&](int pos0) {
    const u16* kg = &kb[((size_t)(b * TK_) + pos0 + sr) * D_ + h * 64 + sc];
    pk0 = *reinterpret_cast<const bf16x8*>(kg);
    pk1 = *reinterpret_cast<const bf16x8*>(kg + 8);
    const u16* vg = &vb[((size_t)(b * TK_) + pos0 + vr) * D_ + h * 64 + vc];
    pv0 = *reinterpret_cast<const short4*>(vg);
    pv1 = *reinterpret_cast<const short4*>(vg + D_);
    pv2 = *reinterpret_cast<const short4*>(vg + 2 * D_);
    pv3 = *reinterpret_cast<const short4*>(vg + 3 * D_);
  };

  auto write_lds = [&](int buf) {
    *reinterpret_cast<bf16x8*>(&ks[buf][KIDX8(sr, sc)]) = pk0;
    *reinterpret_cast<bf16x8*>(&ks[buf][KIDX8(sr, sc + 8)]) = pk1;
    short4 t0 = make_short4(pv0.x, pv1.x, pv2.x, pv3.x);
    short4 t1 = make_short4(pv0.y, pv1.y, pv2.y, pv3.y);
    short4 t2 = make_short4(pv0.z, pv1.z, pv2.z, pv3.z);
    short4 t3 = make_short4(pv0.w, pv1.w, pv2.w, pv3.w);
    *reinterpret_cast<short4*>(&vst[buf][KIDX4(vc + 0, vr)]) = t0;
    *reinterpret_cast<short4*>(&vst[buf][KIDX4(vc + 1, vr)]) = t1;
    *reinterpret_cast<short4*>(&vst[buf][KIDX4(vc + 2, vr)]) = t2;
    *reinterpret_cast<short4*>(&vst[buf][KIDX4(vc + 3, vr)]) = t3;
  };

  unsigned int* pw = (unsigned int*)pbuf[w];

  auto compute = [&](int buf, int pos0, int base, bool masked) {
    float sv[4][4];
    __builtin_amdgcn_s_setprio(1);
    #pragma unroll
    for (int kt = 0; kt < 4; ++kt) {
      // A = K subtile (16 keys x 32 d), lane: key row kt*16+lr, d=lg*8..
      bf16x8 ka0 = *reinterpret_cast<const bf16x8*>(&ks[buf][KIDX8(kt * 16 + lr, lg * 8)]);
      bf16x8 ka1 = *reinterpret_cast<const bf16x8*>(&ks[buf][KIDX8(kt * 16 + lr, 32 + lg * 8)]);
      f32x4 sf = (f32x4){0.f, 0.f, 0.f, 0.f};
      sf = __builtin_amdgcn_mfma_f32_16x16x32_bf16(ka0, aq[0], sf, 0, 0, 0);
      sf = __builtin_amdgcn_mfma_f32_16x16x32_bf16(ka1, aq[1], sf, 0, 0, 0);
      #pragma unroll
      for (int r = 0; r < 4; ++r) sv[kt][r] = sf[r];
    }
    __builtin_amdgcn_s_setprio(0);
    // mask + scale: key for sv[kt][r] is pos0 + kt*16 + lg*4 + r (lane's q = tq)
    if (masked) {
      #pragma unroll
      for (int kt = 0; kt < 4; ++kt) {
        #pragma unroll
        for (int r = 0; r < 4; ++r) {
          int tk = pos0 + kt * 16 + lg * 4 + r - base;
          bool valid = (vtok[tk] != 0) && (tk <= tq);
          sv[kt][r] = valid ? sv[kt][r] * 0.125f : -1e30f;
        }
      }
    } else {
      #pragma unroll
      for (int kt = 0; kt < 4; ++kt)
        #pragma unroll
        for (int r = 0; r < 4; ++r) sv[kt][r] *= 0.125f;
    }
    // online softmax: per-lane scalar state (one q per lane)
    float pmax = sv[0][0];
    #pragma unroll
    for (int kt = 0; kt < 4; ++kt)
      #pragma unroll
      for (int r = 0; r < 4; ++r) pmax = fmaxf(pmax, sv[kt][r]);
    pmax = fmaxf(pmax, __shfl_xor(pmax, 16));
    pmax = fmaxf(pmax, __shfl_xor(pmax, 32));
    float mnew = fmaxf(m_, pmax);
    float al = __expf(m_ - mnew);
    m_ = mnew;
    float psum = 0.f;
    #pragma unroll
    for (int kt = 0; kt < 4; ++kt)
      #pragma unroll
      for (int r = 0; r < 4; ++r) {
        float pe = __expf(sv[kt][r] - mnew);
        sv[kt][r] = pe;
        psum += pe;
      }
    psum += __shfl_xor(psum, 16);
    psum += __shfl_xor(psum, 32);
    lsum = lsum * al + psum;
    #pragma unroll
    for (int dt = 0; dt < 4; ++dt) {
      f32x4 o = od[dt];
      o[0] *= al; o[1] *= al; o[2] *= al; o[3] *= al;
      od[dt] = o;
    }
    // pack P pairs -> per-wave LDS (u32 = bf16(lo)|bf16(hi)<<16), swizzled
    #pragma unroll
    for (int kt = 0; kt < 4; ++kt) {
      uint2 wp;
      asm("v_cvt_pk_bf16_f32 %0, %1, %2" : "=v"(wp.x) : "v"(sv[kt][0]), "v"(sv[kt][1]));
      asm("v_cvt_pk_bf16_f32 %0, %1, %2" : "=v"(wp.y) : "v"(sv[kt][2]), "v"(sv[kt][3]));
      *reinterpret_cast<uint2*>(&pw[PIDX(lr, kt * 8 + lg * 2)]) = wp;
    }
    // B-frags: lane needs keys m*32 + lg*8 .. +7 for q=lr (pairs m*16+lg*4 .. +3)
    bf16x8 pf0 = *reinterpret_cast<const bf16x8*>(&pw[PIDX(lr, lg * 4)]);
    bf16x8 pf1 = *reinterpret_cast<const bf16x8*>(&pw[PIDX(lr, 16 + lg * 4)]);
    __builtin_amdgcn_s_setprio(1);
    #pragma unroll
    for (int dt = 0; dt < 4; ++dt) {
      // A = V^T subtile (16 d x 32 k), lane: d row dt*16+lr, k=lg*8..
      short4 lo0 = *reinterpret_cast<const short4*>(&vst[buf][KIDX4(dt * 16 + lr, lg * 8)]);
      short4 hi0 = *reinterpret_cast<const short4*>(&vst[buf][KIDX4(dt * 16 + lr, lg * 8 + 4)]);
      short4 lo1 = *reinterpret_cast<const short4*>(&vst[buf][KIDX4(dt * 16 + lr, 32 + lg * 8)]);
      short4 hi1 = *reinterpret_cast<const short4*>(&vst[buf][KIDX4(dt * 16 + lr, 36 + lg * 8)]);
      bf16x8 va0 = {lo0.x, lo0.y, lo0.z, lo0.w, hi0.x, hi0.y, hi0.z, hi0.w};
      bf16x8 va1 = {lo1.x, lo1.y, lo1.z, lo1.w, hi1.x, hi1.y, hi1.z, hi1.w};
      od[dt] = __builtin_amdgcn_mfma_f32_16x16x32_bf16(va0, pf0, od[dt], 0, 0, 0);
      od[dt] = __builtin_amdgcn_mfma_f32_16x16x32_bf16(va1, pf1, od[dt], 0, 0, 0);
    }
    __builtin_amdgcn_s_setprio(0);
  };

  // prologue: load tile 0 into regs
  {
    int pos0, base; bool masked;
    tile_pos(0, pos0, base, masked);
    load_regs(pos0);
  }
  // main loop: ONE barrier per tile.
  // write_lds(i -> buf i&1) conflicts only with compute(i-2) (same buf), which is
  // fenced by iteration i-1's barrier.
  for (int i = 0; i < nt; ++i) {
    write_lds(i & 1);
    __syncthreads();
    int pos0, base; bool masked;
    tile_pos(i, pos0, base, masked);
    if (i + 1 < nt) {
      int npos, nbase; bool nmask;
      tile_pos(i + 1, npos, nbase, nmask);
      load_regs(npos);  // HBM loads in flight under compute
    }
    compute(i & 1, pos0, base, masked);
  }

  // epilogue: od^T holds O[q=lr][d=dt*16+lg*4+r]
  float inv = 1.0f / lsum;
  #pragma unroll
  for (int dt = 0; dt < 4; ++dt) {
    ushort4 o4;
    o4.x = (u16)f2bf(od[dt][0] * inv);
    o4.y = (u16)f2bf(od[dt][1] * inv);
    o4.z = (u16)f2bf(od[dt][2] * inv);
    o4.w = (u16)f2bf(od[dt][3] * inv);
    *reinterpret_cast<ushort4*>(
        &ob[((size_t)(b * T_) + tq) * D_ + h * 64 + dt * 16 + lg * 4]) = o4;
  }
}

extern "C" void kernel_launch(void* const* d_in, const int* in_sizes, int n_in,
                              void* d_out, int out_size, void* d_ws, size_t ws_size,
                              hipStream_t stream) {
  (void)in_sizes; (void)n_in; (void)out_size; (void)ws_size;
  const int* tokens = (const int*)d_in[0];
  const int* mem_ids = (const int*)d_in[1];
  const float* mem_emb = (const float*)d_in[2];
  const float* ssum = (const float*)d_in[3];
  const float* embed = (const float*)d_in[4];
  const float* engram_t = (const float*)d_in[5];
  const float* engram_g = (const float*)d_in[6];
  const float* engram_s = (const float*)d_in[7];
  const float* mem_W = (const float*)d_in[8];
  const float* mem_b = (const float*)d_in[9];
  const float* mem_s = (const float*)d_in[10];
  const float* alpha_g = (const float*)d_in[11];
  const float* ssum_W = (const float*)d_in[12];
  const float* ln1 = (const float*)d_in[13];
  const float* qW = (const float*)d_in[14];
  const float* qbias = (const float*)d_in[15];
  const float* kW = (const float*)d_in[16];
  const float* kbias = (const float*)d_in[17];
  const float* vW = (const float*)d_in[18];
  const float* vbias = (const float*)d_in[19];
  const float* oW = (const float*)d_in[20];
  const float* obias = (const float*)d_in[21];
  const float* ln2 = (const float*)d_in[22];
  const float* w_in = (const float*)d_in[23];
  const float* w_out = (const float*)d_in[24];
  const float* final_s = (const float*)d_in[25];

  char* p = (char*)d_ws;
  auto alloc = [&](size_t bytes) { char* r = p; p += (bytes + 255) & ~(size_t)255; return r; };
  u16* kv_b   = (u16*)alloc((size_t)B_ * TK_ * D_ * 2);
  float* cx   = (float*)alloc((size_t)B_ * T_ * D_ * 4);
  u16* nx_b   = (u16*)alloc((size_t)B_ * T_ * D_ * 2);   // also ob (attn out)
  u16* qb_b   = (u16*)alloc((size_t)B_ * T_ * D_ * 2);   // also mem_tmp f32
  u16* kb_b   = (u16*)alloc((size_t)B_ * TK_ * D_ * 2);  // hb spans kb_b+vb_b
  u16* vb_b   = (u16*)alloc((size_t)B_ * TK_ * D_ * 2);
  u16* wqkvoT = (u16*)alloc((size_t)L_ * 4 * D_ * D_ * 2);
  u16* wiT    = (u16*)alloc((size_t)L_ * 4096 * 512 * 2);
  u16* woutT  = (u16*)alloc((size_t)L_ * 512 * 2048 * 2);
  float* ssp  = (float*)alloc((size_t)B_ * D_ * 4);
  float* rc   = (float*)alloc((size_t)TK_ * 32 * 4);
  float* rs   = (float*)alloc((size_t)TK_ * 32 * 4);
  float* mem_tmp = (float*)qb_b;
  u16* ob_b = nx_b;
  u16* hb = kb_b;
  (void)vb_b;

  // preamble + batched weight conversion
  rope_table_k<<<TK_ * 32 / 64, 64, 0, stream>>>(rc, rs);
  wconv_qkvo_k<<<dim3(8, 8, L_ * 4), 256, 0, stream>>>(qW, kW, vW, oW, wqkvoT);
  wconv_win_k<<<dim3(64, 8, L_), 256, 0, stream>>>(w_in, wiT);
  wconv_wout_k<<<dim3(8, 32, L_), 256, 0, stream>>>(w_out, woutT);
  ssum_proj_k<<<dim3(2, B_), 256, 0, stream>>>(ssum, ssum_W, ssp);
  sgemm_k<<<dim3(8, 8), 256, 0, stream>>>(mem_emb, mem_W, mem_b, mem_tmp, B_ * O_, D_, D_);
  memnorm_k<<<dim3(O_, B_), 128, 0, stream>>>(mem_tmp, mem_s, kv_b);
  engram_k<<<dim3(T_, B_), 128, 0, stream>>>(tokens, mem_ids, engram_t, engram_g, engram_s, kv_b);
  embed_k<<<dim3(T_, B_), 128, 0, stream>>>(tokens, embed, ssp, alpha_g, cx, kv_b);

  const size_t WSZ = (size_t)D_ * D_;
  for (int l = 0; l < L_; ++l) {
    const u16* wqT = wqkvoT + ((size_t)l * 4 + 0) * WSZ;
    const u16* wkT = wqkvoT + ((size_t)l * 4 + 1) * WSZ;
    const u16* wvT = wqkvoT + ((size_t)l * 4 + 2) * WSZ;
    const u16* woT = wqkvoT + ((size_t)l * 4 + 3) * WSZ;
    const u16* wil = wiT + (size_t)l * 4096 * 512;
    const u16* wol = woutT + (size_t)l * 512 * 2048;

    rmsnorm_k<1><<<B_ * T_, 128, 0, stream>>>(cx, ln1 + l * D_, nx_b);
    gemm_bf16_k<1, 2><<<dim3(4, 64), 256, 0, stream>>>(nx_b, wqT, qbias + l * D_, qb_b,
                                                       B_ * T_, D_, D_, T_, rc, rs);
    kv_gemm_k<<<dim3(8, 68), 256, 0, stream>>>(kv_b, wkT, wvT, kbias + l * D_, vbias + l * D_,
                                               kb_b, vb_b, rc, rs);
    attn_mfma_k<<<dim3(512), 256, 0, stream>>>(qb_b, kb_b, vb_b, tokens, ob_b);
    gemm_bf16_k<2, 2><<<dim3(4, 64), 256, 0, stream>>>(ob_b, woT, obias + l * D_, cx,
                                                       B_ * T_, D_, D_, 0, nullptr, nullptr);
    rmsnorm_k<1><<<B_ * T_, 128, 0, stream>>>(cx, ln2 + l * D_, nx_b);
    mlp_in_mfma_k<<<dim3(32, 32), 256, 0, stream>>>(nx_b, wil, hb);
    gemm_bf16_k<2, 2><<<dim3(4, 64), 256, 0, stream>>>(hb, wol, nullptr, cx,
                                                       B_ * T_, D_, 2048, 0, nullptr, nullptr);
  }
  rmsnorm_k<0><<<B_ * T_, 128, 0, stream>>>(cx, final_s, d_out);
}

// Round 7
// 1155.908 us; speedup vs baseline: 11.4167x; 1.1113x over previous
//
#include <hip/hip_runtime.h>
#include <hip/hip_bf16.h>
#include <math.h>

#define B_ 4
#define T_ 1024
#define O_ 128
#define D_ 512
#define H_ 8
#define L_ 6
#define TK_ 2176
#define MM_ 100000
#define EH_ 4
#define EHD_ 128
#define HD_ 64

typedef float f32x4 __attribute__((ext_vector_type(4)));
typedef short bf16x8 __attribute__((ext_vector_type(8)));
typedef unsigned short u16;

// PRIMES per reference: base=131, x=base+h*1009; row[i]=x; x=x*31+1 (uint32 wrap)
__device__ __constant__ unsigned int PRIMES_[4][4] = {
  {131u,  4062u,  125923u, 3903614u},
  {1140u, 35341u, 1095572u, 33962733u},
  {2149u, 66620u, 2065221u, 64021852u},
  {3158u, 97899u, 3034870u, 94080971u},
};

__device__ __forceinline__ float wave_sum_f(float v) {
  #pragma unroll
  for (int off = 32; off; off >>= 1) v += __shfl_xor(v, off);
  return v;
}

__device__ __forceinline__ short f2bf(float f) {
  unsigned int u = __float_as_uint(f);
  unsigned int r = (u + 0x7fffu + ((u >> 16) & 1u)) >> 16;
  return (short)r;
}

__device__ __forceinline__ void gload16(const void* g, void* l) {
  __builtin_amdgcn_global_load_lds((const __attribute__((address_space(1))) void*)g,
                                   (__attribute__((address_space(3))) void*)l, 16, 0, 0);
}

// ---------------- rope tables: cos/sin [TK][32] ----------------
__global__ __launch_bounds__(64) void rope_table_k(float* __restrict__ rc,
                                                   float* __restrict__ rs) {
  int i = blockIdx.x * 64 + threadIdx.x;
  int t = i >> 5, j = i & 31;
  float freq = __powf(10000.0f, -(float)j / 32.0f);
  float ang = (float)t * freq;
  rc[i] = cosf(ang);
  rs[i] = sinf(ang);
}

// ---------------- ssum @ ssum_W -> ssp[B][D] ----------------
__global__ __launch_bounds__(256) void ssum_proj_k(const float* __restrict__ ssum,
                                                   const float* __restrict__ sW,
                                                   float* __restrict__ ssp) {
  int col = blockIdx.x * 256 + threadIdx.x;
  int b = blockIdx.y;
  float acc = 0.f;
  for (int d = 0; d < D_; ++d) acc += ssum[b * D_ + d] * sW[(size_t)d * D_ + col];
  ssp[b * D_ + col] = acc;
}

// ---------------- f32 tiled GEMM (preamble mem projection only) ----------------
__global__ __launch_bounds__(256) void sgemm_k(const float* __restrict__ A,
                                               const float* __restrict__ W,
                                               const float* __restrict__ bias,
                                               float* __restrict__ C,
                                               int M, int N, int K) {
  __shared__ float As[16][68];
  __shared__ float Bs[16][68];
  int tid = threadIdx.x;
  int row0 = blockIdx.y * 64;
  int col0 = blockIdx.x * 64;
  int tx = tid & 15, ty = tid >> 4;
  int am = tid >> 2, ak = (tid & 3) * 4;
  int bk = tid >> 4, bc = (tid & 15) * 4;
  float acc[4][4] = {};
  for (int k0 = 0; k0 < K; k0 += 16) {
    float4 av = *reinterpret_cast<const float4*>(&A[(size_t)(row0 + am) * K + k0 + ak]);
    As[ak + 0][am] = av.x; As[ak + 1][am] = av.y; As[ak + 2][am] = av.z; As[ak + 3][am] = av.w;
    float4 bv = *reinterpret_cast<const float4*>(&W[(size_t)(k0 + bk) * N + col0 + bc]);
    *reinterpret_cast<float4*>(&Bs[bk][bc]) = bv;
    __syncthreads();
    #pragma unroll
    for (int kk = 0; kk < 16; ++kk) {
      float4 a4 = *reinterpret_cast<const float4*>(&As[kk][ty * 4]);
      float4 b4 = *reinterpret_cast<const float4*>(&Bs[kk][tx * 4]);
      float a[4] = {a4.x, a4.y, a4.z, a4.w};
      float b[4] = {b4.x, b4.y, b4.z, b4.w};
      #pragma unroll
      for (int i = 0; i < 4; ++i)
        #pragma unroll
        for (int j = 0; j < 4; ++j) acc[i][j] += a[i] * b[j];
    }
    __syncthreads();
  }
  int cbase = col0 + tx * 4;
  float4 b4 = *reinterpret_cast<const float4*>(&bias[cbase]);
  float bb[4] = {b4.x, b4.y, b4.z, b4.w};
  #pragma unroll
  for (int i = 0; i < 4; ++i) {
    int row = row0 + ty * 4 + i;
    *reinterpret_cast<float4*>(&C[(size_t)row * N + cbase]) =
        make_float4(acc[i][0] + bb[0], acc[i][1] + bb[1], acc[i][2] + bb[2], acc[i][3] + bb[3]);
  }
}

// ---------------- batched weight convert+transpose: f32 [K][N] -> bf16 [N][K] ----------------
__device__ __forceinline__ void wconv_tile(const float* __restrict__ W, u16* __restrict__ wT,
                                           int K, int N) {
  __shared__ float s[64][65];
  int n0 = blockIdx.x * 64, k0 = blockIdx.y * 64;
  int tid = threadIdx.x;
  int kr = tid >> 4, nc = (tid & 15) * 4;
  #pragma unroll
  for (int kk = 0; kk < 4; ++kk) {
    float4 f = *reinterpret_cast<const float4*>(&W[(size_t)(k0 + kr + kk * 16) * N + n0 + nc]);
    s[kr + kk * 16][nc + 0] = f.x; s[kr + kk * 16][nc + 1] = f.y;
    s[kr + kk * 16][nc + 2] = f.z; s[kr + kk * 16][nc + 3] = f.w;
  }
  __syncthreads();
  int nr = tid >> 4, kc = (tid & 15) * 4;
  #pragma unroll
  for (int nn = 0; nn < 4; ++nn) {
    int n = nr + nn * 16;
    ushort4 o;
    o.x = (u16)f2bf(s[kc + 0][n]); o.y = (u16)f2bf(s[kc + 1][n]);
    o.z = (u16)f2bf(s[kc + 2][n]); o.w = (u16)f2bf(s[kc + 3][n]);
    *reinterpret_cast<ushort4*>(&wT[(size_t)(n0 + n) * K + k0 + kc]) = o;
  }
}

__global__ __launch_bounds__(256) void wconv_qkvo_k(const float* __restrict__ qW,
                                                    const float* __restrict__ kW,
                                                    const float* __restrict__ vW,
                                                    const float* __restrict__ oW,
                                                    u16* __restrict__ dst) {
  int z = blockIdx.z;
  int l = z >> 2, which = z & 3;
  const float* src = which == 0 ? qW : which == 1 ? kW : which == 2 ? vW : oW;
  wconv_tile(src + (size_t)l * D_ * D_, dst + (size_t)z * D_ * D_, D_, D_);
}

__global__ __launch_bounds__(256) void wconv_win_k(const float* __restrict__ w_in,
                                                   u16* __restrict__ dst) {
  int l = blockIdx.z;
  wconv_tile(w_in + (size_t)l * 512 * 4096, dst + (size_t)l * 4096 * 512, 512, 4096);
}

__global__ __launch_bounds__(256) void wconv_wout_k(const float* __restrict__ w_out,
                                                    u16* __restrict__ dst) {
  int l = blockIdx.z;
  wconv_tile(w_out + (size_t)l * 2048 * 512, dst + (size_t)l * 512 * 2048, 2048, 512);
}

// ---------------- MFMA GEMM: C = A@Bt^T (+bias) [+rope | f32 +=] ----------------
template<int EPI, int MI>
__global__ __launch_bounds__(256) void gemm_bf16_k(const u16* __restrict__ A,
                                                   const u16* __restrict__ Bt,
                                                   const float* __restrict__ bias,
                                                   void* __restrict__ Cout,
                                                   int M, int N, int K, int posmod,
                                                   const float* __restrict__ rc,
                                                   const float* __restrict__ rs) {
  __shared__ __align__(16) u16 As[2][MI * 32 * 32];
  __shared__ __align__(16) u16 Bs[2][128 * 32];
  int tid = threadIdx.x;
  int w = tid >> 6, lane = tid & 63;
  int lr = lane & 15, lg = lane >> 4;
  int row0 = blockIdx.y * (MI * 32), col0 = blockIdx.x * 128;
  int wr = w >> 1, wc = w & 1;
  f32x4 acc[MI][4] = {};

  int srow = lane >> 2;
  int skel = (lane & 3) * 8;

  auto stage = [&](int buf, int k0) {
    if constexpr (MI == 4) {
      #pragma unroll
      for (int ci = 0; ci < 2; ++ci) {
        int c = w * 2 + ci;
        gload16(A + (size_t)(row0 + c * 16 + srow) * K + k0 + skel, &As[buf][c * 512]);
      }
    } else {
      gload16(A + (size_t)(row0 + w * 16 + srow) * K + k0 + skel, &As[buf][w * 512]);
    }
    #pragma unroll
    for (int ci = 0; ci < 2; ++ci) {
      int c = w * 2 + ci;
      gload16(Bt + (size_t)(col0 + c * 16 + srow) * K + k0 + skel, &Bs[buf][c * 512]);
    }
  };

  stage(0, 0);
  __syncthreads();
  int nk = K >> 5;
  int buf = 0;
  for (int t = 0; t < nk; ++t) {
    if (t + 1 < nk) stage(buf ^ 1, (t + 1) * 32);
    bf16x8 af[MI], bfr[4];
    #pragma unroll
    for (int i = 0; i < MI; ++i)
      af[i] = *reinterpret_cast<const bf16x8*>(
          &As[buf][(wr * (16 * MI) + i * 16 + lr) * 32 + lg * 8]);
    #pragma unroll
    for (int j = 0; j < 4; ++j)
      bfr[j] = *reinterpret_cast<const bf16x8*>(&Bs[buf][(wc * 64 + j * 16 + lr) * 32 + lg * 8]);
    #pragma unroll
    for (int i = 0; i < MI; ++i)
      #pragma unroll
      for (int j = 0; j < 4; ++j)
        acc[i][j] = __builtin_amdgcn_mfma_f32_16x16x32_bf16(af[i], bfr[j], acc[i][j], 0, 0, 0);
    __syncthreads();
    buf ^= 1;
  }

  #pragma unroll
  for (int j = 0; j < 4; ++j) {
    int col = col0 + wc * 64 + j * 16 + lr;
    float bs = bias ? bias[col] : 0.f;
    #pragma unroll
    for (int i = 0; i < MI; ++i) {
      #pragma unroll
      for (int r = 0; r < 4; ++r) {
        int row = row0 + wr * (16 * MI) + i * 16 + lg * 4 + r;
        float v = acc[i][j][r] + bs;
        if (EPI == 1) {
          int pos = row % posmod;
          int d = col & 63;
          float c = rc[(size_t)pos * 32 + (d >> 1)];
          float s = rs[(size_t)pos * 32 + (d >> 1)];
          float partner = __shfl_xor(v, 1);
          v = (d & 1) ? (partner * s + v * c) : (v * c - partner * s);
        }
        if (EPI == 2) {
          float* Cf = (float*)Cout;
          Cf[(size_t)row * N + col] += v;
        } else {
          u16* Cb = (u16*)Cout;
          Cb[(size_t)row * N + col] = (u16)f2bf(v);
        }
      }
    }
  }
}

// ---------------- fused K+V projection (optionally batched over layers via grid.z) ----------------
__global__ __launch_bounds__(256) void kv_gemm_k(const u16* __restrict__ A,
                                                 const u16* __restrict__ wqkvoT,
                                                 const float* __restrict__ kbias_all,
                                                 const float* __restrict__ vbias_all,
                                                 u16* __restrict__ kb_base,
                                                 u16* __restrict__ vb_base,
                                                 const float* __restrict__ rc,
                                                 const float* __restrict__ rs,
                                                 int l0, size_t ostride) {
  __shared__ __align__(16) u16 As[2][128 * 32];
  __shared__ __align__(16) u16 Bk[2][64 * 32];
  __shared__ __align__(16) u16 Bv[2][64 * 32];
  const int K = 512, N = 512;
  int l = l0 + blockIdx.z;
  const u16* wkT = wqkvoT + ((size_t)l * 4 + 1) * (D_ * D_);
  const u16* wvT = wqkvoT + ((size_t)l * 4 + 2) * (D_ * D_);
  const float* kbias = kbias_all + l * D_;
  const float* vbias = vbias_all + l * D_;
  u16* kb = kb_base + (size_t)blockIdx.z * ostride;
  u16* vb = vb_base + (size_t)blockIdx.z * ostride;
  int tid = threadIdx.x;
  int w = tid >> 6, lane = tid & 63;
  int lr = lane & 15, lg = lane >> 4;
  int row0 = blockIdx.y * 128, col0 = blockIdx.x * 64;
  int wr = w >> 1, wc = w & 1;
  f32x4 ak_[4][2] = {};
  f32x4 av_[4][2] = {};

  int srow = lane >> 2;
  int skel = (lane & 3) * 8;

  auto stage = [&](int buf, int k0) {
    #pragma unroll
    for (int ci = 0; ci < 2; ++ci) {
      int c = w * 2 + ci;
      gload16(A + (size_t)(row0 + c * 16 + srow) * K + k0 + skel, &As[buf][c * 512]);
    }
    gload16(wkT + (size_t)(col0 + w * 16 + srow) * K + k0 + skel, &Bk[buf][w * 512]);
    gload16(wvT + (size_t)(col0 + w * 16 + srow) * K + k0 + skel, &Bv[buf][w * 512]);
  };

  stage(0, 0);
  __syncthreads();
  int buf = 0;
  for (int t = 0; t < 16; ++t) {
    if (t + 1 < 16) stage(buf ^ 1, (t + 1) * 32);
    bf16x8 af[4], bk[2], bv[2];
    #pragma unroll
    for (int i = 0; i < 4; ++i)
      af[i] = *reinterpret_cast<const bf16x8*>(&As[buf][(wr * 64 + i * 16 + lr) * 32 + lg * 8]);
    #pragma unroll
    for (int j = 0; j < 2; ++j) {
      bk[j] = *reinterpret_cast<const bf16x8*>(&Bk[buf][(wc * 32 + j * 16 + lr) * 32 + lg * 8]);
      bv[j] = *reinterpret_cast<const bf16x8*>(&Bv[buf][(wc * 32 + j * 16 + lr) * 32 + lg * 8]);
    }
    #pragma unroll
    for (int i = 0; i < 4; ++i)
      #pragma unroll
      for (int j = 0; j < 2; ++j) {
        ak_[i][j] = __builtin_amdgcn_mfma_f32_16x16x32_bf16(af[i], bk[j], ak_[i][j], 0, 0, 0);
        av_[i][j] = __builtin_amdgcn_mfma_f32_16x16x32_bf16(af[i], bv[j], av_[i][j], 0, 0, 0);
      }
    __syncthreads();
    buf ^= 1;
  }

  #pragma unroll
  for (int j = 0; j < 2; ++j) {
    int col = col0 + wc * 32 + j * 16 + lr;
    float kbs = kbias[col], vbs = vbias[col];
    int d = col & 63;
    #pragma unroll
    for (int i = 0; i < 4; ++i) {
      #pragma unroll
      for (int r = 0; r < 4; ++r) {
        int row = row0 + wr * 64 + i * 16 + lg * 4 + r;
        int pos = row % TK_;
        float vk = ak_[i][j][r] + kbs;
        float c = rc[(size_t)pos * 32 + (d >> 1)];
        float s = rs[(size_t)pos * 32 + (d >> 1)];
        float partner = __shfl_xor(vk, 1);
        vk = (d & 1) ? (partner * s + vk * c) : (vk * c - partner * s);
        kb[(size_t)row * N + col] = (u16)f2bf(vk);
        vb[(size_t)row * N + col] = (u16)f2bf(av_[i][j][r] + vbs);
      }
    }
  }
}

// ---------------- fused MLP-in MFMA ----------------
__global__ __launch_bounds__(256) void mlp_in_mfma_k(const u16* __restrict__ A,
                                                     const u16* __restrict__ wiT,
                                                     u16* __restrict__ Hout) {
  __shared__ __align__(16) u16 As[2][128 * 32];
  __shared__ __align__(16) u16 Bg[2][64 * 32];
  __shared__ __align__(16) u16 Bv[2][64 * 32];
  int tid = threadIdx.x;
  int w = tid >> 6, lane = tid & 63;
  int lr = lane & 15, lg = lane >> 4;
  int hc0 = blockIdx.x * 64, row0 = blockIdx.y * 128;
  int wr = w >> 1, wc = w & 1;
  f32x4 ag[4][2] = {};
  f32x4 av[4][2] = {};
  const int K = 512;

  int srow = lane >> 2;
  int skel = (lane & 3) * 8;

  auto stage = [&](int buf, int k0) {
    #pragma unroll
    for (int ci = 0; ci < 2; ++ci) {
      int c = w * 2 + ci;
      gload16(A + (size_t)(row0 + c * 16 + srow) * K + k0 + skel, &As[buf][c * 512]);
    }
    gload16(wiT + (size_t)(hc0 + w * 16 + srow) * K + k0 + skel, &Bg[buf][w * 512]);
    gload16(wiT + (size_t)(2048 + hc0 + w * 16 + srow) * K + k0 + skel, &Bv[buf][w * 512]);
  };

  stage(0, 0);
  __syncthreads();
  int buf = 0;
  for (int t = 0; t < 16; ++t) {
    if (t + 1 < 16) stage(buf ^ 1, (t + 1) * 32);
    bf16x8 af[4], bg[2], bv[2];
    #pragma unroll
    for (int i = 0; i < 4; ++i)
      af[i] = *reinterpret_cast<const bf16x8*>(&As[buf][(wr * 64 + i * 16 + lr) * 32 + lg * 8]);
    #pragma unroll
    for (int j = 0; j < 2; ++j) {
      bg[j] = *reinterpret_cast<const bf16x8*>(&Bg[buf][(wc * 32 + j * 16 + lr) * 32 + lg * 8]);
      bv[j] = *reinterpret_cast<const bf16x8*>(&Bv[buf][(wc * 32 + j * 16 + lr) * 32 + lg * 8]);
    }
    #pragma unroll
    for (int i = 0; i < 4; ++i)
      #pragma unroll
      for (int j = 0; j < 2; ++j) {
        ag[i][j] = __builtin_amdgcn_mfma_f32_16x16x32_bf16(af[i], bg[j], ag[i][j], 0, 0, 0);
        av[i][j] = __builtin_amdgcn_mfma_f32_16x16x32_bf16(af[i], bv[j], av[i][j], 0, 0, 0);
      }
    __syncthreads();
    buf ^= 1;
  }

  #pragma unroll
  for (int j = 0; j < 2; ++j) {
    int col = hc0 + wc * 32 + j * 16 + lr;
    #pragma unroll
    for (int i = 0; i < 4; ++i) {
      #pragma unroll
      for (int r = 0; r < 4; ++r) {
        int row = row0 + wr * 64 + i * 16 + lg * 4 + r;
        float g = ag[i][j][r];
        float sg = g / (1.f + __expf(-g));
        Hout[(size_t)row * 2048 + col] = (u16)f2bf(sg * av[i][j][r]);
      }
    }
  }
}

// ---------------- rmsnorm rows ----------------
template<int OUTBF>
__global__ __launch_bounds__(128) void rmsnorm_k(const float* __restrict__ in,
                                                 const float* __restrict__ scale,
                                                 void* __restrict__ out) {
  int row = blockIdx.x;
  int tid = threadIdx.x;
  float4 v = *reinterpret_cast<const float4*>(&in[(size_t)row * D_ + tid * 4]);
  float ss = v.x * v.x + v.y * v.y + v.z * v.z + v.w * v.w;
  ss = wave_sum_f(ss);
  __shared__ float red[2];
  if ((tid & 63) == 0) red[tid >> 6] = ss;
  __syncthreads();
  ss = red[0] + red[1];
  float inv = 1.0f / sqrtf(ss / (float)D_ + 1e-6f);
  float4 sc = *reinterpret_cast<const float4*>(&scale[tid * 4]);
  float o0 = v.x * inv * sc.x, o1 = v.y * inv * sc.y, o2 = v.z * inv * sc.z, o3 = v.w * inv * sc.w;
  if (OUTBF) {
    ushort4 o;
    o.x = (u16)f2bf(o0); o.y = (u16)f2bf(o1); o.z = (u16)f2bf(o2); o.w = (u16)f2bf(o3);
    *reinterpret_cast<ushort4*>((u16*)out + (size_t)row * D_ + tid * 4) = o;
  } else {
    *reinterpret_cast<float4*>((float*)out + (size_t)row * D_ + tid * 4) =
        make_float4(o0, o1, o2, o3);
  }
}

// ---------------- mem rows ----------------
__global__ __launch_bounds__(128) void memnorm_k(const float* __restrict__ tmp,
                                                 const float* __restrict__ scale,
                                                 u16* __restrict__ kv) {
  int o = blockIdx.x, b = blockIdx.y;
  int tid = threadIdx.x;
  float4 v = *reinterpret_cast<const float4*>(&tmp[(size_t)(b * O_ + o) * D_ + tid * 4]);
  float ss = v.x * v.x + v.y * v.y + v.z * v.z + v.w * v.w;
  ss = wave_sum_f(ss);
  __shared__ float red[2];
  if ((tid & 63) == 0) red[tid >> 6] = ss;
  __syncthreads();
  ss = red[0] + red[1];
  float inv = 1.0f / sqrtf(ss / (float)D_ + 1e-6f);
  float4 sc = *reinterpret_cast<const float4*>(&scale[tid * 4]);
  ushort4 oo;
  oo.x = (u16)f2bf(v.x * inv * sc.x); oo.y = (u16)f2bf(v.y * inv * sc.y);
  oo.z = (u16)f2bf(v.z * inv * sc.z); oo.w = (u16)f2bf(v.w * inv * sc.w);
  *reinterpret_cast<ushort4*>(&kv[(size_t)(b * TK_ + o) * D_ + tid * 4]) = oo;
}

// ---------------- engram rows ----------------
__global__ __launch_bounds__(128) void engram_k(const int* __restrict__ tokens,
                                                const int* __restrict__ mem_ids,
                                                const float* __restrict__ etab,
                                                const float* __restrict__ egate,
                                                const float* __restrict__ escale,
                                                u16* __restrict__ kv) {
  int t = blockIdx.x, b = blockIdx.y;
  int tid = threadIdx.x;
  unsigned int toks[4];
  #pragma unroll
  for (int i = 0; i < 4; ++i) {
    int idx = t - i;
    toks[i] = (idx >= 0) ? (unsigned int)tokens[b * T_ + idx]
                         : (unsigned int)mem_ids[b * O_ + O_ + idx];
  }
  int c = tid * 4;
  int h = c >> 7;
  int e = c & 127;
  unsigned int hs = 0;
  #pragma unroll
  for (int i = 0; i < 4; ++i) hs += toks[i] * PRIMES_[h][i];
  int idxh = (int)(hs % (unsigned int)MM_);
  float4 r = *reinterpret_cast<const float4*>(&etab[((size_t)idxh * EH_ + h) * EHD_ + e]);
  float4 g = *reinterpret_cast<const float4*>(&egate[h * EHD_ + e]);
  float4 val;
  val.x = r.x / (1.f + __expf(-g.x));
  val.y = r.y / (1.f + __expf(-g.y));
  val.z = r.z / (1.f + __expf(-g.z));
  val.w = r.w / (1.f + __expf(-g.w));
  float ss = val.x * val.x + val.y * val.y + val.z * val.z + val.w * val.w;
  ss = wave_sum_f(ss);
  __shared__ float red[2];
  if ((tid & 63) == 0) red[tid >> 6] = ss;
  __syncthreads();
  ss = red[0] + red[1];
  float inv = 1.0f / sqrtf(ss / (float)D_ + 1e-6f);
  float4 sc = *reinterpret_cast<const float4*>(&escale[c]);
  ushort4 oo;
  oo.x = (u16)f2bf(val.x * inv * sc.x); oo.y = (u16)f2bf(val.y * inv * sc.y);
  oo.z = (u16)f2bf(val.z * inv * sc.z); oo.w = (u16)f2bf(val.w * inv * sc.w);
  *reinterpret_cast<ushort4*>(&kv[(size_t)(b * TK_ + O_ + t) * D_ + c]) = oo;
}

// ---------------- embed + ssum inject ----------------
__global__ __launch_bounds__(128) void embed_k(const int* __restrict__ tokens,
                                               const float* __restrict__ etab,
                                               const float* __restrict__ ssp,
                                               const float* __restrict__ alpha_g,
                                               float* __restrict__ cx,
                                               u16* __restrict__ kv) {
  int t = blockIdx.x, b = blockIdx.y;
  int tid = threadIdx.x;
  int c = tid * 4;
  int tok = tokens[b * T_ + t];
  float4 e = *reinterpret_cast<const float4*>(&etab[(size_t)tok * D_ + c]);
  float4 sp = *reinterpret_cast<const float4*>(&ssp[b * D_ + c]);
  float4 ag = *reinterpret_cast<const float4*>(&alpha_g[c]);
  float4 x;
  x.x = e.x + sp.x / (1.f + __expf(-ag.x));
  x.y = e.y + sp.y / (1.f + __expf(-ag.y));
  x.z = e.z + sp.z / (1.f + __expf(-ag.z));
  x.w = e.w + sp.w / (1.f + __expf(-ag.w));
  *reinterpret_cast<float4*>(&cx[(size_t)(b * T_ + t) * D_ + c]) = x;
  ushort4 oo;
  oo.x = (u16)f2bf(x.x); oo.y = (u16)f2bf(x.y);
  oo.z = (u16)f2bf(x.z); oo.w = (u16)f2bf(x.w);
  *reinterpret_cast<ushort4*>(&kv[(size_t)(b * TK_ + O_ + T_ + t) * D_ + c]) = oo;
}

// ---------------- MFMA flash attention v4: 8 waves, paired q-tiles share staged K/V ----------------
// waves 0-3 -> q-tile bxA=pair, waves 4-7 -> q-tile bxB=15-pair. Tiles iterate bxB's
// (superset) schedule; A-waves skip tiles beyond their causal prefix (fully masked).
#define KIDX8(r, c) (((r) << 6) + ((c) ^ (((r) & 7) << 3)))
#define KIDX4(r, c) (((r) << 6) + ((c) ^ (((r) & 15) << 2)))
#define PIDX(q, o) (((q) << 5) + ((o) ^ (((q) & 7) << 2)))

__global__ __launch_bounds__(512) void attn_mfma_k(const u16* __restrict__ qb,
                                                   const u16* __restrict__ kb,
                                                   const u16* __restrict__ vb,
                                                   const int* __restrict__ tokens,
                                                   u16* __restrict__ ob) {
  __shared__ __align__(16) short ks[2][64 * 64];
  __shared__ __align__(16) short vst[2][64 * 64];        // transposed: [d][k]
  __shared__ __align__(16) unsigned int pbuf[8][16 * 32]; // per-wave P^T packed pairs
  __shared__ unsigned char vtok[T_];

  // fid -> (b, h, pair): h = fid&7 pins each head to one XCD.
  int fid = blockIdx.x;       // 256 blocks
  int h = fid & 7;
  int s = fid >> 3;           // 0..31
  int pair = s & 7;           // bxA = pair, bxB = 15 - pair
  int b = s >> 3;             // 0..3
  int bxA = pair, bxB = 15 - pair;

  int tid = threadIdx.x;
  int w = tid >> 6, lane = tid & 63;
  int lr = lane & 15;
  int lg = lane >> 4;
  int myBx = (w < 4) ? bxA : bxB;
  int qw0 = myBx * 64 + (w & 3) * 16;
  int tq = qw0 + lr;  // this lane's query row

  for (int i = tid; i < T_; i += 512) vtok[i] = (tokens[b * T_ + i] != 0);

  bf16x8 aq[2];  // Q for this lane's q row: B-operand (col=lr, d=lg*8..)
  {
    const u16* qp = &qb[((size_t)(b * T_) + tq) * D_ + h * 64];
    aq[0] = *reinterpret_cast<const bf16x8*>(qp + lg * 8);
    aq[1] = *reinterpret_cast<const bf16x8*>(qp + 32 + lg * 8);
  }

  float m_ = -1e30f, lsum = 0.f;
  f32x4 od[4];
  #pragma unroll
  for (int dt = 0; dt < 4; ++dt) od[dt] = (f32x4){0.f, 0.f, 0.f, 0.f};

  // K staging map (512 thr): row sr (0..63), 8-col chunk sc
  int sr = tid >> 3;
  int sc = (tid & 7) * 8;
  // V staging map (512 thr): 2 rows x 4 cols
  int vr2 = (tid >> 4) * 2;
  int vc = (tid & 15) * 4;

  int nt = 2 + 2 * (bxB + 1);
  auto tile_pos = [&](int i, int& pos0, int& base, bool& masked, bool& part) {
    if (i < 2) { pos0 = i * 64; base = 0; masked = false; part = true; }
    else if (i < 3 + bxB) {
      int t = i - 2;
      pos0 = O_ + t * 64; base = O_; masked = true; part = (t <= myBx);
    } else {
      int t = i - (3 + bxB);
      pos0 = O_ + T_ + t * 64; base = O_ + T_; masked = true; part = (t <= myBx);
    }
  };

  bf16x8 pk0;
  short4 pv0, pv1;

  auto load_regs = [&](int pos0) {
    const u16* kg = &kb[((size_t)(b * TK_) + pos0 + sr) * D_ + h * 64 + sc];
    pk0 = *reinterpret_cast<const bf16x8*>(kg);
    const u16* vg = &vb[((size_t)(b * TK_) + pos0 + vr2) * D_ + h * 64 + vc];
    pv0 = *reinterpret_cast<const short4*>(vg);
    pv1 = *reinterpret_cast<const short4*>(vg + D_);
  };

  auto write_lds = [&](int buf) {
    *reinterpret_cast<bf16x8*>(&ks[buf][KIDX8(sr, sc)]) = pk0;
    // transpose 2x4 -> 4 u32 writes (2 shorts each) at col vr2 (even)
    unsigned int t0 = (unsigned int)(u16)pv0.x | ((unsigned int)(u16)pv1.x << 16);
    unsigned int t1 = (unsigned int)(u16)pv0.y | ((unsigned int)(u16)pv1.y << 16);
    unsigned int t2 = (unsigned int)(u16)pv0.z | ((unsigned int)(u16)pv1.z << 16);
    unsigned int t3 = (unsigned int)(u16)pv0.w | ((unsigned int)(u16)pv1.w << 16);
    *reinterpret_cast<unsigned int*>(&vst[buf][KIDX4(vc + 0, vr2)]) = t0;
    *reinterpret_cast<unsigned int*>(&vst[buf][KIDX4(vc + 1, vr2)]) = t1;
    *reinterpret_cast<unsigned int*>(&vst[buf][KIDX4(vc + 2, vr2)]) = t2;
    *reinterpret_cast<unsigned int*>(&vst[buf][KIDX4(vc + 3, vr2)]) = t3;
  };

  unsigned int* pw = (unsigned int*)pbuf[w];

  auto compute = [&](int buf, int pos0, int base, bool masked) {
    float sv[4][4];
    __builtin_amdgcn_s_setprio(1);
    #pragma unroll
    for (int kt = 0; kt < 4; ++kt) {
      bf16x8 ka0 = *reinterpret_cast<const bf16x8*>(&ks[buf][KIDX8(kt * 16 + lr, lg * 8)]);
      bf16x8 ka1 = *reinterpret_cast<const bf16x8*>(&ks[buf][KIDX8(kt * 16 + lr, 32 + lg * 8)]);
      f32x4 sf = (f32x4){0.f, 0.f, 0.f, 0.f};
      sf = __builtin_amdgcn_mfma_f32_16x16x32_bf16(ka0, aq[0], sf, 0, 0, 0);
      sf = __builtin_amdgcn_mfma_f32_16x16x32_bf16(ka1, aq[1], sf, 0, 0, 0);
      #pragma unroll
      for (int r = 0; r < 4; ++r) sv[kt][r] = sf[r];
    }
    __builtin_amdgcn_s_setprio(0);
    if (masked) {
      #pragma unroll
      for (int kt = 0; kt < 4; ++kt) {
        #pragma unroll
        for (int r = 0; r < 4; ++r) {
          int tk = pos0 + kt * 16 + lg * 4 + r - base;
          bool valid = (vtok[tk] != 0) && (tk <= tq);
          sv[kt][r] = valid ? sv[kt][r] * 0.125f : -1e30f;
        }
      }
    } else {
      #pragma unroll
      for (int kt = 0; kt < 4; ++kt)
        #pragma unroll
        for (int r = 0; r < 4; ++r) sv[kt][r] *= 0.125f;
    }
    float pmax = sv[0][0];
    #pragma unroll
    for (int kt = 0; kt < 4; ++kt)
      #pragma unroll
      for (int r = 0; r < 4; ++r) pmax = fmaxf(pmax, sv[kt][r]);
    pmax = fmaxf(pmax, __shfl_xor(pmax, 16));
    pmax = fmaxf(pmax, __shfl_xor(pmax, 32));
    float mnew = fmaxf(m_, pmax);
    float al = __expf(m_ - mnew);
    m_ = mnew;
    float psum = 0.f;
    #pragma unroll
    for (int kt = 0; kt < 4; ++kt)
      #pragma unroll
      for (int r = 0; r < 4; ++r) {
        float pe = __expf(sv[kt][r] - mnew);
        sv[kt][r] = pe;
        psum += pe;
      }
    psum += __shfl_xor(psum, 16);
    psum += __shfl_xor(psum, 32);
    lsum = lsum * al + psum;
    #pragma unroll
    for (int dt = 0; dt < 4; ++dt) {
      f32x4 o = od[dt];
      o[0] *= al; o[1] *= al; o[2] *= al; o[3] *= al;
      od[dt] = o;
    }
    #pragma unroll
    for (int kt = 0; kt < 4; ++kt) {
      uint2 wp;
      asm("v_cvt_pk_bf16_f32 %0, %1, %2" : "=v"(wp.x) : "v"(sv[kt][0]), "v"(sv[kt][1]));
      asm("v_cvt_pk_bf16_f32 %0, %1, %2" : "=v"(wp.y) : "v"(sv[kt][2]), "v"(sv[kt][3]));
      *reinterpret_cast<uint2*>(&pw[PIDX(lr, kt * 8 + lg * 2)]) = wp;
    }
    bf16x8 pf0 = *reinterpret_cast<const bf16x8*>(&pw[PIDX(lr, lg * 4)]);
    bf16x8 pf1 = *reinterpret_cast<const bf16x8*>(&pw[PIDX(lr, 16 + lg * 4)]);
    __builtin_amdgcn_s_setprio(1);
    #pragma unroll
    for (int dt = 0; dt < 4; ++dt) {
      short4 lo0 = *reinterpret_cast<const short4*>(&vst[buf][KIDX4(dt * 16 + lr, lg * 8)]);
      short4 hi0 = *reinterpret_cast<const short4*>(&vst[buf][KIDX4(dt * 16 + lr, lg * 8 + 4)]);
      short4 lo1 = *reinterpret_cast<const short4*>(&vst[buf][KIDX4(dt * 16 + lr, 32 + lg * 8)]);
      short4 hi1 = *reinterpret_cast<const short4*>(&vst[buf][KIDX4(dt * 16 + lr, 36 + lg * 8)]);
      bf16x8 va0 = {lo0.x, lo0.y, lo0.z, lo0.w, hi0.x, hi0.y, hi0.z, hi0.w};
      bf16x8 va1 = {lo1.x, lo1.y, lo1.z, lo1.w, hi1.x, hi1.y, hi1.z, hi1.w};
      od[dt] = __builtin_amdgcn_mfma_f32_16x16x32_bf16(va0, pf0, od[dt], 0, 0, 0);
      od[dt] = __builtin_amdgcn_mfma_f32_16x16x32_bf16(va1, pf1, od[dt], 0, 0, 0);
    }
    __builtin_amdgcn_s_setprio(0);
  };

  // prologue: load tile 0 into regs
  {
    int pos0, base; bool masked, part;
    tile_pos(0, pos0, base, masked, part);
    load_regs(pos0);
  }
  // main loop: one barrier per tile (write_lds(i) vs compute(i-2) fenced by i-1's barrier)
  for (int i = 0; i < nt; ++i) {
    write_lds(i & 1);
    __syncthreads();
    int pos0, base; bool masked, part;
    tile_pos(i, pos0, base, masked, part);
    if (i + 1 < nt) {
      int npos, nbase; bool nmask, npart;
      tile_pos(i + 1, npos, nbase, nmask, npart);
      load_regs(npos);  // HBM loads in flight under compute
    }
    if (part) compute(i & 1, pos0, base, masked);
  }

  // epilogue: od^T holds O[q=lr][d=dt*16+lg*4+r]
  float inv = 1.0f / lsum;
  #pragma unroll
  for (int dt = 0; dt < 4; ++dt) {
    ushort4 o4;
    o4.x = (u16)f2bf(od[dt][0] * inv);
    o4.y = (u16)f2bf(od[dt][1] * inv);
    o4.z = (u16)f2bf(od[dt][2] * inv);
    o4.w = (u16)f2bf(od[dt][3] * inv);
    *reinterpret_cast<ushort4*>(
        &ob[((size_t)(b * T_) + tq) * D_ + h * 64 + dt * 16 + lg * 4]) = o4;
  }
}

extern "C" void kernel_launch(void* const* d_in, const int* in_sizes, int n_in,
                              void* d_out, int out_size, void* d_ws, size_t ws_size,
                              hipStream_t stream) {
  (void)in_sizes; (void)n_in; (void)out_size;
  const int* tokens = (const int*)d_in[0];
  const int* mem_ids = (const int*)d_in[1];
  const float* mem_emb = (const float*)d_in[2];
  const float* ssum = (const float*)d_in[3];
  const float* embed = (const float*)d_in[4];
  const float* engram_t = (const float*)d_in[5];
  const float* engram_g = (const float*)d_in[6];
  const float* engram_s = (const float*)d_in[7];
  const float* mem_W = (const float*)d_in[8];
  const float* mem_b = (const float*)d_in[9];
  const float* mem_s = (const float*)d_in[10];
  const float* alpha_g = (const float*)d_in[11];
  const float* ssum_W = (const float*)d_in[12];
  const float* ln1 = (const float*)d_in[13];
  const float* qW = (const float*)d_in[14];
  const float* qbias = (const float*)d_in[15];
  const float* kW = (const float*)d_in[16];
  const float* kbias = (const float*)d_in[17];
  const float* vW = (const float*)d_in[18];
  const float* vbias = (const float*)d_in[19];
  const float* oW = (const float*)d_in[20];
  const float* obias = (const float*)d_in[21];
  const float* ln2 = (const float*)d_in[22];
  const float* w_in = (const float*)d_in[23];
  const float* w_out = (const float*)d_in[24];
  const float* final_s = (const float*)d_in[25];

  const size_t KVSZ = (size_t)B_ * TK_ * D_;   // elements per K or V plane
  // batched layout needs ~200 MB; fall back to per-layer if workspace is smaller
  size_t need = (KVSZ * 2 * 2 * L_) + 120u * 1024 * 1024;
  bool batched = ws_size >= need;

  char* p = (char*)d_ws;
  auto alloc = [&](size_t bytes) { char* r = p; p += (bytes + 255) & ~(size_t)255; return r; };
  u16* kv_b   = (u16*)alloc(KVSZ * 2);
  float* cx   = (float*)alloc((size_t)B_ * T_ * D_ * 4);
  u16* nx_b   = (u16*)alloc((size_t)B_ * T_ * D_ * 2);   // also ob (attn out)
  u16* qb_b   = (u16*)alloc((size_t)B_ * T_ * D_ * 2);   // also mem_tmp f32
  int nkv = batched ? L_ : 1;
  u16* kb_all = (u16*)alloc(KVSZ * 2 * nkv);
  u16* vb_all = (u16*)alloc(KVSZ * 2 * nkv);
  u16* hb;
  if (batched) hb = (u16*)alloc((size_t)B_ * T_ * 2048 * 2);
  else hb = kb_all;  // spans kb+vb (17.8 MB >= 16.8 MB needed)
  u16* wqkvoT = (u16*)alloc((size_t)L_ * 4 * D_ * D_ * 2);
  u16* wiT    = (u16*)alloc((size_t)L_ * 4096 * 512 * 2);
  u16* woutT  = (u16*)alloc((size_t)L_ * 512 * 2048 * 2);
  float* ssp  = (float*)alloc((size_t)B_ * D_ * 4);
  float* rc   = (float*)alloc((size_t)TK_ * 32 * 4);
  float* rs   = (float*)alloc((size_t)TK_ * 32 * 4);
  float* mem_tmp = (float*)qb_b;
  u16* ob_b = nx_b;

  // preamble + batched weight conversion
  rope_table_k<<<TK_ * 32 / 64, 64, 0, stream>>>(rc, rs);
  wconv_qkvo_k<<<dim3(8, 8, L_ * 4), 256, 0, stream>>>(qW, kW, vW, oW, wqkvoT);
  wconv_win_k<<<dim3(64, 8, L_), 256, 0, stream>>>(w_in, wiT);
  wconv_wout_k<<<dim3(8, 32, L_), 256, 0, stream>>>(w_out, woutT);
  ssum_proj_k<<<dim3(2, B_), 256, 0, stream>>>(ssum, ssum_W, ssp);
  sgemm_k<<<dim3(8, 8), 256, 0, stream>>>(mem_emb, mem_W, mem_b, mem_tmp, B_ * O_, D_, D_);
  memnorm_k<<<dim3(O_, B_), 128, 0, stream>>>(mem_tmp, mem_s, kv_b);
  engram_k<<<dim3(T_, B_), 128, 0, stream>>>(tokens, mem_ids, engram_t, engram_g, engram_s, kv_b);
  embed_k<<<dim3(T_, B_), 128, 0, stream>>>(tokens, embed, ssp, alpha_g, cx, kv_b);

  if (batched) {
    // all 6 layers' K/V in one dispatch (kv_seq is layer-invariant)
    kv_gemm_k<<<dim3(8, 68, L_), 256, 0, stream>>>(kv_b, wqkvoT, kbias, vbias,
                                                   kb_all, vb_all, rc, rs, 0, KVSZ);
  }

  const size_t WSZ = (size_t)D_ * D_;
  for (int l = 0; l < L_; ++l) {
    const u16* wqT = wqkvoT + ((size_t)l * 4 + 0) * WSZ;
    const u16* woT = wqkvoT + ((size_t)l * 4 + 3) * WSZ;
    const u16* wil = wiT + (size_t)l * 4096 * 512;
    const u16* wol = woutT + (size_t)l * 512 * 2048;
    u16* kb_l = batched ? kb_all + (size_t)l * KVSZ : kb_all;
    u16* vb_l = batched ? vb_all + (size_t)l * KVSZ : vb_all;

    rmsnorm_k<1><<<B_ * T_, 128, 0, stream>>>(cx, ln1 + l * D_, nx_b);
    gemm_bf16_k<1, 2><<<dim3(4, 64), 256, 0, stream>>>(nx_b, wqT, qbias + l * D_, qb_b,
                                                       B_ * T_, D_, D_, T_, rc, rs);
    if (!batched) {
      kv_gemm_k<<<dim3(8, 68, 1), 256, 0, stream>>>(kv_b, wqkvoT, kbias, vbias,
                                                    kb_l, vb_l, rc, rs, l, 0);
    }
    attn_mfma_k<<<dim3(256), 512, 0, stream>>>(qb_b, kb_l, vb_l, tokens, ob_b);
    gemm_bf16_k<2, 2><<<dim3(4, 64), 256, 0, stream>>>(ob_b, woT, obias + l * D_, cx,
                                                       B_ * T_, D_, D_, 0, nullptr, nullptr);
    rmsnorm_k<1><<<B_ * T_, 128, 0, stream>>>(cx, ln2 + l * D_, nx_b);
    mlp_in_mfma_k<<<dim3(32, 32), 256, 0, stream>>>(nx_b, wil, hb);
    gemm_bf16_k<2, 2><<<dim3(4, 64), 256, 0, stream>>>(hb, wol, nullptr, cx,
                                                       B_ * T_, D_, 2048, 0, nullptr, nullptr);
  }
  rmsnorm_k<0><<<B_ * T_, 128, 0, stream>>>(cx, final_s, d_out);
}

// Round 8
// 1087.887 us; speedup vs baseline: 12.1306x; 1.0625x over previous
//
#include <hip/hip_runtime.h>
#include <hip/hip_bf16.h>
#include <math.h>

#define B_ 4
#define T_ 1024
#define O_ 128
#define D_ 512
#define H_ 8
#define L_ 6
#define TK_ 2176
#define MM_ 100000
#define EH_ 4
#define EHD_ 128
#define HD_ 64

typedef float f32x4 __attribute__((ext_vector_type(4)));
typedef short bf16x8 __attribute__((ext_vector_type(8)));
typedef unsigned short u16;

// PRIMES per reference: base=131, x=base+h*1009; row[i]=x; x=x*31+1 (uint32 wrap)
__device__ __constant__ unsigned int PRIMES_[4][4] = {
  {131u,  4062u,  125923u, 3903614u},
  {1140u, 35341u, 1095572u, 33962733u},
  {2149u, 66620u, 2065221u, 64021852u},
  {3158u, 97899u, 3034870u, 94080971u},
};

__device__ __forceinline__ float wave_sum_f(float v) {
  #pragma unroll
  for (int off = 32; off; off >>= 1) v += __shfl_xor(v, off);
  return v;
}

__device__ __forceinline__ short f2bf(float f) {
  unsigned int u = __float_as_uint(f);
  unsigned int r = (u + 0x7fffu + ((u >> 16) & 1u)) >> 16;
  return (short)r;
}

__device__ __forceinline__ void gload16(const void* g, void* l) {
  __builtin_amdgcn_global_load_lds((const __attribute__((address_space(1))) void*)g,
                                   (__attribute__((address_space(3))) void*)l, 16, 0, 0);
}

// ---------------- rope tables: cos/sin [TK][32] ----------------
__global__ __launch_bounds__(64) void rope_table_k(float* __restrict__ rc,
                                                   float* __restrict__ rs) {
  int i = blockIdx.x * 64 + threadIdx.x;
  int t = i >> 5, j = i & 31;
  float freq = __powf(10000.0f, -(float)j / 32.0f);
  float ang = (float)t * freq;
  rc[i] = cosf(ang);
  rs[i] = sinf(ang);
}

// ---------------- ssum @ ssum_W -> ssp[B][D] ----------------
__global__ __launch_bounds__(256) void ssum_proj_k(const float* __restrict__ ssum,
                                                   const float* __restrict__ sW,
                                                   float* __restrict__ ssp) {
  int col = blockIdx.x * 256 + threadIdx.x;
  int b = blockIdx.y;
  float acc = 0.f;
  for (int d = 0; d < D_; ++d) acc += ssum[b * D_ + d] * sW[(size_t)d * D_ + col];
  ssp[b * D_ + col] = acc;
}

// ---------------- f32 tiled GEMM (preamble mem projection only) ----------------
__global__ __launch_bounds__(256) void sgemm_k(const float* __restrict__ A,
                                               const float* __restrict__ W,
                                               const float* __restrict__ bias,
                                               float* __restrict__ C,
                                               int M, int N, int K) {
  __shared__ float As[16][68];
  __shared__ float Bs[16][68];
  int tid = threadIdx.x;
  int row0 = blockIdx.y * 64;
  int col0 = blockIdx.x * 64;
  int tx = tid & 15, ty = tid >> 4;
  int am = tid >> 2, ak = (tid & 3) * 4;
  int bk = tid >> 4, bc = (tid & 15) * 4;
  float acc[4][4] = {};
  for (int k0 = 0; k0 < K; k0 += 16) {
    float4 av = *reinterpret_cast<const float4*>(&A[(size_t)(row0 + am) * K + k0 + ak]);
    As[ak + 0][am] = av.x; As[ak + 1][am] = av.y; As[ak + 2][am] = av.z; As[ak + 3][am] = av.w;
    float4 bv = *reinterpret_cast<const float4*>(&W[(size_t)(k0 + bk) * N + col0 + bc]);
    *reinterpret_cast<float4*>(&Bs[bk][bc]) = bv;
    __syncthreads();
    #pragma unroll
    for (int kk = 0; kk < 16; ++kk) {
      float4 a4 = *reinterpret_cast<const float4*>(&As[kk][ty * 4]);
      float4 b4 = *reinterpret_cast<const float4*>(&Bs[kk][tx * 4]);
      float a[4] = {a4.x, a4.y, a4.z, a4.w};
      float b[4] = {b4.x, b4.y, b4.z, b4.w};
      #pragma unroll
      for (int i = 0; i < 4; ++i)
        #pragma unroll
        for (int j = 0; j < 4; ++j) acc[i][j] += a[i] * b[j];
    }
    __syncthreads();
  }
  int cbase = col0 + tx * 4;
  float4 b4 = *reinterpret_cast<const float4*>(&bias[cbase]);
  float bb[4] = {b4.x, b4.y, b4.z, b4.w};
  #pragma unroll
  for (int i = 0; i < 4; ++i) {
    int row = row0 + ty * 4 + i;
    *reinterpret_cast<float4*>(&C[(size_t)row * N + cbase]) =
        make_float4(acc[i][0] + bb[0], acc[i][1] + bb[1], acc[i][2] + bb[2], acc[i][3] + bb[3]);
  }
}

// ---------------- batched weight convert+transpose: f32 [K][N] -> bf16 [N][K] ----------------
__device__ __forceinline__ void wconv_tile(const float* __restrict__ W, u16* __restrict__ wT,
                                           int K, int N) {
  __shared__ float s[64][65];
  int n0 = blockIdx.x * 64, k0 = blockIdx.y * 64;
  int tid = threadIdx.x;
  int kr = tid >> 4, nc = (tid & 15) * 4;
  #pragma unroll
  for (int kk = 0; kk < 4; ++kk) {
    float4 f = *reinterpret_cast<const float4*>(&W[(size_t)(k0 + kr + kk * 16) * N + n0 + nc]);
    s[kr + kk * 16][nc + 0] = f.x; s[kr + kk * 16][nc + 1] = f.y;
    s[kr + kk * 16][nc + 2] = f.z; s[kr + kk * 16][nc + 3] = f.w;
  }
  __syncthreads();
  int nr = tid >> 4, kc = (tid & 15) * 4;
  #pragma unroll
  for (int nn = 0; nn < 4; ++nn) {
    int n = nr + nn * 16;
    ushort4 o;
    o.x = (u16)f2bf(s[kc + 0][n]); o.y = (u16)f2bf(s[kc + 1][n]);
    o.z = (u16)f2bf(s[kc + 2][n]); o.w = (u16)f2bf(s[kc + 3][n]);
    *reinterpret_cast<ushort4*>(&wT[(size_t)(n0 + n) * K + k0 + kc]) = o;
  }
}

__global__ __launch_bounds__(256) void wconv_qkvo_k(const float* __restrict__ qW,
                                                    const float* __restrict__ kW,
                                                    const float* __restrict__ vW,
                                                    const float* __restrict__ oW,
                                                    u16* __restrict__ dst) {
  int z = blockIdx.z;
  int l = z >> 2, which = z & 3;
  const float* src = which == 0 ? qW : which == 1 ? kW : which == 2 ? vW : oW;
  wconv_tile(src + (size_t)l * D_ * D_, dst + (size_t)z * D_ * D_, D_, D_);
}

__global__ __launch_bounds__(256) void wconv_win_k(const float* __restrict__ w_in,
                                                   u16* __restrict__ dst) {
  int l = blockIdx.z;
  wconv_tile(w_in + (size_t)l * 512 * 4096, dst + (size_t)l * 4096 * 512, 512, 4096);
}

__global__ __launch_bounds__(256) void wconv_wout_k(const float* __restrict__ w_out,
                                                    u16* __restrict__ dst) {
  int l = blockIdx.z;
  wconv_tile(w_out + (size_t)l * 2048 * 512, dst + (size_t)l * 512 * 2048, 2048, 512);
}

// ---------------- small MFMA GEMM: 64x64 tile, 4 waves (wave 32x32), 2 blocks/CU ----------------
// A bf16 [M][K], Bt bf16 [N][K]. EPI: 1 = bf16 out + bias + rope, 2 = f32 += (+opt bias)
template<int EPI>
__global__ __launch_bounds__(256) void gemm_sm_k(const u16* __restrict__ A,
                                                 const u16* __restrict__ Bt,
                                                 const float* __restrict__ bias,
                                                 void* __restrict__ Cout,
                                                 int M, int N, int K, int posmod,
                                                 const float* __restrict__ rc,
                                                 const float* __restrict__ rs) {
  __shared__ __align__(16) u16 As[2][64 * 32];
  __shared__ __align__(16) u16 Bs[2][64 * 32];
  int tid = threadIdx.x;
  int w = tid >> 6, lane = tid & 63;
  int lr = lane & 15, lg = lane >> 4;
  int row0 = blockIdx.y * 64, col0 = blockIdx.x * 64;
  int wr = w >> 1, wc = w & 1;
  f32x4 acc[2][2] = {};

  int srow = tid >> 2;          // 0..63
  int skel = (tid & 3) * 8;     // 0,8,16,24

  auto stage = [&](int buf, int k0) {
    gload16(A + (size_t)(row0 + srow) * K + k0 + skel, &As[buf][srow * 32 + skel]);
    gload16(Bt + (size_t)(col0 + srow) * K + k0 + skel, &Bs[buf][srow * 32 + skel]);
  };

  stage(0, 0);
  __syncthreads();
  int nk = K >> 5;
  int buf = 0;
  for (int t = 0; t < nk; ++t) {
    if (t + 1 < nk) stage(buf ^ 1, (t + 1) * 32);
    bf16x8 af[2], bf[2];
    #pragma unroll
    for (int i = 0; i < 2; ++i)
      af[i] = *reinterpret_cast<const bf16x8*>(&As[buf][(wr * 32 + i * 16 + lr) * 32 + lg * 8]);
    #pragma unroll
    for (int j = 0; j < 2; ++j)
      bf[j] = *reinterpret_cast<const bf16x8*>(&Bs[buf][(wc * 32 + j * 16 + lr) * 32 + lg * 8]);
    #pragma unroll
    for (int i = 0; i < 2; ++i)
      #pragma unroll
      for (int j = 0; j < 2; ++j)
        acc[i][j] = __builtin_amdgcn_mfma_f32_16x16x32_bf16(af[i], bf[j], acc[i][j], 0, 0, 0);
    __syncthreads();
    buf ^= 1;
  }

  #pragma unroll
  for (int j = 0; j < 2; ++j) {
    int col = col0 + wc * 32 + j * 16 + lr;
    float bs = bias ? bias[col] : 0.f;
    #pragma unroll
    for (int i = 0; i < 2; ++i) {
      #pragma unroll
      for (int r = 0; r < 4; ++r) {
        int row = row0 + wr * 32 + i * 16 + lg * 4 + r;
        float v = acc[i][j][r] + bs;
        if (EPI == 1) {
          int pos = row % posmod;
          int d = col & 63;
          float c = rc[(size_t)pos * 32 + (d >> 1)];
          float s = rs[(size_t)pos * 32 + (d >> 1)];
          float partner = __shfl_xor(v, 1);
          v = (d & 1) ? (partner * s + v * c) : (v * c - partner * s);
        }
        if (EPI == 2) {
          float* Cf = (float*)Cout;
          Cf[(size_t)row * N + col] += v;
        } else {
          u16* Cb = (u16*)Cout;
          Cb[(size_t)row * N + col] = (u16)f2bf(v);
        }
      }
    }
  }
}

// ---------------- fused K+V projection (batched over layers via grid.z) ----------------
// Vectorized epilogue: stage 128x64 output in LDS, store 16B chunks (kills write-allocate).
__global__ __launch_bounds__(256) void kv_gemm_k(const u16* __restrict__ A,
                                                 const u16* __restrict__ wqkvoT,
                                                 const float* __restrict__ kbias_all,
                                                 const float* __restrict__ vbias_all,
                                                 u16* __restrict__ kb_base,
                                                 u16* __restrict__ vb_base,
                                                 const float* __restrict__ rc,
                                                 const float* __restrict__ rs,
                                                 int l0, size_t ostride) {
  __shared__ __align__(16) u16 As[2][128 * 32];
  __shared__ __align__(16) u16 Bk[2][64 * 32];
  __shared__ __align__(16) u16 Bv[2][64 * 32];
  const int K = 512, N = 512;
  int l = l0 + blockIdx.z;
  const u16* wkT = wqkvoT + ((size_t)l * 4 + 1) * (D_ * D_);
  const u16* wvT = wqkvoT + ((size_t)l * 4 + 2) * (D_ * D_);
  const float* kbias = kbias_all + l * D_;
  const float* vbias = vbias_all + l * D_;
  u16* kb = kb_base + (size_t)blockIdx.z * ostride;
  u16* vb = vb_base + (size_t)blockIdx.z * ostride;
  int tid = threadIdx.x;
  int w = tid >> 6, lane = tid & 63;
  int lr = lane & 15, lg = lane >> 4;
  int row0 = blockIdx.y * 128, col0 = blockIdx.x * 64;
  int wr = w >> 1, wc = w & 1;
  f32x4 ak_[4][2] = {};
  f32x4 av_[4][2] = {};

  int srow = lane >> 2;
  int skel = (lane & 3) * 8;

  auto stage = [&](int buf, int k0) {
    #pragma unroll
    for (int ci = 0; ci < 2; ++ci) {
      int c = w * 2 + ci;
      gload16(A + (size_t)(row0 + c * 16 + srow) * K + k0 + skel, &As[buf][c * 512]);
    }
    gload16(wkT + (size_t)(col0 + w * 16 + srow) * K + k0 + skel, &Bk[buf][w * 512]);
    gload16(wvT + (size_t)(col0 + w * 16 + srow) * K + k0 + skel, &Bv[buf][w * 512]);
  };

  stage(0, 0);
  __syncthreads();
  int buf = 0;
  for (int t = 0; t < 16; ++t) {
    if (t + 1 < 16) stage(buf ^ 1, (t + 1) * 32);
    bf16x8 af[4], bk[2], bv[2];
    #pragma unroll
    for (int i = 0; i < 4; ++i)
      af[i] = *reinterpret_cast<const bf16x8*>(&As[buf][(wr * 64 + i * 16 + lr) * 32 + lg * 8]);
    #pragma unroll
    for (int j = 0; j < 2; ++j) {
      bk[j] = *reinterpret_cast<const bf16x8*>(&Bk[buf][(wc * 32 + j * 16 + lr) * 32 + lg * 8]);
      bv[j] = *reinterpret_cast<const bf16x8*>(&Bv[buf][(wc * 32 + j * 16 + lr) * 32 + lg * 8]);
    }
    #pragma unroll
    for (int i = 0; i < 4; ++i)
      #pragma unroll
      for (int j = 0; j < 2; ++j) {
        ak_[i][j] = __builtin_amdgcn_mfma_f32_16x16x32_bf16(af[i], bk[j], ak_[i][j], 0, 0, 0);
        av_[i][j] = __builtin_amdgcn_mfma_f32_16x16x32_bf16(af[i], bv[j], av_[i][j], 0, 0, 0);
      }
    __syncthreads();
    buf ^= 1;
  }

  // epilogue: rope+bias -> LDS staging (reuse As: 16 KB = 128x64 u16) -> 16B stores
  u16* stg = &As[0][0];
  __syncthreads();
  #pragma unroll
  for (int pass = 0; pass < 2; ++pass) {
    #pragma unroll
    for (int j = 0; j < 2; ++j) {
      int lcol = wc * 32 + j * 16 + lr;
      int gcol = col0 + lcol;
      float bs = pass ? vbias[gcol] : kbias[gcol];
      int d = gcol & 63;
      #pragma unroll
      for (int i = 0; i < 4; ++i) {
        #pragma unroll
        for (int r = 0; r < 4; ++r) {
          int lrow = wr * 64 + i * 16 + lg * 4 + r;
          float v = (pass ? av_[i][j][r] : ak_[i][j][r]) + bs;
          if (!pass) {
            int pos = (row0 + lrow) % TK_;
            float c = rc[(size_t)pos * 32 + (d >> 1)];
            float s = rs[(size_t)pos * 32 + (d >> 1)];
            float partner = __shfl_xor(v, 1);
            v = (d & 1) ? (partner * s + v * c) : (v * c - partner * s);
          }
          stg[lrow * 64 + lcol] = (u16)f2bf(v);
        }
      }
    }
    __syncthreads();
    {
      int trow = tid >> 1, tc0 = (tid & 1) * 32;
      u16* dst = (pass ? vb : kb) + (size_t)(row0 + trow) * N + col0 + tc0;
      const u16* src = &stg[trow * 64 + tc0];
      #pragma unroll
      for (int c = 0; c < 4; ++c)
        *reinterpret_cast<bf16x8*>(dst + c * 8) = *reinterpret_cast<const bf16x8*>(src + c * 8);
    }
    __syncthreads();
  }
}

// ---------------- fused MLP-in MFMA ----------------
__global__ __launch_bounds__(256) void mlp_in_mfma_k(const u16* __restrict__ A,
                                                     const u16* __restrict__ wiT,
                                                     u16* __restrict__ Hout) {
  __shared__ __align__(16) u16 As[2][128 * 32];
  __shared__ __align__(16) u16 Bg[2][64 * 32];
  __shared__ __align__(16) u16 Bv[2][64 * 32];
  int tid = threadIdx.x;
  int w = tid >> 6, lane = tid & 63;
  int lr = lane & 15, lg = lane >> 4;
  int hc0 = blockIdx.x * 64, row0 = blockIdx.y * 128;
  int wr = w >> 1, wc = w & 1;
  f32x4 ag[4][2] = {};
  f32x4 av[4][2] = {};
  const int K = 512;

  int srow = lane >> 2;
  int skel = (lane & 3) * 8;

  auto stage = [&](int buf, int k0) {
    #pragma unroll
    for (int ci = 0; ci < 2; ++ci) {
      int c = w * 2 + ci;
      gload16(A + (size_t)(row0 + c * 16 + srow) * K + k0 + skel, &As[buf][c * 512]);
    }
    gload16(wiT + (size_t)(hc0 + w * 16 + srow) * K + k0 + skel, &Bg[buf][w * 512]);
    gload16(wiT + (size_t)(2048 + hc0 + w * 16 + srow) * K + k0 + skel, &Bv[buf][w * 512]);
  };

  stage(0, 0);
  __syncthreads();
  int buf = 0;
  for (int t = 0; t < 16; ++t) {
    if (t + 1 < 16) stage(buf ^ 1, (t + 1) * 32);
    bf16x8 af[4], bg[2], bv[2];
    #pragma unroll
    for (int i = 0; i < 4; ++i)
      af[i] = *reinterpret_cast<const bf16x8*>(&As[buf][(wr * 64 + i * 16 + lr) * 32 + lg * 8]);
    #pragma unroll
    for (int j = 0; j < 2; ++j) {
      bg[j] = *reinterpret_cast<const bf16x8*>(&Bg[buf][(wc * 32 + j * 16 + lr) * 32 + lg * 8]);
      bv[j] = *reinterpret_cast<const bf16x8*>(&Bv[buf][(wc * 32 + j * 16 + lr) * 32 + lg * 8]);
    }
    #pragma unroll
    for (int i = 0; i < 4; ++i)
      #pragma unroll
      for (int j = 0; j < 2; ++j) {
        ag[i][j] = __builtin_amdgcn_mfma_f32_16x16x32_bf16(af[i], bg[j], ag[i][j], 0, 0, 0);
        av[i][j] = __builtin_amdgcn_mfma_f32_16x16x32_bf16(af[i], bv[j], av[i][j], 0, 0, 0);
      }
    __syncthreads();
    buf ^= 1;
  }

  #pragma unroll
  for (int j = 0; j < 2; ++j) {
    int col = hc0 + wc * 32 + j * 16 + lr;
    #pragma unroll
    for (int i = 0; i < 4; ++i) {
      #pragma unroll
      for (int r = 0; r < 4; ++r) {
        int row = row0 + wr * 64 + i * 16 + lg * 4 + r;
        float g = ag[i][j][r];
        float sg = g / (1.f + __expf(-g));
        Hout[(size_t)row * 2048 + col] = (u16)f2bf(sg * av[i][j][r]);
      }
    }
  }
}

// ---------------- rmsnorm rows ----------------
template<int OUTBF>
__global__ __launch_bounds__(128) void rmsnorm_k(const float* __restrict__ in,
                                                 const float* __restrict__ scale,
                                                 void* __restrict__ out) {
  int row = blockIdx.x;
  int tid = threadIdx.x;
  float4 v = *reinterpret_cast<const float4*>(&in[(size_t)row * D_ + tid * 4]);
  float ss = v.x * v.x + v.y * v.y + v.z * v.z + v.w * v.w;
  ss = wave_sum_f(ss);
  __shared__ float red[2];
  if ((tid & 63) == 0) red[tid >> 6] = ss;
  __syncthreads();
  ss = red[0] + red[1];
  float inv = 1.0f / sqrtf(ss / (float)D_ + 1e-6f);
  float4 sc = *reinterpret_cast<const float4*>(&scale[tid * 4]);
  float o0 = v.x * inv * sc.x, o1 = v.y * inv * sc.y, o2 = v.z * inv * sc.z, o3 = v.w * inv * sc.w;
  if (OUTBF) {
    ushort4 o;
    o.x = (u16)f2bf(o0); o.y = (u16)f2bf(o1); o.z = (u16)f2bf(o2); o.w = (u16)f2bf(o3);
    *reinterpret_cast<ushort4*>((u16*)out + (size_t)row * D_ + tid * 4) = o;
  } else {
    *reinterpret_cast<float4*>((float*)out + (size_t)row * D_ + tid * 4) =
        make_float4(o0, o1, o2, o3);
  }
}

// ---------------- mem rows ----------------
__global__ __launch_bounds__(128) void memnorm_k(const float* __restrict__ tmp,
                                                 const float* __restrict__ scale,
                                                 u16* __restrict__ kv) {
  int o = blockIdx.x, b = blockIdx.y;
  int tid = threadIdx.x;
  float4 v = *reinterpret_cast<const float4*>(&tmp[(size_t)(b * O_ + o) * D_ + tid * 4]);
  float ss = v.x * v.x + v.y * v.y + v.z * v.z + v.w * v.w;
  ss = wave_sum_f(ss);
  __shared__ float red[2];
  if ((tid & 63) == 0) red[tid >> 6] = ss;
  __syncthreads();
  ss = red[0] + red[1];
  float inv = 1.0f / sqrtf(ss / (float)D_ + 1e-6f);
  float4 sc = *reinterpret_cast<const float4*>(&scale[tid * 4]);
  ushort4 oo;
  oo.x = (u16)f2bf(v.x * inv * sc.x); oo.y = (u16)f2bf(v.y * inv * sc.y);
  oo.z = (u16)f2bf(v.z * inv * sc.z); oo.w = (u16)f2bf(v.w * inv * sc.w);
  *reinterpret_cast<ushort4*>(&kv[(size_t)(b * TK_ + o) * D_ + tid * 4]) = oo;
}

// ---------------- engram rows ----------------
__global__ __launch_bounds__(128) void engram_k(const int* __restrict__ tokens,
                                                const int* __restrict__ mem_ids,
                                                const float* __restrict__ etab,
                                                const float* __restrict__ egate,
                                                const float* __restrict__ escale,
                                                u16* __restrict__ kv) {
  int t = blockIdx.x, b = blockIdx.y;
  int tid = threadIdx.x;
  unsigned int toks[4];
  #pragma unroll
  for (int i = 0; i < 4; ++i) {
    int idx = t - i;
    toks[i] = (idx >= 0) ? (unsigned int)tokens[b * T_ + idx]
                         : (unsigned int)mem_ids[b * O_ + O_ + idx];
  }
  int c = tid * 4;
  int h = c >> 7;
  int e = c & 127;
  unsigned int hs = 0;
  #pragma unroll
  for (int i = 0; i < 4; ++i) hs += toks[i] * PRIMES_[h][i];
  int idxh = (int)(hs % (unsigned int)MM_);
  float4 r = *reinterpret_cast<const float4*>(&etab[((size_t)idxh * EH_ + h) * EHD_ + e]);
  float4 g = *reinterpret_cast<const float4*>(&egate[h * EHD_ + e]);
  float4 val;
  val.x = r.x / (1.f + __expf(-g.x));
  val.y = r.y / (1.f + __expf(-g.y));
  val.z = r.z / (1.f + __expf(-g.z));
  val.w = r.w / (1.f + __expf(-g.w));
  float ss = val.x * val.x + val.y * val.y + val.z * val.z + val.w * val.w;
  ss = wave_sum_f(ss);
  __shared__ float red[2];
  if ((tid & 63) == 0) red[tid >> 6] = ss;
  __syncthreads();
  ss = red[0] + red[1];
  float inv = 1.0f / sqrtf(ss / (float)D_ + 1e-6f);
  float4 sc = *reinterpret_cast<const float4*>(&escale[c]);
  ushort4 oo;
  oo.x = (u16)f2bf(val.x * inv * sc.x); oo.y = (u16)f2bf(val.y * inv * sc.y);
  oo.z = (u16)f2bf(val.z * inv * sc.z); oo.w = (u16)f2bf(val.w * inv * sc.w);
  *reinterpret_cast<ushort4*>(&kv[(size_t)(b * TK_ + O_ + t) * D_ + c]) = oo;
}

// ---------------- embed + ssum inject ----------------
__global__ __launch_bounds__(128) void embed_k(const int* __restrict__ tokens,
                                               const float* __restrict__ etab,
                                               const float* __restrict__ ssp,
                                               const float* __restrict__ alpha_g,
                                               float* __restrict__ cx,
                                               u16* __restrict__ kv) {
  int t = blockIdx.x, b = blockIdx.y;
  int tid = threadIdx.x;
  int c = tid * 4;
  int tok = tokens[b * T_ + t];
  float4 e = *reinterpret_cast<const float4*>(&etab[(size_t)tok * D_ + c]);
  float4 sp = *reinterpret_cast<const float4*>(&ssp[b * D_ + c]);
  float4 ag = *reinterpret_cast<const float4*>(&alpha_g[c]);
  float4 x;
  x.x = e.x + sp.x / (1.f + __expf(-ag.x));
  x.y = e.y + sp.y / (1.f + __expf(-ag.y));
  x.z = e.z + sp.z / (1.f + __expf(-ag.z));
  x.w = e.w + sp.w / (1.f + __expf(-ag.w));
  *reinterpret_cast<float4*>(&cx[(size_t)(b * T_ + t) * D_ + c]) = x;
  ushort4 oo;
  oo.x = (u16)f2bf(x.x); oo.y = (u16)f2bf(x.y);
  oo.z = (u16)f2bf(x.z); oo.w = (u16)f2bf(x.w);
  *reinterpret_cast<ushort4*>(&kv[(size_t)(b * TK_ + O_ + T_ + t) * D_ + c]) = oo;
}

// ---------------- MFMA flash attention v4: 8 waves, paired q-tiles share staged K/V ----------------
#define KIDX8(r, c) (((r) << 6) + ((c) ^ (((r) & 7) << 3)))
#define KIDX4(r, c) (((r) << 6) + ((c) ^ (((r) & 15) << 2)))
#define PIDX(q, o) (((q) << 5) + ((o) ^ (((q) & 7) << 2)))

__global__ __launch_bounds__(512) void attn_mfma_k(const u16* __restrict__ qb,
                                                   const u16* __restrict__ kb,
                                                   const u16* __restrict__ vb,
                                                   const int* __restrict__ tokens,
                                                   u16* __restrict__ ob) {
  __shared__ __align__(16) short ks[2][64 * 64];
  __shared__ __align__(16) short vst[2][64 * 64];        // transposed: [d][k]
  __shared__ __align__(16) unsigned int pbuf[8][16 * 32]; // per-wave P^T packed pairs
  __shared__ unsigned char vtok[T_];

  int fid = blockIdx.x;       // 256 blocks
  int h = fid & 7;
  int s = fid >> 3;           // 0..31
  int pair = s & 7;           // bxA = pair, bxB = 15 - pair
  int b = s >> 3;             // 0..3
  int bxA = pair, bxB = 15 - pair;

  int tid = threadIdx.x;
  int w = tid >> 6, lane = tid & 63;
  int lr = lane & 15;
  int lg = lane >> 4;
  int myBx = (w < 4) ? bxA : bxB;
  int qw0 = myBx * 64 + (w & 3) * 16;
  int tq = qw0 + lr;  // this lane's query row

  for (int i = tid; i < T_; i += 512) vtok[i] = (tokens[b * T_ + i] != 0);

  bf16x8 aq[2];  // Q for this lane's q row: B-operand (col=lr, d=lg*8..)
  {
    const u16* qp = &qb[((size_t)(b * T_) + tq) * D_ + h * 64];
    aq[0] = *reinterpret_cast<const bf16x8*>(qp + lg * 8);
    aq[1] = *reinterpret_cast<const bf16x8*>(qp + 32 + lg * 8);
  }

  float m_ = -1e30f, lsum = 0.f;
  f32x4 od[4];
  #pragma unroll
  for (int dt = 0; dt < 4; ++dt) od[dt] = (f32x4){0.f, 0.f, 0.f, 0.f};

  int sr = tid >> 3;
  int sc = (tid & 7) * 8;
  int vr2 = (tid >> 4) * 2;
  int vc = (tid & 15) * 4;

  int nt = 2 + 2 * (bxB + 1);
  auto tile_pos = [&](int i, int& pos0, int& base, bool& masked, bool& part) {
    if (i < 2) { pos0 = i * 64; base = 0; masked = false; part = true; }
    else if (i < 3 + bxB) {
      int t = i - 2;
      pos0 = O_ + t * 64; base = O_; masked = true; part = (t <= myBx);
    } else {
      int t = i - (3 + bxB);
      pos0 = O_ + T_ + t * 64; base = O_ + T_; masked = true; part = (t <= myBx);
    }
  };

  bf16x8 pk0;
  short4 pv0, pv1;

  auto load_regs = [&](int pos0) {
    const u16* kg = &kb[((size_t)(b * TK_) + pos0 + sr) * D_ + h * 64 + sc];
    pk0 = *reinterpret_cast<const bf16x8*>(kg);
    const u16* vg = &vb[((size_t)(b * TK_) + pos0 + vr2) * D_ + h * 64 + vc];
    pv0 = *reinterpret_cast<const short4*>(vg);
    pv1 = *reinterpret_cast<const short4*>(vg + D_);
  };

  auto write_lds = [&](int buf) {
    *reinterpret_cast<bf16x8*>(&ks[buf][KIDX8(sr, sc)]) = pk0;
    unsigned int t0 = (unsigned int)(u16)pv0.x | ((unsigned int)(u16)pv1.x << 16);
    unsigned int t1 = (unsigned int)(u16)pv0.y | ((unsigned int)(u16)pv1.y << 16);
    unsigned int t2 = (unsigned int)(u16)pv0.z | ((unsigned int)(u16)pv1.z << 16);
    unsigned int t3 = (unsigned int)(u16)pv0.w | ((unsigned int)(u16)pv1.w << 16);
    *reinterpret_cast<unsigned int*>(&vst[buf][KIDX4(vc + 0, vr2)]) = t0;
    *reinterpret_cast<unsigned int*>(&vst[buf][KIDX4(vc + 1, vr2)]) = t1;
    *reinterpret_cast<unsigned int*>(&vst[buf][KIDX4(vc + 2, vr2)]) = t2;
    *reinterpret_cast<unsigned int*>(&vst[buf][KIDX4(vc + 3, vr2)]) = t3;
  };

  unsigned int* pw = (unsigned int*)pbuf[w];

  auto compute = [&](int buf, int pos0, int base, bool masked) {
    float sv[4][4];
    __builtin_amdgcn_s_setprio(1);
    #pragma unroll
    for (int kt = 0; kt < 4; ++kt) {
      bf16x8 ka0 = *reinterpret_cast<const bf16x8*>(&ks[buf][KIDX8(kt * 16 + lr, lg * 8)]);
      bf16x8 ka1 = *reinterpret_cast<const bf16x8*>(&ks[buf][KIDX8(kt * 16 + lr, 32 + lg * 8)]);
      f32x4 sf = (f32x4){0.f, 0.f, 0.f, 0.f};
      sf = __builtin_amdgcn_mfma_f32_16x16x32_bf16(ka0, aq[0], sf, 0, 0, 0);
      sf = __builtin_amdgcn_mfma_f32_16x16x32_bf16(ka1, aq[1], sf, 0, 0, 0);
      #pragma unroll
      for (int r = 0; r < 4; ++r) sv[kt][r] = sf[r];
    }
    __builtin_amdgcn_s_setprio(0);
    if (masked) {
      #pragma unroll
      for (int kt = 0; kt < 4; ++kt) {
        #pragma unroll
        for (int r = 0; r < 4; ++r) {
          int tk = pos0 + kt * 16 + lg * 4 + r - base;
          bool valid = (vtok[tk] != 0) && (tk <= tq);
          sv[kt][r] = valid ? sv[kt][r] * 0.125f : -1e30f;
        }
      }
    } else {
      #pragma unroll
      for (int kt = 0; kt < 4; ++kt)
        #pragma unroll
        for (int r = 0; r < 4; ++r) sv[kt][r] *= 0.125f;
    }
    float pmax = sv[0][0];
    #pragma unroll
    for (int kt = 0; kt < 4; ++kt)
      #pragma unroll
      for (int r = 0; r < 4; ++r) pmax = fmaxf(pmax, sv[kt][r]);
    pmax = fmaxf(pmax, __shfl_xor(pmax, 16));
    pmax = fmaxf(pmax, __shfl_xor(pmax, 32));
    float mnew = fmaxf(m_, pmax);
    float al = __expf(m_ - mnew);
    m_ = mnew;
    float psum = 0.f;
    #pragma unroll
    for (int kt = 0; kt < 4; ++kt)
      #pragma unroll
      for (int r = 0; r < 4; ++r) {
        float pe = __expf(sv[kt][r] - mnew);
        sv[kt][r] = pe;
        psum += pe;
      }
    psum += __shfl_xor(psum, 16);
    psum += __shfl_xor(psum, 32);
    lsum = lsum * al + psum;
    #pragma unroll
    for (int dt = 0; dt < 4; ++dt) {
      f32x4 o = od[dt];
      o[0] *= al; o[1] *= al; o[2] *= al; o[3] *= al;
      od[dt] = o;
    }
    #pragma unroll
    for (int kt = 0; kt < 4; ++kt) {
      uint2 wp;
      asm("v_cvt_pk_bf16_f32 %0, %1, %2" : "=v"(wp.x) : "v"(sv[kt][0]), "v"(sv[kt][1]));
      asm("v_cvt_pk_bf16_f32 %0, %1, %2" : "=v"(wp.y) : "v"(sv[kt][2]), "v"(sv[kt][3]));
      *reinterpret_cast<uint2*>(&pw[PIDX(lr, kt * 8 + lg * 2)]) = wp;
    }
    bf16x8 pf0 = *reinterpret_cast<const bf16x8*>(&pw[PIDX(lr, lg * 4)]);
    bf16x8 pf1 = *reinterpret_cast<const bf16x8*>(&pw[PIDX(lr, 16 + lg * 4)]);
    __builtin_amdgcn_s_setprio(1);
    #pragma unroll
    for (int dt = 0; dt < 4; ++dt) {
      short4 lo0 = *reinterpret_cast<const short4*>(&vst[buf][KIDX4(dt * 16 + lr, lg * 8)]);
      short4 hi0 = *reinterpret_cast<const short4*>(&vst[buf][KIDX4(dt * 16 + lr, lg * 8 + 4)]);
      short4 lo1 = *reinterpret_cast<const short4*>(&vst[buf][KIDX4(dt * 16 + lr, 32 + lg * 8)]);
      short4 hi1 = *reinterpret_cast<const short4*>(&vst[buf][KIDX4(dt * 16 + lr, 36 + lg * 8)]);
      bf16x8 va0 = {lo0.x, lo0.y, lo0.z, lo0.w, hi0.x, hi0.y, hi0.z, hi0.w};
      bf16x8 va1 = {lo1.x, lo1.y, lo1.z, lo1.w, hi1.x, hi1.y, hi1.z, hi1.w};
      od[dt] = __builtin_amdgcn_mfma_f32_16x16x32_bf16(va0, pf0, od[dt], 0, 0, 0);
      od[dt] = __builtin_amdgcn_mfma_f32_16x16x32_bf16(va1, pf1, od[dt], 0, 0, 0);
    }
    __builtin_amdgcn_s_setprio(0);
  };

  {
    int pos0, base; bool masked, part;
    tile_pos(0, pos0, base, masked, part);
    load_regs(pos0);
  }
  for (int i = 0; i < nt; ++i) {
    write_lds(i & 1);
    __syncthreads();
    int pos0, base; bool masked, part;
    tile_pos(i, pos0, base, masked, part);
    if (i + 1 < nt) {
      int npos, nbase; bool nmask, npart;
      tile_pos(i + 1, npos, nbase, nmask, npart);
      load_regs(npos);
    }
    if (part) compute(i & 1, pos0, base, masked);
  }

  float inv = 1.0f / lsum;
  #pragma unroll
  for (int dt = 0; dt < 4; ++dt) {
    ushort4 o4;
    o4.x = (u16)f2bf(od[dt][0] * inv);
    o4.y = (u16)f2bf(od[dt][1] * inv);
    o4.z = (u16)f2bf(od[dt][2] * inv);
    o4.w = (u16)f2bf(od[dt][3] * inv);
    *reinterpret_cast<ushort4*>(
        &ob[((size_t)(b * T_) + tq) * D_ + h * 64 + dt * 16 + lg * 4]) = o4;
  }
}

extern "C" void kernel_launch(void* const* d_in, const int* in_sizes, int n_in,
                              void* d_out, int out_size, void* d_ws, size_t ws_size,
                              hipStream_t stream) {
  (void)in_sizes; (void)n_in; (void)out_size;
  const int* tokens = (const int*)d_in[0];
  const int* mem_ids = (const int*)d_in[1];
  const float* mem_emb = (const float*)d_in[2];
  const float* ssum = (const float*)d_in[3];
  const float* embed = (const float*)d_in[4];
  const float* engram_t = (const float*)d_in[5];
  const float* engram_g = (const float*)d_in[6];
  const float* engram_s = (const float*)d_in[7];
  const float* mem_W = (const float*)d_in[8];
  const float* mem_b = (const float*)d_in[9];
  const float* mem_s = (const float*)d_in[10];
  const float* alpha_g = (const float*)d_in[11];
  const float* ssum_W = (const float*)d_in[12];
  const float* ln1 = (const float*)d_in[13];
  const float* qW = (const float*)d_in[14];
  const float* qbias = (const float*)d_in[15];
  const float* kW = (const float*)d_in[16];
  const float* kbias = (const float*)d_in[17];
  const float* vW = (const float*)d_in[18];
  const float* vbias = (const float*)d_in[19];
  const float* oW = (const float*)d_in[20];
  const float* obias = (const float*)d_in[21];
  const float* ln2 = (const float*)d_in[22];
  const float* w_in = (const float*)d_in[23];
  const float* w_out = (const float*)d_in[24];
  const float* final_s = (const float*)d_in[25];

  const size_t KVSZ = (size_t)B_ * TK_ * D_;
  size_t need = (KVSZ * 2 * 2 * L_) + 120u * 1024 * 1024;
  bool batched = ws_size >= need;

  char* p = (char*)d_ws;
  auto alloc = [&](size_t bytes) { char* r = p; p += (bytes + 255) & ~(size_t)255; return r; };
  u16* kv_b   = (u16*)alloc(KVSZ * 2);
  float* cx   = (float*)alloc((size_t)B_ * T_ * D_ * 4);
  u16* nx_b   = (u16*)alloc((size_t)B_ * T_ * D_ * 2);   // also ob (attn out)
  u16* qb_b   = (u16*)alloc((size_t)B_ * T_ * D_ * 2);   // also mem_tmp f32
  int nkv = batched ? L_ : 1;
  u16* kb_all = (u16*)alloc(KVSZ * 2 * nkv);
  u16* vb_all = (u16*)alloc(KVSZ * 2 * nkv);
  u16* hb;
  if (batched) hb = (u16*)alloc((size_t)B_ * T_ * 2048 * 2);
  else hb = kb_all;  // spans kb+vb
  u16* wqkvoT = (u16*)alloc((size_t)L_ * 4 * D_ * D_ * 2);
  u16* wiT    = (u16*)alloc((size_t)L_ * 4096 * 512 * 2);
  u16* woutT  = (u16*)alloc((size_t)L_ * 512 * 2048 * 2);
  float* ssp  = (float*)alloc((size_t)B_ * D_ * 4);
  float* rc   = (float*)alloc((size_t)TK_ * 32 * 4);
  float* rs   = (float*)alloc((size_t)TK_ * 32 * 4);
  float* mem_tmp = (float*)qb_b;
  u16* ob_b = nx_b;

  // preamble + batched weight conversion
  rope_table_k<<<TK_ * 32 / 64, 64, 0, stream>>>(rc, rs);
  wconv_qkvo_k<<<dim3(8, 8, L_ * 4), 256, 0, stream>>>(qW, kW, vW, oW, wqkvoT);
  wconv_win_k<<<dim3(64, 8, L_), 256, 0, stream>>>(w_in, wiT);
  wconv_wout_k<<<dim3(8, 32, L_), 256, 0, stream>>>(w_out, woutT);
  ssum_proj_k<<<dim3(2, B_), 256, 0, stream>>>(ssum, ssum_W, ssp);
  sgemm_k<<<dim3(8, 8), 256, 0, stream>>>(mem_emb, mem_W, mem_b, mem_tmp, B_ * O_, D_, D_);
  memnorm_k<<<dim3(O_, B_), 128, 0, stream>>>(mem_tmp, mem_s, kv_b);
  engram_k<<<dim3(T_, B_), 128, 0, stream>>>(tokens, mem_ids, engram_t, engram_g, engram_s, kv_b);
  embed_k<<<dim3(T_, B_), 128, 0, stream>>>(tokens, embed, ssp, alpha_g, cx, kv_b);

  if (batched) {
    kv_gemm_k<<<dim3(8, 68, L_), 256, 0, stream>>>(kv_b, wqkvoT, kbias, vbias,
                                                   kb_all, vb_all, rc, rs, 0, KVSZ);
  }

  const size_t WSZ = (size_t)D_ * D_;
  for (int l = 0; l < L_; ++l) {
    const u16* wqT = wqkvoT + ((size_t)l * 4 + 0) * WSZ;
    const u16* woT = wqkvoT + ((size_t)l * 4 + 3) * WSZ;
    const u16* wil = wiT + (size_t)l * 4096 * 512;
    const u16* wol = woutT + (size_t)l * 512 * 2048;
    u16* kb_l = batched ? kb_all + (size_t)l * KVSZ : kb_all;
    u16* vb_l = batched ? vb_all + (size_t)l * KVSZ : vb_all;

    rmsnorm_k<1><<<B_ * T_, 128, 0, stream>>>(cx, ln1 + l * D_, nx_b);
    gemm_sm_k<1><<<dim3(8, 64), 256, 0, stream>>>(nx_b, wqT, qbias + l * D_, qb_b,
                                                  B_ * T_, D_, D_, T_, rc, rs);
    if (!batched) {
      kv_gemm_k<<<dim3(8, 68, 1), 256, 0, stream>>>(kv_b, wqkvoT, kbias, vbias,
                                                    kb_l, vb_l, rc, rs, l, 0);
    }
    attn_mfma_k<<<dim3(256), 512, 0, stream>>>(qb_b, kb_l, vb_l, tokens, ob_b);
    gemm_sm_k<2><<<dim3(8, 64), 256, 0, stream>>>(ob_b, woT, obias + l * D_, cx,
                                                  B_ * T_, D_, D_, 0, nullptr, nullptr);
    rmsnorm_k<1><<<B_ * T_, 128, 0, stream>>>(cx, ln2 + l * D_, nx_b);
    mlp_in_mfma_k<<<dim3(32, 32), 256, 0, stream>>>(nx_b, wil, hb);
    gemm_sm_k<2><<<dim3(8, 64), 256, 0, stream>>>(hb, wol, nullptr, cx,
                                                  B_ * T_, D_, 2048, 0, nullptr, nullptr);
  }
  rmsnorm_k<0><<<B_ * T_, 128, 0, stream>>>(cx, final_s, d_out);
}

// Round 9
// 1052.359 us; speedup vs baseline: 12.5401x; 1.0338x over previous
//
#include <hip/hip_runtime.h>
#include <hip/hip_bf16.h>
#include <math.h>

#define B_ 4
#define T_ 1024
#define O_ 128
#define D_ 512
#define H_ 8
#define L_ 6
#define TK_ 2176
#define MM_ 100000
#define EH_ 4
#define EHD_ 128
#define HD_ 64

typedef float f32x4 __attribute__((ext_vector_type(4)));
typedef short bf16x8 __attribute__((ext_vector_type(8)));
typedef unsigned short u16;

// PRIMES per reference: base=131, x=base+h*1009; row[i]=x; x=x*31+1 (uint32 wrap)
__device__ __constant__ unsigned int PRIMES_[4][4] = {
  {131u,  4062u,  125923u, 3903614u},
  {1140u, 35341u, 1095572u, 33962733u},
  {2149u, 66620u, 2065221u, 64021852u},
  {3158u, 97899u, 3034870u, 94080971u},
};

__device__ __forceinline__ float wave_sum_f(float v) {
  #pragma unroll
  for (int off = 32; off; off >>= 1) v += __shfl_xor(v, off);
  return v;
}

__device__ __forceinline__ short f2bf(float f) {
  unsigned int u = __float_as_uint(f);
  unsigned int r = (u + 0x7fffu + ((u >> 16) & 1u)) >> 16;
  return (short)r;
}

__device__ __forceinline__ void gload16(const void* g, void* l) {
  __builtin_amdgcn_global_load_lds((const __attribute__((address_space(1))) void*)g,
                                   (__attribute__((address_space(3))) void*)l, 16, 0, 0);
}

// ---------------- rope tables: cos/sin [TK][32] ----------------
__global__ __launch_bounds__(64) void rope_table_k(float* __restrict__ rc,
                                                   float* __restrict__ rs) {
  int i = blockIdx.x * 64 + threadIdx.x;
  int t = i >> 5, j = i & 31;
  float freq = __powf(10000.0f, -(float)j / 32.0f);
  float ang = (float)t * freq;
  rc[i] = cosf(ang);
  rs[i] = sinf(ang);
}

// ---------------- ssum @ ssum_W -> ssp[B][D] ----------------
__global__ __launch_bounds__(256) void ssum_proj_k(const float* __restrict__ ssum,
                                                   const float* __restrict__ sW,
                                                   float* __restrict__ ssp) {
  int col = blockIdx.x * 256 + threadIdx.x;
  int b = blockIdx.y;
  float acc = 0.f;
  for (int d = 0; d < D_; ++d) acc += ssum[b * D_ + d] * sW[(size_t)d * D_ + col];
  ssp[b * D_ + col] = acc;
}

// ---------------- f32 tiled GEMM (preamble mem projection only) ----------------
__global__ __launch_bounds__(256) void sgemm_k(const float* __restrict__ A,
                                               const float* __restrict__ W,
                                               const float* __restrict__ bias,
                                               float* __restrict__ C,
                                               int M, int N, int K) {
  __shared__ float As[16][68];
  __shared__ float Bs[16][68];
  int tid = threadIdx.x;
  int row0 = blockIdx.y * 64;
  int col0 = blockIdx.x * 64;
  int tx = tid & 15, ty = tid >> 4;
  int am = tid >> 2, ak = (tid & 3) * 4;
  int bk = tid >> 4, bc = (tid & 15) * 4;
  float acc[4][4] = {};
  for (int k0 = 0; k0 < K; k0 += 16) {
    float4 av = *reinterpret_cast<const float4*>(&A[(size_t)(row0 + am) * K + k0 + ak]);
    As[ak + 0][am] = av.x; As[ak + 1][am] = av.y; As[ak + 2][am] = av.z; As[ak + 3][am] = av.w;
    float4 bv = *reinterpret_cast<const float4*>(&W[(size_t)(k0 + bk) * N + col0 + bc]);
    *reinterpret_cast<float4*>(&Bs[bk][bc]) = bv;
    __syncthreads();
    #pragma unroll
    for (int kk = 0; kk < 16; ++kk) {
      float4 a4 = *reinterpret_cast<const float4*>(&As[kk][ty * 4]);
      float4 b4 = *reinterpret_cast<const float4*>(&Bs[kk][tx * 4]);
      float a[4] = {a4.x, a4.y, a4.z, a4.w};
      float b[4] = {b4.x, b4.y, b4.z, b4.w};
      #pragma unroll
      for (int i = 0; i < 4; ++i)
        #pragma unroll
        for (int j = 0; j < 4; ++j) acc[i][j] += a[i] * b[j];
    }
    __syncthreads();
  }
  int cbase = col0 + tx * 4;
  float4 b4 = *reinterpret_cast<const float4*>(&bias[cbase]);
  float bb[4] = {b4.x, b4.y, b4.z, b4.w};
  #pragma unroll
  for (int i = 0; i < 4; ++i) {
    int row = row0 + ty * 4 + i;
    *reinterpret_cast<float4*>(&C[(size_t)row * N + cbase]) =
        make_float4(acc[i][0] + bb[0], acc[i][1] + bb[1], acc[i][2] + bb[2], acc[i][3] + bb[3]);
  }
}

// ---------------- batched weight convert+transpose: f32 [K][N] -> bf16 [N][K] ----------------
__device__ __forceinline__ void wconv_tile(const float* __restrict__ W, u16* __restrict__ wT,
                                           int K, int N) {
  __shared__ float s[64][65];
  int n0 = blockIdx.x * 64, k0 = blockIdx.y * 64;
  int tid = threadIdx.x;
  int kr = tid >> 4, nc = (tid & 15) * 4;
  #pragma unroll
  for (int kk = 0; kk < 4; ++kk) {
    float4 f = *reinterpret_cast<const float4*>(&W[(size_t)(k0 + kr + kk * 16) * N + n0 + nc]);
    s[kr + kk * 16][nc + 0] = f.x; s[kr + kk * 16][nc + 1] = f.y;
    s[kr + kk * 16][nc + 2] = f.z; s[kr + kk * 16][nc + 3] = f.w;
  }
  __syncthreads();
  int nr = tid >> 4, kc = (tid & 15) * 4;
  #pragma unroll
  for (int nn = 0; nn < 4; ++nn) {
    int n = nr + nn * 16;
    ushort4 o;
    o.x = (u16)f2bf(s[kc + 0][n]); o.y = (u16)f2bf(s[kc + 1][n]);
    o.z = (u16)f2bf(s[kc + 2][n]); o.w = (u16)f2bf(s[kc + 3][n]);
    *reinterpret_cast<ushort4*>(&wT[(size_t)(n0 + n) * K + k0 + kc]) = o;
  }
}

__global__ __launch_bounds__(256) void wconv_qkvo_k(const float* __restrict__ qW,
                                                    const float* __restrict__ kW,
                                                    const float* __restrict__ vW,
                                                    const float* __restrict__ oW,
                                                    u16* __restrict__ dst) {
  int z = blockIdx.z;
  int l = z >> 2, which = z & 3;
  const float* src = which == 0 ? qW : which == 1 ? kW : which == 2 ? vW : oW;
  wconv_tile(src + (size_t)l * D_ * D_, dst + (size_t)z * D_ * D_, D_, D_);
}

__global__ __launch_bounds__(256) void wconv_win_k(const float* __restrict__ w_in,
                                                   u16* __restrict__ dst) {
  int l = blockIdx.z;
  wconv_tile(w_in + (size_t)l * 512 * 4096, dst + (size_t)l * 4096 * 512, 512, 4096);
}

__global__ __launch_bounds__(256) void wconv_wout_k(const float* __restrict__ w_out,
                                                    u16* __restrict__ dst) {
  int l = blockIdx.z;
  wconv_tile(w_out + (size_t)l * 2048 * 512, dst + (size_t)l * 512 * 2048, 2048, 512);
}

// ---------------- small MFMA GEMM: 64x64 tile, 4 waves (wave 32x32) ----------------
template<int EPI>
__global__ __launch_bounds__(256) void gemm_sm_k(const u16* __restrict__ A,
                                                 const u16* __restrict__ Bt,
                                                 const float* __restrict__ bias,
                                                 void* __restrict__ Cout,
                                                 int M, int N, int K, int posmod,
                                                 const float* __restrict__ rc,
                                                 const float* __restrict__ rs) {
  __shared__ __align__(16) u16 As[2][64 * 32];
  __shared__ __align__(16) u16 Bs[2][64 * 32];
  int tid = threadIdx.x;
  int w = tid >> 6, lane = tid & 63;
  int lr = lane & 15, lg = lane >> 4;
  int row0 = blockIdx.y * 64, col0 = blockIdx.x * 64;
  int wr = w >> 1, wc = w & 1;
  f32x4 acc[2][2] = {};

  int srow = tid >> 2;
  int skel = (tid & 3) * 8;

  auto stage = [&](int buf, int k0) {
    gload16(A + (size_t)(row0 + srow) * K + k0 + skel, &As[buf][srow * 32 + skel]);
    gload16(Bt + (size_t)(col0 + srow) * K + k0 + skel, &Bs[buf][srow * 32 + skel]);
  };

  stage(0, 0);
  __syncthreads();
  int nk = K >> 5;
  int buf = 0;
  for (int t = 0; t < nk; ++t) {
    if (t + 1 < nk) stage(buf ^ 1, (t + 1) * 32);
    bf16x8 af[2], bf[2];
    #pragma unroll
    for (int i = 0; i < 2; ++i)
      af[i] = *reinterpret_cast<const bf16x8*>(&As[buf][(wr * 32 + i * 16 + lr) * 32 + lg * 8]);
    #pragma unroll
    for (int j = 0; j < 2; ++j)
      bf[j] = *reinterpret_cast<const bf16x8*>(&Bs[buf][(wc * 32 + j * 16 + lr) * 32 + lg * 8]);
    #pragma unroll
    for (int i = 0; i < 2; ++i)
      #pragma unroll
      for (int j = 0; j < 2; ++j)
        acc[i][j] = __builtin_amdgcn_mfma_f32_16x16x32_bf16(af[i], bf[j], acc[i][j], 0, 0, 0);
    __syncthreads();
    buf ^= 1;
  }

  #pragma unroll
  for (int j = 0; j < 2; ++j) {
    int col = col0 + wc * 32 + j * 16 + lr;
    float bs = bias ? bias[col] : 0.f;
    #pragma unroll
    for (int i = 0; i < 2; ++i) {
      #pragma unroll
      for (int r = 0; r < 4; ++r) {
        int row = row0 + wr * 32 + i * 16 + lg * 4 + r;
        float v = acc[i][j][r] + bs;
        if (EPI == 1) {
          int pos = row % posmod;
          int d = col & 63;
          float c = rc[(size_t)pos * 32 + (d >> 1)];
          float s = rs[(size_t)pos * 32 + (d >> 1)];
          float partner = __shfl_xor(v, 1);
          v = (d & 1) ? (partner * s + v * c) : (v * c - partner * s);
        }
        if (EPI == 2) {
          float* Cf = (float*)Cout;
          Cf[(size_t)row * N + col] += v;
        } else {
          u16* Cb = (u16*)Cout;
          Cb[(size_t)row * N + col] = (u16)f2bf(v);
        }
      }
    }
  }
}

// ---------------- fused K+V projection, XCD-pinned grid ----------------
// 1D grid: bid = c + 8*(x + 8*(yh + 9*z)); y = yh*8 + c. bid%8 = y%8 pins all
// col-blocks + all layers of row-stripe y to one XCD -> A stays L2-resident.
__global__ __launch_bounds__(256) void kv_gemm_k(const u16* __restrict__ A,
                                                 const u16* __restrict__ wqkvoT,
                                                 const float* __restrict__ kbias_all,
                                                 const float* __restrict__ vbias_all,
                                                 u16* __restrict__ kb_base,
                                                 u16* __restrict__ vb_base,
                                                 const float* __restrict__ rc,
                                                 const float* __restrict__ rs,
                                                 int l0, size_t ostride) {
  __shared__ __align__(16) u16 As[2][128 * 32];
  __shared__ __align__(16) u16 Bk[2][64 * 32];
  __shared__ __align__(16) u16 Bv[2][64 * 32];
  const int K = 512, N = 512;
  int bid = blockIdx.x;
  int c_ = bid & 7;
  int x_ = (bid >> 3) & 7;
  int rest = bid >> 6;
  int yh = rest % 9;
  int z = rest / 9;
  int y_ = yh * 8 + c_;
  if (y_ >= 68) return;
  int l = l0 + z;
  const u16* wkT = wqkvoT + ((size_t)l * 4 + 1) * (D_ * D_);
  const u16* wvT = wqkvoT + ((size_t)l * 4 + 2) * (D_ * D_);
  const float* kbias = kbias_all + l * D_;
  const float* vbias = vbias_all + l * D_;
  u16* kb = kb_base + (size_t)z * ostride;
  u16* vb = vb_base + (size_t)z * ostride;
  int tid = threadIdx.x;
  int w = tid >> 6, lane = tid & 63;
  int lr = lane & 15, lg = lane >> 4;
  int row0 = y_ * 128, col0 = x_ * 64;
  int wr = w >> 1, wc = w & 1;
  f32x4 ak_[4][2] = {};
  f32x4 av_[4][2] = {};

  int srow = lane >> 2;
  int skel = (lane & 3) * 8;

  auto stage = [&](int buf, int k0) {
    #pragma unroll
    for (int ci = 0; ci < 2; ++ci) {
      int c = w * 2 + ci;
      gload16(A + (size_t)(row0 + c * 16 + srow) * K + k0 + skel, &As[buf][c * 512]);
    }
    gload16(wkT + (size_t)(col0 + w * 16 + srow) * K + k0 + skel, &Bk[buf][w * 512]);
    gload16(wvT + (size_t)(col0 + w * 16 + srow) * K + k0 + skel, &Bv[buf][w * 512]);
  };

  stage(0, 0);
  __syncthreads();
  int buf = 0;
  for (int t = 0; t < 16; ++t) {
    if (t + 1 < 16) stage(buf ^ 1, (t + 1) * 32);
    bf16x8 af[4], bk[2], bv[2];
    #pragma unroll
    for (int i = 0; i < 4; ++i)
      af[i] = *reinterpret_cast<const bf16x8*>(&As[buf][(wr * 64 + i * 16 + lr) * 32 + lg * 8]);
    #pragma unroll
    for (int j = 0; j < 2; ++j) {
      bk[j] = *reinterpret_cast<const bf16x8*>(&Bk[buf][(wc * 32 + j * 16 + lr) * 32 + lg * 8]);
      bv[j] = *reinterpret_cast<const bf16x8*>(&Bv[buf][(wc * 32 + j * 16 + lr) * 32 + lg * 8]);
    }
    #pragma unroll
    for (int i = 0; i < 4; ++i)
      #pragma unroll
      for (int j = 0; j < 2; ++j) {
        ak_[i][j] = __builtin_amdgcn_mfma_f32_16x16x32_bf16(af[i], bk[j], ak_[i][j], 0, 0, 0);
        av_[i][j] = __builtin_amdgcn_mfma_f32_16x16x32_bf16(af[i], bv[j], av_[i][j], 0, 0, 0);
      }
    __syncthreads();
    buf ^= 1;
  }

  #pragma unroll
  for (int j = 0; j < 2; ++j) {
    int col = col0 + wc * 32 + j * 16 + lr;
    float kbs = kbias[col], vbs = vbias[col];
    int d = col & 63;
    #pragma unroll
    for (int i = 0; i < 4; ++i) {
      #pragma unroll
      for (int r = 0; r < 4; ++r) {
        int row = row0 + wr * 64 + i * 16 + lg * 4 + r;
        int pos = row % TK_;
        float vk = ak_[i][j][r] + kbs;
        float c = rc[(size_t)pos * 32 + (d >> 1)];
        float s = rs[(size_t)pos * 32 + (d >> 1)];
        float partner = __shfl_xor(vk, 1);
        vk = (d & 1) ? (partner * s + vk * c) : (vk * c - partner * s);
        kb[(size_t)row * N + col] = (u16)f2bf(vk);
        vb[(size_t)row * N + col] = (u16)f2bf(av_[i][j][r] + vbs);
      }
    }
  }
}

// ---------------- fused MLP-in MFMA ----------------
__global__ __launch_bounds__(256) void mlp_in_mfma_k(const u16* __restrict__ A,
                                                     const u16* __restrict__ wiT,
                                                     u16* __restrict__ Hout) {
  __shared__ __align__(16) u16 As[2][128 * 32];
  __shared__ __align__(16) u16 Bg[2][64 * 32];
  __shared__ __align__(16) u16 Bv[2][64 * 32];
  int tid = threadIdx.x;
  int w = tid >> 6, lane = tid & 63;
  int lr = lane & 15, lg = lane >> 4;
  int hc0 = blockIdx.x * 64, row0 = blockIdx.y * 128;
  int wr = w >> 1, wc = w & 1;
  f32x4 ag[4][2] = {};
  f32x4 av[4][2] = {};
  const int K = 512;

  int srow = lane >> 2;
  int skel = (lane & 3) * 8;

  auto stage = [&](int buf, int k0) {
    #pragma unroll
    for (int ci = 0; ci < 2; ++ci) {
      int c = w * 2 + ci;
      gload16(A + (size_t)(row0 + c * 16 + srow) * K + k0 + skel, &As[buf][c * 512]);
    }
    gload16(wiT + (size_t)(hc0 + w * 16 + srow) * K + k0 + skel, &Bg[buf][w * 512]);
    gload16(wiT + (size_t)(2048 + hc0 + w * 16 + srow) * K + k0 + skel, &Bv[buf][w * 512]);
  };

  stage(0, 0);
  __syncthreads();
  int buf = 0;
  for (int t = 0; t < 16; ++t) {
    if (t + 1 < 16) stage(buf ^ 1, (t + 1) * 32);
    bf16x8 af[4], bg[2], bv[2];
    #pragma unroll
    for (int i = 0; i < 4; ++i)
      af[i] = *reinterpret_cast<const bf16x8*>(&As[buf][(wr * 64 + i * 16 + lr) * 32 + lg * 8]);
    #pragma unroll
    for (int j = 0; j < 2; ++j) {
      bg[j] = *reinterpret_cast<const bf16x8*>(&Bg[buf][(wc * 32 + j * 16 + lr) * 32 + lg * 8]);
      bv[j] = *reinterpret_cast<const bf16x8*>(&Bv[buf][(wc * 32 + j * 16 + lr) * 32 + lg * 8]);
    }
    #pragma unroll
    for (int i = 0; i < 4; ++i)
      #pragma unroll
      for (int j = 0; j < 2; ++j) {
        ag[i][j] = __builtin_amdgcn_mfma_f32_16x16x32_bf16(af[i], bg[j], ag[i][j], 0, 0, 0);
        av[i][j] = __builtin_amdgcn_mfma_f32_16x16x32_bf16(af[i], bv[j], av[i][j], 0, 0, 0);
      }
    __syncthreads();
    buf ^= 1;
  }

  #pragma unroll
  for (int j = 0; j < 2; ++j) {
    int col = hc0 + wc * 32 + j * 16 + lr;
    #pragma unroll
    for (int i = 0; i < 4; ++i) {
      #pragma unroll
      for (int r = 0; r < 4; ++r) {
        int row = row0 + wr * 64 + i * 16 + lg * 4 + r;
        float g = ag[i][j][r];
        float sg = g / (1.f + __expf(-g));
        Hout[(size_t)row * 2048 + col] = (u16)f2bf(sg * av[i][j][r]);
      }
    }
  }
}

// ---------------- rmsnorm rows ----------------
template<int OUTBF>
__global__ __launch_bounds__(128) void rmsnorm_k(const float* __restrict__ in,
                                                 const float* __restrict__ scale,
                                                 void* __restrict__ out) {
  int row = blockIdx.x;
  int tid = threadIdx.x;
  float4 v = *reinterpret_cast<const float4*>(&in[(size_t)row * D_ + tid * 4]);
  float ss = v.x * v.x + v.y * v.y + v.z * v.z + v.w * v.w;
  ss = wave_sum_f(ss);
  __shared__ float red[2];
  if ((tid & 63) == 0) red[tid >> 6] = ss;
  __syncthreads();
  ss = red[0] + red[1];
  float inv = 1.0f / sqrtf(ss / (float)D_ + 1e-6f);
  float4 sc = *reinterpret_cast<const float4*>(&scale[tid * 4]);
  float o0 = v.x * inv * sc.x, o1 = v.y * inv * sc.y, o2 = v.z * inv * sc.z, o3 = v.w * inv * sc.w;
  if (OUTBF) {
    ushort4 o;
    o.x = (u16)f2bf(o0); o.y = (u16)f2bf(o1); o.z = (u16)f2bf(o2); o.w = (u16)f2bf(o3);
    *reinterpret_cast<ushort4*>((u16*)out + (size_t)row * D_ + tid * 4) = o;
  } else {
    *reinterpret_cast<float4*>((float*)out + (size_t)row * D_ + tid * 4) =
        make_float4(o0, o1, o2, o3);
  }
}

// ---------------- mem rows ----------------
__global__ __launch_bounds__(128) void memnorm_k(const float* __restrict__ tmp,
                                                 const float* __restrict__ scale,
                                                 u16* __restrict__ kv) {
  int o = blockIdx.x, b = blockIdx.y;
  int tid = threadIdx.x;
  float4 v = *reinterpret_cast<const float4*>(&tmp[(size_t)(b * O_ + o) * D_ + tid * 4]);
  float ss = v.x * v.x + v.y * v.y + v.z * v.z + v.w * v.w;
  ss = wave_sum_f(ss);
  __shared__ float red[2];
  if ((tid & 63) == 0) red[tid >> 6] = ss;
  __syncthreads();
  ss = red[0] + red[1];
  float inv = 1.0f / sqrtf(ss / (float)D_ + 1e-6f);
  float4 sc = *reinterpret_cast<const float4*>(&scale[tid * 4]);
  ushort4 oo;
  oo.x = (u16)f2bf(v.x * inv * sc.x); oo.y = (u16)f2bf(v.y * inv * sc.y);
  oo.z = (u16)f2bf(v.z * inv * sc.z); oo.w = (u16)f2bf(v.w * inv * sc.w);
  *reinterpret_cast<ushort4*>(&kv[(size_t)(b * TK_ + o) * D_ + tid * 4]) = oo;
}

// ---------------- engram rows ----------------
__global__ __launch_bounds__(128) void engram_k(const int* __restrict__ tokens,
                                                const int* __restrict__ mem_ids,
                                                const float* __restrict__ etab,
                                                const float* __restrict__ egate,
                                                const float* __restrict__ escale,
                                                u16* __restrict__ kv) {
  int t = blockIdx.x, b = blockIdx.y;
  int tid = threadIdx.x;
  unsigned int toks[4];
  #pragma unroll
  for (int i = 0; i < 4; ++i) {
    int idx = t - i;
    toks[i] = (idx >= 0) ? (unsigned int)tokens[b * T_ + idx]
                         : (unsigned int)mem_ids[b * O_ + O_ + idx];
  }
  int c = tid * 4;
  int h = c >> 7;
  int e = c & 127;
  unsigned int hs = 0;
  #pragma unroll
  for (int i = 0; i < 4; ++i) hs += toks[i] * PRIMES_[h][i];
  int idxh = (int)(hs % (unsigned int)MM_);
  float4 r = *reinterpret_cast<const float4*>(&etab[((size_t)idxh * EH_ + h) * EHD_ + e]);
  float4 g = *reinterpret_cast<const float4*>(&egate[h * EHD_ + e]);
  float4 val;
  val.x = r.x / (1.f + __expf(-g.x));
  val.y = r.y / (1.f + __expf(-g.y));
  val.z = r.z / (1.f + __expf(-g.z));
  val.w = r.w / (1.f + __expf(-g.w));
  float ss = val.x * val.x + val.y * val.y + val.z * val.z + val.w * val.w;
  ss = wave_sum_f(ss);
  __shared__ float red[2];
  if ((tid & 63) == 0) red[tid >> 6] = ss;
  __syncthreads();
  ss = red[0] + red[1];
  float inv = 1.0f / sqrtf(ss / (float)D_ + 1e-6f);
  float4 sc = *reinterpret_cast<const float4*>(&escale[c]);
  ushort4 oo;
  oo.x = (u16)f2bf(val.x * inv * sc.x); oo.y = (u16)f2bf(val.y * inv * sc.y);
  oo.z = (u16)f2bf(val.z * inv * sc.z); oo.w = (u16)f2bf(val.w * inv * sc.w);
  *reinterpret_cast<ushort4*>(&kv[(size_t)(b * TK_ + O_ + t) * D_ + c]) = oo;
}

// ---------------- embed + ssum inject ----------------
__global__ __launch_bounds__(128) void embed_k(const int* __restrict__ tokens,
                                               const float* __restrict__ etab,
                                               const float* __restrict__ ssp,
                                               const float* __restrict__ alpha_g,
                                               float* __restrict__ cx,
                                               u16* __restrict__ kv) {
  int t = blockIdx.x, b = blockIdx.y;
  int tid = threadIdx.x;
  int c = tid * 4;
  int tok = tokens[b * T_ + t];
  float4 e = *reinterpret_cast<const float4*>(&etab[(size_t)tok * D_ + c]);
  float4 sp = *reinterpret_cast<const float4*>(&ssp[b * D_ + c]);
  float4 ag = *reinterpret_cast<const float4*>(&alpha_g[c]);
  float4 x;
  x.x = e.x + sp.x / (1.f + __expf(-ag.x));
  x.y = e.y + sp.y / (1.f + __expf(-ag.y));
  x.z = e.z + sp.z / (1.f + __expf(-ag.z));
  x.w = e.w + sp.w / (1.f + __expf(-ag.w));
  *reinterpret_cast<float4*>(&cx[(size_t)(b * T_ + t) * D_ + c]) = x;
  ushort4 oo;
  oo.x = (u16)f2bf(x.x); oo.y = (u16)f2bf(x.y);
  oo.z = (u16)f2bf(x.z); oo.w = (u16)f2bf(x.w);
  *reinterpret_cast<ushort4*>(&kv[(size_t)(b * TK_ + O_ + T_ + t) * D_ + c]) = oo;
}

// ---------------- MFMA flash attention v5: paired q-tiles + 2-deep reg prefetch ----------------
#define KIDX8(r, c) (((r) << 6) + ((c) ^ (((r) & 7) << 3)))
#define KIDX4(r, c) (((r) << 6) + ((c) ^ (((r) & 15) << 2)))
#define PIDX(q, o) (((q) << 5) + ((o) ^ (((q) & 7) << 2)))

__global__ __launch_bounds__(512) void attn_mfma_k(const u16* __restrict__ qb,
                                                   const u16* __restrict__ kb,
                                                   const u16* __restrict__ vb,
                                                   const int* __restrict__ tokens,
                                                   u16* __restrict__ ob) {
  __shared__ __align__(16) short ks[2][64 * 64];
  __shared__ __align__(16) short vst[2][64 * 64];        // transposed: [d][k]
  __shared__ __align__(16) unsigned int pbuf[8][16 * 32]; // per-wave P^T packed pairs
  __shared__ unsigned char vtok[T_];

  int fid = blockIdx.x;       // 256 blocks
  int h = fid & 7;
  int s = fid >> 3;           // 0..31
  int pair = s & 7;           // bxA = pair, bxB = 15 - pair
  int b = s >> 3;             // 0..3
  int bxA = pair, bxB = 15 - pair;

  int tid = threadIdx.x;
  int w = tid >> 6, lane = tid & 63;
  int lr = lane & 15;
  int lg = lane >> 4;
  int myBx = (w < 4) ? bxA : bxB;
  int qw0 = myBx * 64 + (w & 3) * 16;
  int tq = qw0 + lr;  // this lane's query row

  for (int i = tid; i < T_; i += 512) vtok[i] = (tokens[b * T_ + i] != 0);

  bf16x8 aq[2];  // Q for this lane's q row: B-operand (col=lr, d=lg*8..)
  {
    const u16* qp = &qb[((size_t)(b * T_) + tq) * D_ + h * 64];
    aq[0] = *reinterpret_cast<const bf16x8*>(qp + lg * 8);
    aq[1] = *reinterpret_cast<const bf16x8*>(qp + 32 + lg * 8);
  }

  float m_ = -1e30f, lsum = 0.f;
  f32x4 od[4];
  #pragma unroll
  for (int dt = 0; dt < 4; ++dt) od[dt] = (f32x4){0.f, 0.f, 0.f, 0.f};

  int sr = tid >> 3;
  int sc = (tid & 7) * 8;
  int vr2 = (tid >> 4) * 2;
  int vc = (tid & 15) * 4;

  int nt = 2 + 2 * (bxB + 1);   // always even
  auto tile_pos = [&](int i, int& pos0, int& base, bool& masked, bool& part) {
    if (i < 2) { pos0 = i * 64; base = 0; masked = false; part = true; }
    else if (i < 3 + bxB) {
      int t = i - 2;
      pos0 = O_ + t * 64; base = O_; masked = true; part = (t <= myBx);
    } else {
      int t = i - (3 + bxB);
      pos0 = O_ + T_ + t * 64; base = O_ + T_; masked = true; part = (t <= myBx);
    }
  };

  // two named prefetch register sets (rule #20: no runtime-indexed reg arrays)
  bf16x8 pkA, pkB;
  short4 pv0A, pv1A, pv0B, pv1B;

  auto load_regs = [&](int pos0, bf16x8& pk, short4& v0, short4& v1) {
    const u16* kg = &kb[((size_t)(b * TK_) + pos0 + sr) * D_ + h * 64 + sc];
    pk = *reinterpret_cast<const bf16x8*>(kg);
    const u16* vg = &vb[((size_t)(b * TK_) + pos0 + vr2) * D_ + h * 64 + vc];
    v0 = *reinterpret_cast<const short4*>(vg);
    v1 = *reinterpret_cast<const short4*>(vg + D_);
  };

  auto write_lds = [&](int buf, bf16x8 pk, short4 pv0, short4 pv1) {
    *reinterpret_cast<bf16x8*>(&ks[buf][KIDX8(sr, sc)]) = pk;
    unsigned int t0 = (unsigned int)(u16)pv0.x | ((unsigned int)(u16)pv1.x << 16);
    unsigned int t1 = (unsigned int)(u16)pv0.y | ((unsigned int)(u16)pv1.y << 16);
    unsigned int t2 = (unsigned int)(u16)pv0.z | ((unsigned int)(u16)pv1.z << 16);
    unsigned int t3 = (unsigned int)(u16)pv0.w | ((unsigned int)(u16)pv1.w << 16);
    *reinterpret_cast<unsigned int*>(&vst[buf][KIDX4(vc + 0, vr2)]) = t0;
    *reinterpret_cast<unsigned int*>(&vst[buf][KIDX4(vc + 1, vr2)]) = t1;
    *reinterpret_cast<unsigned int*>(&vst[buf][KIDX4(vc + 2, vr2)]) = t2;
    *reinterpret_cast<unsigned int*>(&vst[buf][KIDX4(vc + 3, vr2)]) = t3;
  };

  unsigned int* pw = (unsigned int*)pbuf[w];

  auto compute = [&](int buf, int pos0, int base, bool masked) {
    float sv[4][4];
    __builtin_amdgcn_s_setprio(1);
    #pragma unroll
    for (int kt = 0; kt < 4; ++kt) {
      bf16x8 ka0 = *reinterpret_cast<const bf16x8*>(&ks[buf][KIDX8(kt * 16 + lr, lg * 8)]);
      bf16x8 ka1 = *reinterpret_cast<const bf16x8*>(&ks[buf][KIDX8(kt * 16 + lr, 32 + lg * 8)]);
      f32x4 sf = (f32x4){0.f, 0.f, 0.f, 0.f};
      sf = __builtin_amdgcn_mfma_f32_16x16x32_bf16(ka0, aq[0], sf, 0, 0, 0);
      sf = __builtin_amdgcn_mfma_f32_16x16x32_bf16(ka1, aq[1], sf, 0, 0, 0);
      #pragma unroll
      for (int r = 0; r < 4; ++r) sv[kt][r] = sf[r];
    }
    __builtin_amdgcn_s_setprio(0);
    if (masked) {
      #pragma unroll
      for (int kt = 0; kt < 4; ++kt) {
        #pragma unroll
        for (int r = 0; r < 4; ++r) {
          int tk = pos0 + kt * 16 + lg * 4 + r - base;
          bool valid = (vtok[tk] != 0) && (tk <= tq);
          sv[kt][r] = valid ? sv[kt][r] * 0.125f : -1e30f;
        }
      }
    } else {
      #pragma unroll
      for (int kt = 0; kt < 4; ++kt)
        #pragma unroll
        for (int r = 0; r < 4; ++r) sv[kt][r] *= 0.125f;
    }
    float pmax = sv[0][0];
    #pragma unroll
    for (int kt = 0; kt < 4; ++kt)
      #pragma unroll
      for (int r = 0; r < 4; ++r) pmax = fmaxf(pmax, sv[kt][r]);
    pmax = fmaxf(pmax, __shfl_xor(pmax, 16));
    pmax = fmaxf(pmax, __shfl_xor(pmax, 32));
    float mnew = fmaxf(m_, pmax);
    float al = __expf(m_ - mnew);
    m_ = mnew;
    float psum = 0.f;
    #pragma unroll
    for (int kt = 0; kt < 4; ++kt)
      #pragma unroll
      for (int r = 0; r < 4; ++r) {
        float pe = __expf(sv[kt][r] - mnew);
        sv[kt][r] = pe;
        psum += pe;
      }
    psum += __shfl_xor(psum, 16);
    psum += __shfl_xor(psum, 32);
    lsum = lsum * al + psum;
    #pragma unroll
    for (int dt = 0; dt < 4; ++dt) {
      f32x4 o = od[dt];
      o[0] *= al; o[1] *= al; o[2] *= al; o[3] *= al;
      od[dt] = o;
    }
    #pragma unroll
    for (int kt = 0; kt < 4; ++kt) {
      uint2 wp;
      asm("v_cvt_pk_bf16_f32 %0, %1, %2" : "=v"(wp.x) : "v"(sv[kt][0]), "v"(sv[kt][1]));
      asm("v_cvt_pk_bf16_f32 %0, %1, %2" : "=v"(wp.y) : "v"(sv[kt][2]), "v"(sv[kt][3]));
      *reinterpret_cast<uint2*>(&pw[PIDX(lr, kt * 8 + lg * 2)]) = wp;
    }
    bf16x8 pf0 = *reinterpret_cast<const bf16x8*>(&pw[PIDX(lr, lg * 4)]);
    bf16x8 pf1 = *reinterpret_cast<const bf16x8*>(&pw[PIDX(lr, 16 + lg * 4)]);
    __builtin_amdgcn_s_setprio(1);
    #pragma unroll
    for (int dt = 0; dt < 4; ++dt) {
      short4 lo0 = *reinterpret_cast<const short4*>(&vst[buf][KIDX4(dt * 16 + lr, lg * 8)]);
      short4 hi0 = *reinterpret_cast<const short4*>(&vst[buf][KIDX4(dt * 16 + lr, lg * 8 + 4)]);
      short4 lo1 = *reinterpret_cast<const short4*>(&vst[buf][KIDX4(dt * 16 + lr, 32 + lg * 8)]);
      short4 hi1 = *reinterpret_cast<const short4*>(&vst[buf][KIDX4(dt * 16 + lr, 36 + lg * 8)]);
      bf16x8 va0 = {lo0.x, lo0.y, lo0.z, lo0.w, hi0.x, hi0.y, hi0.z, hi0.w};
      bf16x8 va1 = {lo1.x, lo1.y, lo1.z, lo1.w, hi1.x, hi1.y, hi1.z, hi1.w};
      od[dt] = __builtin_amdgcn_mfma_f32_16x16x32_bf16(va0, pf0, od[dt], 0, 0, 0);
      od[dt] = __builtin_amdgcn_mfma_f32_16x16x32_bf16(va1, pf1, od[dt], 0, 0, 0);
    }
    __builtin_amdgcn_s_setprio(0);
  };

  // prologue: load tiles 0 and 1 into reg sets A, B (2-deep)
  {
    int pos0, base; bool masked, part;
    tile_pos(0, pos0, base, masked, part);
    load_regs(pos0, pkA, pv0A, pv1A);
    tile_pos(1, pos0, base, masked, part);
    load_regs(pos0, pkB, pv0B, pv1B);
  }
  // main loop unrolled by 2 (nt always even); one barrier per tile.
  // write_lds(i) into buf(i&1) vs compute(i-2) same buf: fenced by iter i-1's barrier.
  for (int i = 0; i < nt; i += 2) {
    // even tile i: set A, buf 0
    write_lds(0, pkA, pv0A, pv1A);
    __syncthreads();
    {
      int pos0, base; bool masked, part;
      tile_pos(i, pos0, base, masked, part);
      if (i + 2 < nt) {
        int npos, nb; bool nm, np;
        tile_pos(i + 2, npos, nb, nm, np);
        load_regs(npos, pkA, pv0A, pv1A);   // 2 tiles ahead
      }
      if (part) compute(0, pos0, base, masked);
    }
    // odd tile i+1: set B, buf 1
    write_lds(1, pkB, pv0B, pv1B);
    __syncthreads();
    {
      int pos0, base; bool masked, part;
      tile_pos(i + 1, pos0, base, masked, part);
      if (i + 3 < nt) {
        int npos, nb; bool nm, np;
        tile_pos(i + 3, npos, nb, nm, np);
        load_regs(npos, pkB, pv0B, pv1B);
      }
      if (part) compute(1, pos0, base, masked);
    }
  }

  float inv = 1.0f / lsum;
  #pragma unroll
  for (int dt = 0; dt < 4; ++dt) {
    ushort4 o4;
    o4.x = (u16)f2bf(od[dt][0] * inv);
    o4.y = (u16)f2bf(od[dt][1] * inv);
    o4.z = (u16)f2bf(od[dt][2] * inv);
    o4.w = (u16)f2bf(od[dt][3] * inv);
    *reinterpret_cast<ushort4*>(
        &ob[((size_t)(b * T_) + tq) * D_ + h * 64 + dt * 16 + lg * 4]) = o4;
  }
}

extern "C" void kernel_launch(void* const* d_in, const int* in_sizes, int n_in,
                              void* d_out, int out_size, void* d_ws, size_t ws_size,
                              hipStream_t stream) {
  (void)in_sizes; (void)n_in; (void)out_size;
  const int* tokens = (const int*)d_in[0];
  const int* mem_ids = (const int*)d_in[1];
  const float* mem_emb = (const float*)d_in[2];
  const float* ssum = (const float*)d_in[3];
  const float* embed = (const float*)d_in[4];
  const float* engram_t = (const float*)d_in[5];
  const float* engram_g = (const float*)d_in[6];
  const float* engram_s = (const float*)d_in[7];
  const float* mem_W = (const float*)d_in[8];
  const float* mem_b = (const float*)d_in[9];
  const float* mem_s = (const float*)d_in[10];
  const float* alpha_g = (const float*)d_in[11];
  const float* ssum_W = (const float*)d_in[12];
  const float* ln1 = (const float*)d_in[13];
  const float* qW = (const float*)d_in[14];
  const float* qbias = (const float*)d_in[15];
  const float* kW = (const float*)d_in[16];
  const float* kbias = (const float*)d_in[17];
  const float* vW = (const float*)d_in[18];
  const float* vbias = (const float*)d_in[19];
  const float* oW = (const float*)d_in[20];
  const float* obias = (const float*)d_in[21];
  const float* ln2 = (const float*)d_in[22];
  const float* w_in = (const float*)d_in[23];
  const float* w_out = (const float*)d_in[24];
  const float* final_s = (const float*)d_in[25];

  const size_t KVSZ = (size_t)B_ * TK_ * D_;
  size_t need = (KVSZ * 2 * 2 * L_) + 120u * 1024 * 1024;
  bool batched = ws_size >= need;

  char* p = (char*)d_ws;
  auto alloc = [&](size_t bytes) { char* r = p; p += (bytes + 255) & ~(size_t)255; return r; };
  u16* kv_b   = (u16*)alloc(KVSZ * 2);
  float* cx   = (float*)alloc((size_t)B_ * T_ * D_ * 4);
  u16* nx_b   = (u16*)alloc((size_t)B_ * T_ * D_ * 2);   // also ob (attn out)
  u16* qb_b   = (u16*)alloc((size_t)B_ * T_ * D_ * 2);   // also mem_tmp f32
  int nkv = batched ? L_ : 1;
  u16* kb_all = (u16*)alloc(KVSZ * 2 * nkv);
  u16* vb_all = (u16*)alloc(KVSZ * 2 * nkv);
  u16* hb;
  if (batched) hb = (u16*)alloc((size_t)B_ * T_ * 2048 * 2);
  else hb = kb_all;  // spans kb+vb
  u16* wqkvoT = (u16*)alloc((size_t)L_ * 4 * D_ * D_ * 2);
  u16* wiT    = (u16*)alloc((size_t)L_ * 4096 * 512 * 2);
  u16* woutT  = (u16*)alloc((size_t)L_ * 512 * 2048 * 2);
  float* ssp  = (float*)alloc((size_t)B_ * D_ * 4);
  float* rc   = (float*)alloc((size_t)TK_ * 32 * 4);
  float* rs   = (float*)alloc((size_t)TK_ * 32 * 4);
  float* mem_tmp = (float*)qb_b;
  u16* ob_b = nx_b;

  // preamble + batched weight conversion
  rope_table_k<<<TK_ * 32 / 64, 64, 0, stream>>>(rc, rs);
  wconv_qkvo_k<<<dim3(8, 8, L_ * 4), 256, 0, stream>>>(qW, kW, vW, oW, wqkvoT);
  wconv_win_k<<<dim3(64, 8, L_), 256, 0, stream>>>(w_in, wiT);
  wconv_wout_k<<<dim3(8, 32, L_), 256, 0, stream>>>(w_out, woutT);
  ssum_proj_k<<<dim3(2, B_), 256, 0, stream>>>(ssum, ssum_W, ssp);
  sgemm_k<<<dim3(8, 8), 256, 0, stream>>>(mem_emb, mem_W, mem_b, mem_tmp, B_ * O_, D_, D_);
  memnorm_k<<<dim3(O_, B_), 128, 0, stream>>>(mem_tmp, mem_s, kv_b);
  engram_k<<<dim3(T_, B_), 128, 0, stream>>>(tokens, mem_ids, engram_t, engram_g, engram_s, kv_b);
  embed_k<<<dim3(T_, B_), 128, 0, stream>>>(tokens, embed, ssp, alpha_g, cx, kv_b);

  if (batched) {
    // all 6 layers' K/V in one XCD-pinned dispatch: 8*8*9*L blocks
    kv_gemm_k<<<dim3(8 * 8 * 9 * L_), 256, 0, stream>>>(kv_b, wqkvoT, kbias, vbias,
                                                        kb_all, vb_all, rc, rs, 0, KVSZ);
  }

  const size_t WSZ = (size_t)D_ * D_;
  for (int l = 0; l < L_; ++l) {
    const u16* wqT = wqkvoT + ((size_t)l * 4 + 0) * WSZ;
    const u16* woT = wqkvoT + ((size_t)l * 4 + 3) * WSZ;
    const u16* wil = wiT + (size_t)l * 4096 * 512;
    const u16* wol = woutT + (size_t)l * 512 * 2048;
    u16* kb_l = batched ? kb_all + (size_t)l * KVSZ : kb_all;
    u16* vb_l = batched ? vb_all + (size_t)l * KVSZ : vb_all;

    rmsnorm_k<1><<<B_ * T_, 128, 0, stream>>>(cx, ln1 + l * D_, nx_b);
    gemm_sm_k<1><<<dim3(8, 64), 256, 0, stream>>>(nx_b, wqT, qbias + l * D_, qb_b,
                                                  B_ * T_, D_, D_, T_, rc, rs);
    if (!batched) {
      kv_gemm_k<<<dim3(8 * 8 * 9), 256, 0, stream>>>(kv_b, wqkvoT, kbias, vbias,
                                                     kb_l, vb_l, rc, rs, l, 0);
    }
    attn_mfma_k<<<dim3(256), 512, 0, stream>>>(qb_b, kb_l, vb_l, tokens, ob_b);
    gemm_sm_k<2><<<dim3(8, 64), 256, 0, stream>>>(ob_b, woT, obias + l * D_, cx,
                                                  B_ * T_, D_, D_, 0, nullptr, nullptr);
    rmsnorm_k<1><<<B_ * T_, 128, 0, stream>>>(cx, ln2 + l * D_, nx_b);
    mlp_in_mfma_k<<<dim3(32, 32), 256, 0, stream>>>(nx_b, wil, hb);
    gemm_sm_k<2><<<dim3(8, 64), 256, 0, stream>>>(hb, wol, nullptr, cx,
                                                  B_ * T_, D_, 2048, 0, nullptr, nullptr);
  }
  rmsnorm_k<0><<<B_ * T_, 128, 0, stream>>>(cx, final_s, d_out);
}

// Round 10
// 1052.179 us; speedup vs baseline: 12.5422x; 1.0002x over previous
//
#include <hip/hip_runtime.h>
#include <hip/hip_bf16.h>
#include <math.h>

#define B_ 4
#define T_ 1024
#define O_ 128
#define D_ 512
#define H_ 8
#define L_ 6
#define TK_ 2176
#define MM_ 100000
#define EH_ 4
#define EHD_ 128
#define HD_ 64

typedef float f32x4 __attribute__((ext_vector_type(4)));
typedef short bf16x8 __attribute__((ext_vector_type(8)));
typedef unsigned short u16;

// PRIMES per reference: base=131, x=base+h*1009; row[i]=x; x=x*31+1 (uint32 wrap)
__device__ __constant__ unsigned int PRIMES_[4][4] = {
  {131u,  4062u,  125923u, 3903614u},
  {1140u, 35341u, 1095572u, 33962733u},
  {2149u, 66620u, 2065221u, 64021852u},
  {3158u, 97899u, 3034870u, 94080971u},
};

__device__ __forceinline__ float wave_sum_f(float v) {
  #pragma unroll
  for (int off = 32; off; off >>= 1) v += __shfl_xor(v, off);
  return v;
}

__device__ __forceinline__ short f2bf(float f) {
  unsigned int u = __float_as_uint(f);
  unsigned int r = (u + 0x7fffu + ((u >> 16) & 1u)) >> 16;
  return (short)r;
}

__device__ __forceinline__ void gload16(const void* g, void* l) {
  __builtin_amdgcn_global_load_lds((const __attribute__((address_space(1))) void*)g,
                                   (__attribute__((address_space(3))) void*)l, 16, 0, 0);
}

// ---------------- rope tables: cos/sin [TK][32] ----------------
__global__ __launch_bounds__(64) void rope_table_k(float* __restrict__ rc,
                                                   float* __restrict__ rs) {
  int i = blockIdx.x * 64 + threadIdx.x;
  int t = i >> 5, j = i & 31;
  float freq = __powf(10000.0f, -(float)j / 32.0f);
  float ang = (float)t * freq;
  rc[i] = cosf(ang);
  rs[i] = sinf(ang);
}

// ---------------- ssum @ ssum_W -> ssp[B][D] ----------------
__global__ __launch_bounds__(256) void ssum_proj_k(const float* __restrict__ ssum,
                                                   const float* __restrict__ sW,
                                                   float* __restrict__ ssp) {
  int col = blockIdx.x * 256 + threadIdx.x;
  int b = blockIdx.y;
  float acc = 0.f;
  for (int d = 0; d < D_; ++d) acc += ssum[b * D_ + d] * sW[(size_t)d * D_ + col];
  ssp[b * D_ + col] = acc;
}

// ---------------- f32 tiled GEMM (preamble mem projection only) ----------------
__global__ __launch_bounds__(256) void sgemm_k(const float* __restrict__ A,
                                               const float* __restrict__ W,
                                               const float* __restrict__ bias,
                                               float* __restrict__ C,
                                               int M, int N, int K) {
  __shared__ float As[16][68];
  __shared__ float Bs[16][68];
  int tid = threadIdx.x;
  int row0 = blockIdx.y * 64;
  int col0 = blockIdx.x * 64;
  int tx = tid & 15, ty = tid >> 4;
  int am = tid >> 2, ak = (tid & 3) * 4;
  int bk = tid >> 4, bc = (tid & 15) * 4;
  float acc[4][4] = {};
  for (int k0 = 0; k0 < K; k0 += 16) {
    float4 av = *reinterpret_cast<const float4*>(&A[(size_t)(row0 + am) * K + k0 + ak]);
    As[ak + 0][am] = av.x; As[ak + 1][am] = av.y; As[ak + 2][am] = av.z; As[ak + 3][am] = av.w;
    float4 bv = *reinterpret_cast<const float4*>(&W[(size_t)(k0 + bk) * N + col0 + bc]);
    *reinterpret_cast<float4*>(&Bs[bk][bc]) = bv;
    __syncthreads();
    #pragma unroll
    for (int kk = 0; kk < 16; ++kk) {
      float4 a4 = *reinterpret_cast<const float4*>(&As[kk][ty * 4]);
      float4 b4 = *reinterpret_cast<const float4*>(&Bs[kk][tx * 4]);
      float a[4] = {a4.x, a4.y, a4.z, a4.w};
      float b[4] = {b4.x, b4.y, b4.z, b4.w};
      #pragma unroll
      for (int i = 0; i < 4; ++i)
        #pragma unroll
        for (int j = 0; j < 4; ++j) acc[i][j] += a[i] * b[j];
    }
    __syncthreads();
  }
  int cbase = col0 + tx * 4;
  float4 b4 = *reinterpret_cast<const float4*>(&bias[cbase]);
  float bb[4] = {b4.x, b4.y, b4.z, b4.w};
  #pragma unroll
  for (int i = 0; i < 4; ++i) {
    int row = row0 + ty * 4 + i;
    *reinterpret_cast<float4*>(&C[(size_t)row * N + cbase]) =
        make_float4(acc[i][0] + bb[0], acc[i][1] + bb[1], acc[i][2] + bb[2], acc[i][3] + bb[3]);
  }
}

// ---------------- batched weight convert+transpose: f32 [K][N] -> bf16 [N][K] ----------------
__device__ __forceinline__ void wconv_tile(const float* __restrict__ W, u16* __restrict__ wT,
                                           int K, int N) {
  __shared__ float s[64][65];
  int n0 = blockIdx.x * 64, k0 = blockIdx.y * 64;
  int tid = threadIdx.x;
  int kr = tid >> 4, nc = (tid & 15) * 4;
  #pragma unroll
  for (int kk = 0; kk < 4; ++kk) {
    float4 f = *reinterpret_cast<const float4*>(&W[(size_t)(k0 + kr + kk * 16) * N + n0 + nc]);
    s[kr + kk * 16][nc + 0] = f.x; s[kr + kk * 16][nc + 1] = f.y;
    s[kr + kk * 16][nc + 2] = f.z; s[kr + kk * 16][nc + 3] = f.w;
  }
  __syncthreads();
  int nr = tid >> 4, kc = (tid & 15) * 4;
  #pragma unroll
  for (int nn = 0; nn < 4; ++nn) {
    int n = nr + nn * 16;
    ushort4 o;
    o.x = (u16)f2bf(s[kc + 0][n]); o.y = (u16)f2bf(s[kc + 1][n]);
    o.z = (u16)f2bf(s[kc + 2][n]); o.w = (u16)f2bf(s[kc + 3][n]);
    *reinterpret_cast<ushort4*>(&wT[(size_t)(n0 + n) * K + k0 + kc]) = o;
  }
}

__global__ __launch_bounds__(256) void wconv_qkvo_k(const float* __restrict__ qW,
                                                    const float* __restrict__ kW,
                                                    const float* __restrict__ vW,
                                                    const float* __restrict__ oW,
                                                    u16* __restrict__ dst) {
  int z = blockIdx.z;
  int l = z >> 2, which = z & 3;
  const float* src = which == 0 ? qW : which == 1 ? kW : which == 2 ? vW : oW;
  wconv_tile(src + (size_t)l * D_ * D_, dst + (size_t)z * D_ * D_, D_, D_);
}

__global__ __launch_bounds__(256) void wconv_win_k(const float* __restrict__ w_in,
                                                   u16* __restrict__ dst) {
  int l = blockIdx.z;
  wconv_tile(w_in + (size_t)l * 512 * 4096, dst + (size_t)l * 4096 * 512, 512, 4096);
}

__global__ __launch_bounds__(256) void wconv_wout_k(const float* __restrict__ w_out,
                                                    u16* __restrict__ dst) {
  int l = blockIdx.z;
  wconv_tile(w_out + (size_t)l * 2048 * 512, dst + (size_t)l * 512 * 2048, 2048, 512);
}

// ---------------- small MFMA GEMM: 64x64 tile, 4 waves (wave 32x32) ----------------
template<int EPI>
__global__ __launch_bounds__(256) void gemm_sm_k(const u16* __restrict__ A,
                                                 const u16* __restrict__ Bt,
                                                 const float* __restrict__ bias,
                                                 void* __restrict__ Cout,
                                                 int M, int N, int K, int posmod,
                                                 const float* __restrict__ rc,
                                                 const float* __restrict__ rs) {
  __shared__ __align__(16) u16 As[2][64 * 32];
  __shared__ __align__(16) u16 Bs[2][64 * 32];
  int tid = threadIdx.x;
  int w = tid >> 6, lane = tid & 63;
  int lr = lane & 15, lg = lane >> 4;
  int row0 = blockIdx.y * 64, col0 = blockIdx.x * 64;
  int wr = w >> 1, wc = w & 1;
  f32x4 acc[2][2] = {};

  int srow = tid >> 2;
  int skel = (tid & 3) * 8;

  auto stage = [&](int buf, int k0) {
    gload16(A + (size_t)(row0 + srow) * K + k0 + skel, &As[buf][srow * 32 + skel]);
    gload16(Bt + (size_t)(col0 + srow) * K + k0 + skel, &Bs[buf][srow * 32 + skel]);
  };

  stage(0, 0);
  __syncthreads();
  int nk = K >> 5;
  int buf = 0;
  for (int t = 0; t < nk; ++t) {
    if (t + 1 < nk) stage(buf ^ 1, (t + 1) * 32);
    bf16x8 af[2], bf[2];
    #pragma unroll
    for (int i = 0; i < 2; ++i)
      af[i] = *reinterpret_cast<const bf16x8*>(&As[buf][(wr * 32 + i * 16 + lr) * 32 + lg * 8]);
    #pragma unroll
    for (int j = 0; j < 2; ++j)
      bf[j] = *reinterpret_cast<const bf16x8*>(&Bs[buf][(wc * 32 + j * 16 + lr) * 32 + lg * 8]);
    #pragma unroll
    for (int i = 0; i < 2; ++i)
      #pragma unroll
      for (int j = 0; j < 2; ++j)
        acc[i][j] = __builtin_amdgcn_mfma_f32_16x16x32_bf16(af[i], bf[j], acc[i][j], 0, 0, 0);
    __syncthreads();
    buf ^= 1;
  }

  #pragma unroll
  for (int j = 0; j < 2; ++j) {
    int col = col0 + wc * 32 + j * 16 + lr;
    float bs = bias ? bias[col] : 0.f;
    #pragma unroll
    for (int i = 0; i < 2; ++i) {
      #pragma unroll
      for (int r = 0; r < 4; ++r) {
        int row = row0 + wr * 32 + i * 16 + lg * 4 + r;
        float v = acc[i][j][r] + bs;
        if (EPI == 1) {
          int pos = row % posmod;
          int d = col & 63;
          float c = rc[(size_t)pos * 32 + (d >> 1)];
          float s = rs[(size_t)pos * 32 + (d >> 1)];
          float partner = __shfl_xor(v, 1);
          v = (d & 1) ? (partner * s + v * c) : (v * c - partner * s);
        }
        if (EPI == 2) {
          float* Cf = (float*)Cout;
          Cf[(size_t)row * N + col] += v;
        } else {
          u16* Cb = (u16*)Cout;
          Cb[(size_t)row * N + col] = (u16)f2bf(v);
        }
      }
    }
  }
}

// ---------------- fused K+V projection, XCD-pinned grid ----------------
__global__ __launch_bounds__(256) void kv_gemm_k(const u16* __restrict__ A,
                                                 const u16* __restrict__ wqkvoT,
                                                 const float* __restrict__ kbias_all,
                                                 const float* __restrict__ vbias_all,
                                                 u16* __restrict__ kb_base,
                                                 u16* __restrict__ vb_base,
                                                 const float* __restrict__ rc,
                                                 const float* __restrict__ rs,
                                                 int l0, size_t ostride) {
  __shared__ __align__(16) u16 As[2][128 * 32];
  __shared__ __align__(16) u16 Bk[2][64 * 32];
  __shared__ __align__(16) u16 Bv[2][64 * 32];
  const int K = 512, N = 512;
  int bid = blockIdx.x;
  int c_ = bid & 7;
  int x_ = (bid >> 3) & 7;
  int rest = bid >> 6;
  int yh = rest % 9;
  int z = rest / 9;
  int y_ = yh * 8 + c_;
  if (y_ >= 68) return;
  int l = l0 + z;
  const u16* wkT = wqkvoT + ((size_t)l * 4 + 1) * (D_ * D_);
  const u16* wvT = wqkvoT + ((size_t)l * 4 + 2) * (D_ * D_);
  const float* kbias = kbias_all + l * D_;
  const float* vbias = vbias_all + l * D_;
  u16* kb = kb_base + (size_t)z * ostride;
  u16* vb = vb_base + (size_t)z * ostride;
  int tid = threadIdx.x;
  int w = tid >> 6, lane = tid & 63;
  int lr = lane & 15, lg = lane >> 4;
  int row0 = y_ * 128, col0 = x_ * 64;
  int wr = w >> 1, wc = w & 1;
  f32x4 ak_[4][2] = {};
  f32x4 av_[4][2] = {};

  int srow = lane >> 2;
  int skel = (lane & 3) * 8;

  auto stage = [&](int buf, int k0) {
    #pragma unroll
    for (int ci = 0; ci < 2; ++ci) {
      int c = w * 2 + ci;
      gload16(A + (size_t)(row0 + c * 16 + srow) * K + k0 + skel, &As[buf][c * 512]);
    }
    gload16(wkT + (size_t)(col0 + w * 16 + srow) * K + k0 + skel, &Bk[buf][w * 512]);
    gload16(wvT + (size_t)(col0 + w * 16 + srow) * K + k0 + skel, &Bv[buf][w * 512]);
  };

  stage(0, 0);
  __syncthreads();
  int buf = 0;
  for (int t = 0; t < 16; ++t) {
    if (t + 1 < 16) stage(buf ^ 1, (t + 1) * 32);
    bf16x8 af[4], bk[2], bv[2];
    #pragma unroll
    for (int i = 0; i < 4; ++i)
      af[i] = *reinterpret_cast<const bf16x8*>(&As[buf][(wr * 64 + i * 16 + lr) * 32 + lg * 8]);
    #pragma unroll
    for (int j = 0; j < 2; ++j) {
      bk[j] = *reinterpret_cast<const bf16x8*>(&Bk[buf][(wc * 32 + j * 16 + lr) * 32 + lg * 8]);
      bv[j] = *reinterpret_cast<const bf16x8*>(&Bv[buf][(wc * 32 + j * 16 + lr) * 32 + lg * 8]);
    }
    #pragma unroll
    for (int i = 0; i < 4; ++i)
      #pragma unroll
      for (int j = 0; j < 2; ++j) {
        ak_[i][j] = __builtin_amdgcn_mfma_f32_16x16x32_bf16(af[i], bk[j], ak_[i][j], 0, 0, 0);
        av_[i][j] = __builtin_amdgcn_mfma_f32_16x16x32_bf16(af[i], bv[j], av_[i][j], 0, 0, 0);
      }
    __syncthreads();
    buf ^= 1;
  }

  #pragma unroll
  for (int j = 0; j < 2; ++j) {
    int col = col0 + wc * 32 + j * 16 + lr;
    float kbs = kbias[col], vbs = vbias[col];
    int d = col & 63;
    #pragma unroll
    for (int i = 0; i < 4; ++i) {
      #pragma unroll
      for (int r = 0; r < 4; ++r) {
        int row = row0 + wr * 64 + i * 16 + lg * 4 + r;
        int pos = row % TK_;
        float vk = ak_[i][j][r] + kbs;
        float c = rc[(size_t)pos * 32 + (d >> 1)];
        float s = rs[(size_t)pos * 32 + (d >> 1)];
        float partner = __shfl_xor(vk, 1);
        vk = (d & 1) ? (partner * s + vk * c) : (vk * c - partner * s);
        kb[(size_t)row * N + col] = (u16)f2bf(vk);
        vb[(size_t)row * N + col] = (u16)f2bf(av_[i][j][r] + vbs);
      }
    }
  }
}

// ---------------- fused MLP-in MFMA ----------------
__global__ __launch_bounds__(256) void mlp_in_mfma_k(const u16* __restrict__ A,
                                                     const u16* __restrict__ wiT,
                                                     u16* __restrict__ Hout) {
  __shared__ __align__(16) u16 As[2][128 * 32];
  __shared__ __align__(16) u16 Bg[2][64 * 32];
  __shared__ __align__(16) u16 Bv[2][64 * 32];
  int tid = threadIdx.x;
  int w = tid >> 6, lane = tid & 63;
  int lr = lane & 15, lg = lane >> 4;
  int hc0 = blockIdx.x * 64, row0 = blockIdx.y * 128;
  int wr = w >> 1, wc = w & 1;
  f32x4 ag[4][2] = {};
  f32x4 av[4][2] = {};
  const int K = 512;

  int srow = lane >> 2;
  int skel = (lane & 3) * 8;

  auto stage = [&](int buf, int k0) {
    #pragma unroll
    for (int ci = 0; ci < 2; ++ci) {
      int c = w * 2 + ci;
      gload16(A + (size_t)(row0 + c * 16 + srow) * K + k0 + skel, &As[buf][c * 512]);
    }
    gload16(wiT + (size_t)(hc0 + w * 16 + srow) * K + k0 + skel, &Bg[buf][w * 512]);
    gload16(wiT + (size_t)(2048 + hc0 + w * 16 + srow) * K + k0 + skel, &Bv[buf][w * 512]);
  };

  stage(0, 0);
  __syncthreads();
  int buf = 0;
  for (int t = 0; t < 16; ++t) {
    if (t + 1 < 16) stage(buf ^ 1, (t + 1) * 32);
    bf16x8 af[4], bg[2], bv[2];
    #pragma unroll
    for (int i = 0; i < 4; ++i)
      af[i] = *reinterpret_cast<const bf16x8*>(&As[buf][(wr * 64 + i * 16 + lr) * 32 + lg * 8]);
    #pragma unroll
    for (int j = 0; j < 2; ++j) {
      bg[j] = *reinterpret_cast<const bf16x8*>(&Bg[buf][(wc * 32 + j * 16 + lr) * 32 + lg * 8]);
      bv[j] = *reinterpret_cast<const bf16x8*>(&Bv[buf][(wc * 32 + j * 16 + lr) * 32 + lg * 8]);
    }
    #pragma unroll
    for (int i = 0; i < 4; ++i)
      #pragma unroll
      for (int j = 0; j < 2; ++j) {
        ag[i][j] = __builtin_amdgcn_mfma_f32_16x16x32_bf16(af[i], bg[j], ag[i][j], 0, 0, 0);
        av[i][j] = __builtin_amdgcn_mfma_f32_16x16x32_bf16(af[i], bv[j], av[i][j], 0, 0, 0);
      }
    __syncthreads();
    buf ^= 1;
  }

  #pragma unroll
  for (int j = 0; j < 2; ++j) {
    int col = hc0 + wc * 32 + j * 16 + lr;
    #pragma unroll
    for (int i = 0; i < 4; ++i) {
      #pragma unroll
      for (int r = 0; r < 4; ++r) {
        int row = row0 + wr * 64 + i * 16 + lg * 4 + r;
        float g = ag[i][j][r];
        float sg = g / (1.f + __expf(-g));
        Hout[(size_t)row * 2048 + col] = (u16)f2bf(sg * av[i][j][r]);
      }
    }
  }
}

// ---------------- rmsnorm rows ----------------
template<int OUTBF>
__global__ __launch_bounds__(128) void rmsnorm_k(const float* __restrict__ in,
                                                 const float* __restrict__ scale,
                                                 void* __restrict__ out) {
  int row = blockIdx.x;
  int tid = threadIdx.x;
  float4 v = *reinterpret_cast<const float4*>(&in[(size_t)row * D_ + tid * 4]);
  float ss = v.x * v.x + v.y * v.y + v.z * v.z + v.w * v.w;
  ss = wave_sum_f(ss);
  __shared__ float red[2];
  if ((tid & 63) == 0) red[tid >> 6] = ss;
  __syncthreads();
  ss = red[0] + red[1];
  float inv = 1.0f / sqrtf(ss / (float)D_ + 1e-6f);
  float4 sc = *reinterpret_cast<const float4*>(&scale[tid * 4]);
  float o0 = v.x * inv * sc.x, o1 = v.y * inv * sc.y, o2 = v.z * inv * sc.z, o3 = v.w * inv * sc.w;
  if (OUTBF) {
    ushort4 o;
    o.x = (u16)f2bf(o0); o.y = (u16)f2bf(o1); o.z = (u16)f2bf(o2); o.w = (u16)f2bf(o3);
    *reinterpret_cast<ushort4*>((u16*)out + (size_t)row * D_ + tid * 4) = o;
  } else {
    *reinterpret_cast<float4*>((float*)out + (size_t)row * D_ + tid * 4) =
        make_float4(o0, o1, o2, o3);
  }
}

// ---------------- mem rows ----------------
__global__ __launch_bounds__(128) void memnorm_k(const float* __restrict__ tmp,
                                                 const float* __restrict__ scale,
                                                 u16* __restrict__ kv) {
  int o = blockIdx.x, b = blockIdx.y;
  int tid = threadIdx.x;
  float4 v = *reinterpret_cast<const float4*>(&tmp[(size_t)(b * O_ + o) * D_ + tid * 4]);
  float ss = v.x * v.x + v.y * v.y + v.z * v.z + v.w * v.w;
  ss = wave_sum_f(ss);
  __shared__ float red[2];
  if ((tid & 63) == 0) red[tid >> 6] = ss;
  __syncthreads();
  ss = red[0] + red[1];
  float inv = 1.0f / sqrtf(ss / (float)D_ + 1e-6f);
  float4 sc = *reinterpret_cast<const float4*>(&scale[tid * 4]);
  ushort4 oo;
  oo.x = (u16)f2bf(v.x * inv * sc.x); oo.y = (u16)f2bf(v.y * inv * sc.y);
  oo.z = (u16)f2bf(v.z * inv * sc.z); oo.w = (u16)f2bf(v.w * inv * sc.w);
  *reinterpret_cast<ushort4*>(&kv[(size_t)(b * TK_ + o) * D_ + tid * 4]) = oo;
}

// ---------------- engram rows ----------------
__global__ __launch_bounds__(128) void engram_k(const int* __restrict__ tokens,
                                                const int* __restrict__ mem_ids,
                                                const float* __restrict__ etab,
                                                const float* __restrict__ egate,
                                                const float* __restrict__ escale,
                                                u16* __restrict__ kv) {
  int t = blockIdx.x, b = blockIdx.y;
  int tid = threadIdx.x;
  unsigned int toks[4];
  #pragma unroll
  for (int i = 0; i < 4; ++i) {
    int idx = t - i;
    toks[i] = (idx >= 0) ? (unsigned int)tokens[b * T_ + idx]
                         : (unsigned int)mem_ids[b * O_ + O_ + idx];
  }
  int c = tid * 4;
  int h = c >> 7;
  int e = c & 127;
  unsigned int hs = 0;
  #pragma unroll
  for (int i = 0; i < 4; ++i) hs += toks[i] * PRIMES_[h][i];
  int idxh = (int)(hs % (unsigned int)MM_);
  float4 r = *reinterpret_cast<const float4*>(&etab[((size_t)idxh * EH_ + h) * EHD_ + e]);
  float4 g = *reinterpret_cast<const float4*>(&egate[h * EHD_ + e]);
  float4 val;
  val.x = r.x / (1.f + __expf(-g.x));
  val.y = r.y / (1.f + __expf(-g.y));
  val.z = r.z / (1.f + __expf(-g.z));
  val.w = r.w / (1.f + __expf(-g.w));
  float ss = val.x * val.x + val.y * val.y + val.z * val.z + val.w * val.w;
  ss = wave_sum_f(ss);
  __shared__ float red[2];
  if ((tid & 63) == 0) red[tid >> 6] = ss;
  __syncthreads();
  ss = red[0] + red[1];
  float inv = 1.0f / sqrtf(ss / (float)D_ + 1e-6f);
  float4 sc = *reinterpret_cast<const float4*>(&escale[c]);
  ushort4 oo;
  oo.x = (u16)f2bf(val.x * inv * sc.x); oo.y = (u16)f2bf(val.y * inv * sc.y);
  oo.z = (u16)f2bf(val.z * inv * sc.z); oo.w = (u16)f2bf(val.w * inv * sc.w);
  *reinterpret_cast<ushort4*>(&kv[(size_t)(b * TK_ + O_ + t) * D_ + c]) = oo;
}

// ---------------- embed + ssum inject ----------------
__global__ __launch_bounds__(128) void embed_k(const int* __restrict__ tokens,
                                               const float* __restrict__ etab,
                                               const float* __restrict__ ssp,
                                               const float* __restrict__ alpha_g,
                                               float* __restrict__ cx,
                                               u16* __restrict__ kv) {
  int t = blockIdx.x, b = blockIdx.y;
  int tid = threadIdx.x;
  int c = tid * 4;
  int tok = tokens[b * T_ + t];
  float4 e = *reinterpret_cast<const float4*>(&etab[(size_t)tok * D_ + c]);
  float4 sp = *reinterpret_cast<const float4*>(&ssp[b * D_ + c]);
  float4 ag = *reinterpret_cast<const float4*>(&alpha_g[c]);
  float4 x;
  x.x = e.x + sp.x / (1.f + __expf(-ag.x));
  x.y = e.y + sp.y / (1.f + __expf(-ag.y));
  x.z = e.z + sp.z / (1.f + __expf(-ag.z));
  x.w = e.w + sp.w / (1.f + __expf(-ag.w));
  *reinterpret_cast<float4*>(&cx[(size_t)(b * T_ + t) * D_ + c]) = x;
  ushort4 oo;
  oo.x = (u16)f2bf(x.x); oo.y = (u16)f2bf(x.y);
  oo.z = (u16)f2bf(x.z); oo.w = (u16)f2bf(x.w);
  *reinterpret_cast<ushort4*>(&kv[(size_t)(b * TK_ + O_ + T_ + t) * D_ + c]) = oo;
}

// ---------------- MFMA flash attention v6: KVBLK=128, paired q-tiles ----------------
// K LDS: [128 k][64 d] swizzled; V^T LDS: [64 d][128 k] swizzled; pbuf: per-wave P^T pairs.
#define KIDX8(r, c) (((r) << 6) + ((c) ^ (((r) & 7) << 3)))
#define VIDX(d, c)  (((d) << 7) + ((c) ^ (((d) & 15) << 2)))
#define PIDX2(q, o) (((q) << 6) + ((o) ^ (((q) & 15) << 2)))

__global__ __launch_bounds__(512) void attn_mfma_k(const u16* __restrict__ qb,
                                                   const u16* __restrict__ kb,
                                                   const u16* __restrict__ vb,
                                                   const int* __restrict__ tokens,
                                                   u16* __restrict__ ob) {
  __shared__ __align__(16) short ks[2][128 * 64];
  __shared__ __align__(16) short vst[2][64 * 128];        // transposed: [d][k]
  __shared__ __align__(16) unsigned int pbuf[8][16 * 64]; // per-wave P^T packed pairs
  __shared__ unsigned char vtok[T_];

  int fid = blockIdx.x;       // 256 blocks
  int h = fid & 7;
  int s = fid >> 3;           // 0..31
  int pair = s & 7;           // bxA = pair, bxB = 15 - pair
  int b = s >> 3;             // 0..3
  int bxA = pair, bxB = 15 - pair;

  int tid = threadIdx.x;
  int w = tid >> 6, lane = tid & 63;
  int lr = lane & 15;
  int lg = lane >> 4;
  int myBx = (w < 4) ? bxA : bxB;
  int qw0 = myBx * 64 + (w & 3) * 16;
  int tq = qw0 + lr;  // this lane's query row

  for (int i = tid; i < T_; i += 512) vtok[i] = (tokens[b * T_ + i] != 0);

  bf16x8 aq[2];  // Q for this lane's q row: B-operand (col=lr, d=lg*8..)
  {
    const u16* qp = &qb[((size_t)(b * T_) + tq) * D_ + h * 64];
    aq[0] = *reinterpret_cast<const bf16x8*>(qp + lg * 8);
    aq[1] = *reinterpret_cast<const bf16x8*>(qp + 32 + lg * 8);
  }

  float m_ = -1e30f, lsum = 0.f;
  f32x4 od[4];
  #pragma unroll
  for (int dt = 0; dt < 4; ++dt) od[dt] = (f32x4){0.f, 0.f, 0.f, 0.f};

  // K staging (512 thr): row sr (0..127), 16-col chunk pair sc
  int sr = tid >> 2;
  int sc = (tid & 3) * 16;
  // V staging (512 thr): 4x4 transpose blocks: source k rows k4..k4+3, cols vc..vc+3
  int k4 = (tid >> 4) * 4;
  int vc = (tid & 15) * 4;

  int te = (bxB >> 1) + 1;           // engram/x 128-key tiles for superset schedule
  int myTe = myBx >> 1;              // last tile index this wave participates in
  int nt = 1 + 2 * te;
  auto tile_pos = [&](int i, int& pos0, int& base, bool& masked, bool& part) {
    if (i < 1) { pos0 = 0; base = 0; masked = false; part = true; }
    else if (i < 1 + te) {
      int t = i - 1;
      pos0 = O_ + t * 128; base = O_; masked = true; part = (t <= myTe);
    } else {
      int t = i - 1 - te;
      pos0 = O_ + T_ + t * 128; base = O_ + T_; masked = true; part = (t <= myTe);
    }
  };

  bf16x8 pk0, pk1;
  short4 pv0, pv1, pv2, pv3;

  auto load_regs = [&](int pos0) {
    const u16* kg = &kb[((size_t)(b * TK_) + pos0 + sr) * D_ + h * 64 + sc];
    pk0 = *reinterpret_cast<const bf16x8*>(kg);
    pk1 = *reinterpret_cast<const bf16x8*>(kg + 8);
    const u16* vg = &vb[((size_t)(b * TK_) + pos0 + k4) * D_ + h * 64 + vc];
    pv0 = *reinterpret_cast<const short4*>(vg);
    pv1 = *reinterpret_cast<const short4*>(vg + D_);
    pv2 = *reinterpret_cast<const short4*>(vg + 2 * D_);
    pv3 = *reinterpret_cast<const short4*>(vg + 3 * D_);
  };

  auto write_lds = [&](int buf) {
    *reinterpret_cast<bf16x8*>(&ks[buf][KIDX8(sr, sc)]) = pk0;
    *reinterpret_cast<bf16x8*>(&ks[buf][KIDX8(sr, sc + 8)]) = pk1;
    short4 t0 = make_short4(pv0.x, pv1.x, pv2.x, pv3.x);
    short4 t1 = make_short4(pv0.y, pv1.y, pv2.y, pv3.y);
    short4 t2 = make_short4(pv0.z, pv1.z, pv2.z, pv3.z);
    short4 t3 = make_short4(pv0.w, pv1.w, pv2.w, pv3.w);
    *reinterpret_cast<short4*>(&vst[buf][VIDX(vc + 0, k4)]) = t0;
    *reinterpret_cast<short4*>(&vst[buf][VIDX(vc + 1, k4)]) = t1;
    *reinterpret_cast<short4*>(&vst[buf][VIDX(vc + 2, k4)]) = t2;
    *reinterpret_cast<short4*>(&vst[buf][VIDX(vc + 3, k4)]) = t3;
  };

  unsigned int* pw = (unsigned int*)pbuf[w];

  auto compute = [&](int buf, int pos0, int base, bool masked) {
    float sv[8][4];
    __builtin_amdgcn_s_setprio(1);
    #pragma unroll
    for (int kt = 0; kt < 8; ++kt) {
      bf16x8 ka0 = *reinterpret_cast<const bf16x8*>(&ks[buf][KIDX8(kt * 16 + lr, lg * 8)]);
      bf16x8 ka1 = *reinterpret_cast<const bf16x8*>(&ks[buf][KIDX8(kt * 16 + lr, 32 + lg * 8)]);
      f32x4 sf = (f32x4){0.f, 0.f, 0.f, 0.f};
      sf = __builtin_amdgcn_mfma_f32_16x16x32_bf16(ka0, aq[0], sf, 0, 0, 0);
      sf = __builtin_amdgcn_mfma_f32_16x16x32_bf16(ka1, aq[1], sf, 0, 0, 0);
      #pragma unroll
      for (int r = 0; r < 4; ++r) sv[kt][r] = sf[r];
    }
    __builtin_amdgcn_s_setprio(0);
    if (masked) {
      #pragma unroll
      for (int kt = 0; kt < 8; ++kt) {
        #pragma unroll
        for (int r = 0; r < 4; ++r) {
          int tk = pos0 + kt * 16 + lg * 4 + r - base;
          bool valid = (vtok[tk] != 0) && (tk <= tq);
          sv[kt][r] = valid ? sv[kt][r] * 0.125f : -1e30f;
        }
      }
    } else {
      #pragma unroll
      for (int kt = 0; kt < 8; ++kt)
        #pragma unroll
        for (int r = 0; r < 4; ++r) sv[kt][r] *= 0.125f;
    }
    float pmax = sv[0][0];
    #pragma unroll
    for (int kt = 0; kt < 8; ++kt)
      #pragma unroll
      for (int r = 0; r < 4; ++r) pmax = fmaxf(pmax, sv[kt][r]);
    pmax = fmaxf(pmax, __shfl_xor(pmax, 16));
    pmax = fmaxf(pmax, __shfl_xor(pmax, 32));
    float mnew = fmaxf(m_, pmax);
    float al = __expf(m_ - mnew);
    m_ = mnew;
    float psum = 0.f;
    #pragma unroll
    for (int kt = 0; kt < 8; ++kt)
      #pragma unroll
      for (int r = 0; r < 4; ++r) {
        float pe = __expf(sv[kt][r] - mnew);
        sv[kt][r] = pe;
        psum += pe;
      }
    psum += __shfl_xor(psum, 16);
    psum += __shfl_xor(psum, 32);
    lsum = lsum * al + psum;
    #pragma unroll
    for (int dt = 0; dt < 4; ++dt) {
      f32x4 o = od[dt];
      o[0] *= al; o[1] *= al; o[2] *= al; o[3] *= al;
      od[dt] = o;
    }
    // pack P pairs -> per-wave LDS (u32 = bf16(lo)|bf16(hi)<<16), swizzled
    #pragma unroll
    for (int kt = 0; kt < 8; ++kt) {
      uint2 wp;
      asm("v_cvt_pk_bf16_f32 %0, %1, %2" : "=v"(wp.x) : "v"(sv[kt][0]), "v"(sv[kt][1]));
      asm("v_cvt_pk_bf16_f32 %0, %1, %2" : "=v"(wp.y) : "v"(sv[kt][2]), "v"(sv[kt][3]));
      *reinterpret_cast<uint2*>(&pw[PIDX2(lr, kt * 8 + lg * 2)]) = wp;
    }
    bf16x8 pf0 = *reinterpret_cast<const bf16x8*>(&pw[PIDX2(lr, 0 * 16 + lg * 4)]);
    bf16x8 pf1 = *reinterpret_cast<const bf16x8*>(&pw[PIDX2(lr, 1 * 16 + lg * 4)]);
    bf16x8 pf2 = *reinterpret_cast<const bf16x8*>(&pw[PIDX2(lr, 2 * 16 + lg * 4)]);
    bf16x8 pf3 = *reinterpret_cast<const bf16x8*>(&pw[PIDX2(lr, 3 * 16 + lg * 4)]);
    __builtin_amdgcn_s_setprio(1);
    #pragma unroll
    for (int dt = 0; dt < 4; ++dt) {
      int d = dt * 16 + lr;
      #pragma unroll
      for (int m = 0; m < 4; ++m) {
        short4 lo = *reinterpret_cast<const short4*>(&vst[buf][VIDX(d, m * 32 + lg * 8)]);
        short4 hi = *reinterpret_cast<const short4*>(&vst[buf][VIDX(d, m * 32 + lg * 8 + 4)]);
        bf16x8 va = {lo.x, lo.y, lo.z, lo.w, hi.x, hi.y, hi.z, hi.w};
        bf16x8 pf = (m == 0) ? pf0 : (m == 1) ? pf1 : (m == 2) ? pf2 : pf3;
        od[dt] = __builtin_amdgcn_mfma_f32_16x16x32_bf16(va, pf, od[dt], 0, 0, 0);
      }
    }
    __builtin_amdgcn_s_setprio(0);
  };

  // prologue: load tile 0
  {
    int pos0, base; bool masked, part;
    tile_pos(0, pos0, base, masked, part);
    load_regs(pos0);
  }
  // main loop: one barrier per 128-key tile.
  // write_lds(i)->buf(i&1) conflicts only with compute(i-2), fenced by barrier(i-1).
  for (int i = 0; i < nt; ++i) {
    write_lds(i & 1);
    __syncthreads();
    int pos0, base; bool masked, part;
    tile_pos(i, pos0, base, masked, part);
    if (i + 1 < nt) {
      int npos, nb; bool nm, np;
      tile_pos(i + 1, npos, nb, nm, np);
      load_regs(npos);  // HBM loads in flight under compute
    }
    if (part) compute(i & 1, pos0, base, masked);
  }

  // epilogue: od^T holds O[q=lr][d=dt*16+lg*4+r]
  float inv = 1.0f / lsum;
  #pragma unroll
  for (int dt = 0; dt < 4; ++dt) {
    ushort4 o4;
    o4.x = (u16)f2bf(od[dt][0] * inv);
    o4.y = (u16)f2bf(od[dt][1] * inv);
    o4.z = (u16)f2bf(od[dt][2] * inv);
    o4.w = (u16)f2bf(od[dt][3] * inv);
    *reinterpret_cast<ushort4*>(
        &ob[((size_t)(b * T_) + tq) * D_ + h * 64 + dt * 16 + lg * 4]) = o4;
  }
}

extern "C" void kernel_launch(void* const* d_in, const int* in_sizes, int n_in,
                              void* d_out, int out_size, void* d_ws, size_t ws_size,
                              hipStream_t stream) {
  (void)in_sizes; (void)n_in; (void)out_size;
  const int* tokens = (const int*)d_in[0];
  const int* mem_ids = (const int*)d_in[1];
  const float* mem_emb = (const float*)d_in[2];
  const float* ssum = (const float*)d_in[3];
  const float* embed = (const float*)d_in[4];
  const float* engram_t = (const float*)d_in[5];
  const float* engram_g = (const float*)d_in[6];
  const float* engram_s = (const float*)d_in[7];
  const float* mem_W = (const float*)d_in[8];
  const float* mem_b = (const float*)d_in[9];
  const float* mem_s = (const float*)d_in[10];
  const float* alpha_g = (const float*)d_in[11];
  const float* ssum_W = (const float*)d_in[12];
  const float* ln1 = (const float*)d_in[13];
  const float* qW = (const float*)d_in[14];
  const float* qbias = (const float*)d_in[15];
  const float* kW = (const float*)d_in[16];
  const float* kbias = (const float*)d_in[17];
  const float* vW = (const float*)d_in[18];
  const float* vbias = (const float*)d_in[19];
  const float* oW = (const float*)d_in[20];
  const float* obias = (const float*)d_in[21];
  const float* ln2 = (const float*)d_in[22];
  const float* w_in = (const float*)d_in[23];
  const float* w_out = (const float*)d_in[24];
  const float* final_s = (const float*)d_in[25];

  const size_t KVSZ = (size_t)B_ * TK_ * D_;
  size_t need = (KVSZ * 2 * 2 * L_) + 120u * 1024 * 1024;
  bool batched = ws_size >= need;

  char* p = (char*)d_ws;
  auto alloc = [&](size_t bytes) { char* r = p; p += (bytes + 255) & ~(size_t)255; return r; };
  u16* kv_b   = (u16*)alloc(KVSZ * 2);
  float* cx   = (float*)alloc((size_t)B_ * T_ * D_ * 4);
  u16* nx_b   = (u16*)alloc((size_t)B_ * T_ * D_ * 2);   // also ob (attn out)
  u16* qb_b   = (u16*)alloc((size_t)B_ * T_ * D_ * 2);   // also mem_tmp f32
  int nkv = batched ? L_ : 1;
  u16* kb_all = (u16*)alloc(KVSZ * 2 * nkv);
  u16* vb_all = (u16*)alloc(KVSZ * 2 * nkv);
  u16* hb;
  if (batched) hb = (u16*)alloc((size_t)B_ * T_ * 2048 * 2);
  else hb = kb_all;  // spans kb+vb
  u16* wqkvoT = (u16*)alloc((size_t)L_ * 4 * D_ * D_ * 2);
  u16* wiT    = (u16*)alloc((size_t)L_ * 4096 * 512 * 2);
  u16* woutT  = (u16*)alloc((size_t)L_ * 512 * 2048 * 2);
  float* ssp  = (float*)alloc((size_t)B_ * D_ * 4);
  float* rc   = (float*)alloc((size_t)TK_ * 32 * 4);
  float* rs   = (float*)alloc((size_t)TK_ * 32 * 4);
  float* mem_tmp = (float*)qb_b;
  u16* ob_b = nx_b;

  // preamble + batched weight conversion
  rope_table_k<<<TK_ * 32 / 64, 64, 0, stream>>>(rc, rs);
  wconv_qkvo_k<<<dim3(8, 8, L_ * 4), 256, 0, stream>>>(qW, kW, vW, oW, wqkvoT);
  wconv_win_k<<<dim3(64, 8, L_), 256, 0, stream>>>(w_in, wiT);
  wconv_wout_k<<<dim3(8, 32, L_), 256, 0, stream>>>(w_out, woutT);
  ssum_proj_k<<<dim3(2, B_), 256, 0, stream>>>(ssum, ssum_W, ssp);
  sgemm_k<<<dim3(8, 8), 256, 0, stream>>>(mem_emb, mem_W, mem_b, mem_tmp, B_ * O_, D_, D_);
  memnorm_k<<<dim3(O_, B_), 128, 0, stream>>>(mem_tmp, mem_s, kv_b);
  engram_k<<<dim3(T_, B_), 128, 0, stream>>>(tokens, mem_ids, engram_t, engram_g, engram_s, kv_b);
  embed_k<<<dim3(T_, B_), 128, 0, stream>>>(tokens, embed, ssp, alpha_g, cx, kv_b);

  if (batched) {
    // all 6 layers' K/V in one XCD-pinned dispatch
    kv_gemm_k<<<dim3(8 * 8 * 9 * L_), 256, 0, stream>>>(kv_b, wqkvoT, kbias, vbias,
                                                        kb_all, vb_all, rc, rs, 0, KVSZ);
  }

  const size_t WSZ = (size_t)D_ * D_;
  for (int l = 0; l < L_; ++l) {
    const u16* wqT = wqkvoT + ((size_t)l * 4 + 0) * WSZ;
    const u16* woT = wqkvoT + ((size_t)l * 4 + 3) * WSZ;
    const u16* wil = wiT + (size_t)l * 4096 * 512;
    const u16* wol = woutT + (size_t)l * 512 * 2048;
    u16* kb_l = batched ? kb_all + (size_t)l * KVSZ : kb_all;
    u16* vb_l = batched ? vb_all + (size_t)l * KVSZ : vb_all;

    rmsnorm_k<1><<<B_ * T_, 128, 0, stream>>>(cx, ln1 + l * D_, nx_b);
    gemm_sm_k<1><<<dim3(8, 64), 256, 0, stream>>>(nx_b, wqT, qbias + l * D_, qb_b,
                                                  B_ * T_, D_, D_, T_, rc, rs);
    if (!batched) {
      kv_gemm_k<<<dim3(8 * 8 * 9), 256, 0, stream>>>(kv_b, wqkvoT, kbias, vbias,
                                                     kb_l, vb_l, rc, rs, l, 0);
    }
    attn_mfma_k<<<dim3(256), 512, 0, stream>>>(qb_b, kb_l, vb_l, tokens, ob_b);
    gemm_sm_k<2><<<dim3(8, 64), 256, 0, stream>>>(ob_b, woT, obias + l * D_, cx,
                                                  B_ * T_, D_, D_, 0, nullptr, nullptr);
    rmsnorm_k<1><<<B_ * T_, 128, 0, stream>>>(cx, ln2 + l * D_, nx_b);
    mlp_in_mfma_k<<<dim3(32, 32), 256, 0, stream>>>(nx_b, wil, hb);
    gemm_sm_k<2><<<dim3(8, 64), 256, 0, stream>>>(hb, wol, nullptr, cx,
                                                  B_ * T_, D_, 2048, 0, nullptr, nullptr);
  }
  rmsnorm_k<0><<<B_ * T_, 128, 0, stream>>>(cx, final_s, d_out);
}